// Round 1
// baseline (903.002 us; speedup 1.0000x reference)
//
#include <hip/hip_runtime.h>
#include <math.h>

#define LRELU_SLOPE 0.2f
#define NEG_INF __int_as_float(0xff800000)

__device__ __forceinline__ void atomicMaxF(float* addr, float v) {
  if (v >= 0.f) atomicMax((int*)addr, __float_as_int(v));
  else atomicMin((unsigned int*)addr, (unsigned int)__float_as_int(v));
}

// ---------------- GEMM: C[M,256] = A[M,256] @ B[256,256] (row-major, fp32) ----
#define GBM 128
#define GBN 128
#define GBK 32
#define LDP 132  // padded LDS leading dim (keeps 16B alignment, breaks pow2 stride)

__global__ __launch_bounds__(256) void gemm_f32(
    const float* __restrict__ A, const float* __restrict__ B,
    float* __restrict__ C, int M) {
  __shared__ float As[GBK][LDP];  // As[k][m]  (A tile transposed)
  __shared__ float Bs[GBK][LDP];  // Bs[k][n]
  const int tid = threadIdx.x;
  const int tx = tid & 15, ty = tid >> 4;
  const int bm = blockIdx.x * GBM;
  const int bn = blockIdx.y * GBN;
  float acc[8][8];
#pragma unroll
  for (int i = 0; i < 8; ++i)
#pragma unroll
    for (int j = 0; j < 8; ++j) acc[i][j] = 0.f;

  for (int kc = 0; kc < 256; kc += GBK) {
    // A tile: 128 rows x 32 k, transposed into As[k][m]
#pragma unroll
    for (int i = 0; i < 4; ++i) {
      int idx = tid + i * 256;          // 0..1023 float4 slots
      int r = idx >> 3;                 // 0..127
      int c4 = (idx & 7) * 4;           // 0..28
      int row = bm + r;
      float4 v = make_float4(0.f, 0.f, 0.f, 0.f);
      if (row < M) v = *(const float4*)(A + (size_t)row * 256 + kc + c4);
      As[c4 + 0][r] = v.x; As[c4 + 1][r] = v.y;
      As[c4 + 2][r] = v.z; As[c4 + 3][r] = v.w;
    }
    // B tile: 32 k x 128 n
#pragma unroll
    for (int i = 0; i < 4; ++i) {
      int idx = tid + i * 256;
      int r = idx >> 5;                 // 0..31
      int c4 = (idx & 31) * 4;          // 0..124
      float4 v = *(const float4*)(B + (size_t)(kc + r) * 256 + bn + c4);
      *(float4*)&Bs[r][c4] = v;
    }
    __syncthreads();
#pragma unroll
    for (int kk = 0; kk < GBK; ++kk) {
      float a[8], b[8];
      *(float4*)&a[0] = *(const float4*)&As[kk][ty * 8];
      *(float4*)&a[4] = *(const float4*)&As[kk][ty * 8 + 4];
      *(float4*)&b[0] = *(const float4*)&Bs[kk][tx * 4];
      *(float4*)&b[4] = *(const float4*)&Bs[kk][64 + tx * 4];
#pragma unroll
      for (int i = 0; i < 8; ++i)
#pragma unroll
        for (int j = 0; j < 8; ++j) acc[i][j] = fmaf(a[i], b[j], acc[i][j]);
    }
    __syncthreads();
  }
#pragma unroll
  for (int i = 0; i < 8; ++i) {
    int row = bm + ty * 8 + i;
    if (row < M) {
      *(float4*)(C + (size_t)row * 256 + bn + tx * 4)      = *(float4*)&acc[i][0];
      *(float4*)(C + (size_t)row * 256 + bn + 64 + tx * 4) = *(float4*)&acc[i][4];
    }
  }
}

// ---------------- attention coefficients: a_src/a_dst [N,4] -------------------
__global__ __launch_bounds__(256) void attn_ab(
    const float* __restrict__ h, const float* __restrict__ att_s,
    const float* __restrict__ att_d, float* __restrict__ a_s,
    float* __restrict__ a_d, int N_) {
  const int lane = threadIdx.x & 63;
  const int head = threadIdx.x >> 6;  // 4 waves = 4 heads
  const float ws_ = att_s[head * 64 + lane];
  const float wd_ = att_d[head * 64 + lane];
  int n0 = blockIdx.x * 8;
  int n1 = min(n0 + 8, N_);
  for (int n = n0; n < n1; ++n) {
    float v = h[(size_t)n * 256 + head * 64 + lane];
    float ps = v * ws_, pd = v * wd_;
#pragma unroll
    for (int off = 32; off > 0; off >>= 1) {
      ps += __shfl_xor(ps, off);
      pd += __shfl_xor(pd, off);
    }
    if (lane == 0) { a_s[n * 4 + head] = ps; a_d[n * 4 + head] = pd; }
  }
}

// ---------------- misc init ---------------------------------------------------
__global__ void init_misc(int* __restrict__ count, float* __restrict__ denom,
                          float* __restrict__ pooled, int N_, int G_) {
  int t = blockIdx.x * 256 + threadIdx.x;
  if (t < N_) count[t] = 1;                 // self loop
  if (t < N_ * 4) denom[t] = 0.f;
  if (t < G_ * 256) pooled[t] = NEG_INF;
}

__global__ void zero_f(float* __restrict__ p, int n) {
  int t = blockIdx.x * 256 + threadIdx.x;
  if (t < n) p[t] = 0.f;
}

// ---------------- CSR build ----------------------------------------------------
__global__ void hist_k(const int* __restrict__ dst, int* __restrict__ count, int E_) {
  int t = blockIdx.x * 256 + threadIdx.x;
  if (t < E_) atomicAdd(&count[dst[t]], 1);
}

__global__ __launch_bounds__(256) void scan_counts(
    const int* __restrict__ count, int* __restrict__ rowptr,
    int* __restrict__ nxt, int N_) {
  __shared__ int tmp[256];
  int t = threadIdx.x;
  int chunk = (N_ + 255) / 256;
  int beg = t * chunk, end = min(beg + chunk, N_);
  int s = 0;
  for (int i = beg; i < end; ++i) s += count[i];
  tmp[t] = s;
  __syncthreads();
  for (int off = 1; off < 256; off <<= 1) {
    int u = (t >= off) ? tmp[t - off] : 0;
    __syncthreads();
    tmp[t] += u;
    __syncthreads();
  }
  int run = tmp[t] - s;  // exclusive prefix of this chunk
  for (int i = beg; i < end; ++i) {
    rowptr[i] = run; nxt[i] = run;
    run += count[i];
  }
  if (t == 255) rowptr[N_] = tmp[255];
}

__global__ void scatter_k(const int* __restrict__ src, const int* __restrict__ dst,
                          int* __restrict__ nxt, int* __restrict__ colx,
                          int E_, int N_) {
  int t = blockIdx.x * 256 + threadIdx.x;
  if (t >= E_ + N_) return;
  int s = (t < E_) ? src[t] : (t - E_);
  int d = (t < E_) ? dst[t] : (t - E_);
  int pos = atomicAdd(&nxt[d], 1);
  colx[pos] = s;
}

// ---------------- softmax denominators (shift-free: logits are O(10)) ---------
__global__ void edge_denom(const int* __restrict__ src, const int* __restrict__ dst,
                           const float* __restrict__ a_s, const float* __restrict__ a_d,
                           float* __restrict__ denom, int E_, int N_) {
  int t = blockIdx.x * 256 + threadIdx.x;
  if (t >= E_ + N_) return;
  int s = (t < E_) ? src[t] : (t - E_);
  int d = (t < E_) ? dst[t] : (t - E_);
  float4 as4 = *(const float4*)(a_s + (size_t)s * 4);
  float4 ad4 = *(const float4*)(a_d + (size_t)d * 4);
  float l;
  l = as4.x + ad4.x; l = l > 0.f ? l : LRELU_SLOPE * l; atomicAdd(denom + d * 4 + 0, expf(l));
  l = as4.y + ad4.y; l = l > 0.f ? l : LRELU_SLOPE * l; atomicAdd(denom + d * 4 + 1, expf(l));
  l = as4.z + ad4.z; l = l > 0.f ? l : LRELU_SLOPE * l; atomicAdd(denom + d * 4 + 2, expf(l));
  l = as4.w + ad4.w; l = l > 0.f ? l : LRELU_SLOPE * l; atomicAdd(denom + d * 4 + 3, expf(l));
}

// ---------------- aggregation: out[n,c] = elu( sum_e alpha*h[src,c] + bias ) --
__global__ __launch_bounds__(256) void agg(
    const float* __restrict__ h, const int* __restrict__ rowptr,
    const int* __restrict__ colx, const float* __restrict__ a_s,
    const float* __restrict__ a_d, const float* __restrict__ denom,
    const float* __restrict__ bias, float* __restrict__ out, int N_) {
  int n = blockIdx.x;
  int c = threadIdx.x;          // 0..255 channel
  int head = c >> 6;
  float ad = a_d[n * 4 + head];
  float inv = 1.f / (denom[n * 4 + head] + 1e-16f);
  float acc = 0.f;
  int e0 = rowptr[n], e1 = rowptr[n + 1];
  for (int j = e0; j < e1; ++j) {
    int s = colx[j];
    float l = a_s[s * 4 + head] + ad;
    l = l > 0.f ? l : LRELU_SLOPE * l;
    float alpha = expf(l) * inv;
    acc = fmaf(alpha, h[(size_t)s * 256 + c], acc);
  }
  float v = acc + bias[c];
  out[(size_t)n * 256 + c] = v > 0.f ? v : expm1f(v);
}

// ---------------- graph max-pool (batch is sorted) -----------------------------
#define PNB 128
__global__ __launch_bounds__(256) void pool_max(
    const float* __restrict__ h, const int* __restrict__ batch,
    float* __restrict__ pooled, int N_) {
  int c = threadIdx.x;
  int n0 = blockIdx.x * PNB;
  int n1 = min(n0 + PNB, N_);
  float run = NEG_INF;
  int g = batch[n0];
  for (int n = n0; n < n1; ++n) {
    int gn = batch[n];
    if (gn != g) {
      atomicMaxF(&pooled[(size_t)g * 256 + c], run);
      run = NEG_INF; g = gn;
    }
    run = fmaxf(run, h[(size_t)n * 256 + c]);
  }
  atomicMaxF(&pooled[(size_t)g * 256 + c], run);
}

// ---------------- head: fixup -inf, lin1 (256->128), lin2 (128->2) ------------
__global__ __launch_bounds__(128) void head_k(
    const float* __restrict__ pooled, const float* __restrict__ w1,
    const float* __restrict__ b1, const float* __restrict__ w2,
    const float* __restrict__ b2, float* __restrict__ out) {
  __shared__ float ps[256];
  __shared__ float z1[128];
  int g = blockIdx.x;
  int t = threadIdx.x;
  for (int i = t; i < 256; i += 128) {
    float v = pooled[(size_t)g * 256 + i];
    if (v < -1e37f) v = 0.f;   // empty-graph guard (isneginf -> 0)
    ps[i] = v;
  }
  __syncthreads();
  float a = b1[t];
  for (int k = 0; k < 256; ++k) a = fmaf(ps[k], w1[k * 128 + t], a);
  z1[t] = a;
  __syncthreads();
  if (t < 2) {
    float a2 = b2[t];
    for (int j = 0; j < 128; ++j) a2 = fmaf(z1[j], w2[j * 2 + t], a2);
    out[g * 2 + t] = a2;
  }
}

// ---------------- driver --------------------------------------------------------
extern "C" void kernel_launch(void* const* d_in, const int* in_sizes, int n_in,
                              void* d_out, int out_size, void* d_ws, size_t ws_size,
                              hipStream_t stream) {
  const int N = in_sizes[2];         // batch array length = #nodes
  const int E = in_sizes[1] / 2;     // edge_index is [2,E]
  const int G = out_size / 2;        // output [G,2]

  const float* x     = (const float*)d_in[0];
  const int*   ei    = (const int*)d_in[1];
  const int*   src   = ei;
  const int*   dst   = ei + E;
  const int*   batch = (const int*)d_in[2];
  const float* W1    = (const float*)d_in[3];
  const float* atts1 = (const float*)d_in[4];
  const float* attd1 = (const float*)d_in[5];
  const float* b1    = (const float*)d_in[6];
  const float* W2    = (const float*)d_in[7];
  const float* atts2 = (const float*)d_in[8];
  const float* attd2 = (const float*)d_in[9];
  const float* b2    = (const float*)d_in[10];
  const float* l1w   = (const float*)d_in[11];
  const float* l1b   = (const float*)d_in[12];
  const float* l2w   = (const float*)d_in[13];
  const float* l2b   = (const float*)d_in[14];

  uintptr_t p = (uintptr_t)d_ws;
  auto alloc = [&](size_t bytes) -> void* {
    p = (p + 255) & ~(uintptr_t)255;
    void* r = (void*)p;
    p += bytes;
    return r;
  };
  float* hbuf   = (float*)alloc((size_t)N * 256 * 4);
  float* fbuf   = (float*)alloc((size_t)N * 256 * 4);
  float* a_s    = (float*)alloc((size_t)N * 4 * 4);
  float* a_d    = (float*)alloc((size_t)N * 4 * 4);
  float* denom  = (float*)alloc((size_t)N * 4 * 4);
  float* pooled = (float*)alloc((size_t)G * 256 * 4);
  int*   count  = (int*)alloc((size_t)N * 4);
  int*   rowptr = (int*)alloc((size_t)(N + 1) * 4);
  int*   nxt    = (int*)alloc((size_t)N * 4);
  int*   colx   = (int*)alloc((size_t)(E + N) * 4);

  dim3 blk(256);
  dim3 gemmGrid((N + GBM - 1) / GBM, 2);
  int initRange = max(N * 4, G * 256);

  // CSR build (shared by both layers) + init
  init_misc<<<(initRange + 255) / 256, blk, 0, stream>>>(count, denom, pooled, N, G);
  hist_k<<<(E + 255) / 256, blk, 0, stream>>>(dst, count, E);
  scan_counts<<<1, blk, 0, stream>>>(count, rowptr, nxt, N);
  scatter_k<<<(E + N + 255) / 256, blk, 0, stream>>>(src, dst, nxt, colx, E, N);

  // ---- layer 1
  gemm_f32<<<gemmGrid, blk, 0, stream>>>(x, W1, hbuf, N);
  attn_ab<<<(N + 7) / 8, blk, 0, stream>>>(hbuf, atts1, attd1, a_s, a_d, N);
  edge_denom<<<(E + N + 255) / 256, blk, 0, stream>>>(src, dst, a_s, a_d, denom, E, N);
  agg<<<N, blk, 0, stream>>>(hbuf, rowptr, colx, a_s, a_d, denom, b1, fbuf, N);

  // ---- layer 2
  zero_f<<<(N * 4 + 255) / 256, blk, 0, stream>>>(denom, N * 4);
  gemm_f32<<<gemmGrid, blk, 0, stream>>>(fbuf, W2, hbuf, N);
  attn_ab<<<(N + 7) / 8, blk, 0, stream>>>(hbuf, atts2, attd2, a_s, a_d, N);
  edge_denom<<<(E + N + 255) / 256, blk, 0, stream>>>(src, dst, a_s, a_d, denom, E, N);
  agg<<<N, blk, 0, stream>>>(hbuf, rowptr, colx, a_s, a_d, denom, b2, fbuf, N);

  // ---- pool + head
  pool_max<<<(N + PNB - 1) / PNB, blk, 0, stream>>>(fbuf, batch, pooled, N);
  head_k<<<G, 128, 0, stream>>>(pooled, l1w, l1b, l2w, l2b, (float*)d_out);
}

// Round 2
// 618.465 us; speedup vs baseline: 1.4601x; 1.4601x over previous
//
#include <hip/hip_runtime.h>
#include <math.h>

#define LRELU_SLOPE 0.2f
#define NEG_INF __int_as_float(0xff800000)

__device__ __forceinline__ void atomicMaxF(float* addr, float v) {
  if (v >= 0.f) atomicMax((int*)addr, __float_as_int(v));
  else atomicMin((unsigned int*)addr, (unsigned int)__float_as_int(v));
}

// ---------------- GEMM: C[M,256] = A[M,256] @ B[256,256] (row-major, fp32) ----
#define GBM 128
#define GBN 128
#define GBK 32
#define LDP 132  // padded LDS leading dim

__global__ __launch_bounds__(256) void gemm_f32(
    const float* __restrict__ A, const float* __restrict__ B,
    float* __restrict__ C, int M) {
  __shared__ float As[GBK][LDP];  // As[k][m]  (A tile transposed)
  __shared__ float Bs[GBK][LDP];  // Bs[k][n]
  const int tid = threadIdx.x;
  const int tx = tid & 15, ty = tid >> 4;
  const int bm = blockIdx.x * GBM;
  const int bn = blockIdx.y * GBN;
  float acc[8][8];
#pragma unroll
  for (int i = 0; i < 8; ++i)
#pragma unroll
    for (int j = 0; j < 8; ++j) acc[i][j] = 0.f;

  for (int kc = 0; kc < 256; kc += GBK) {
#pragma unroll
    for (int i = 0; i < 4; ++i) {
      int idx = tid + i * 256;
      int r = idx >> 3;
      int c4 = (idx & 7) * 4;
      int row = bm + r;
      float4 v = make_float4(0.f, 0.f, 0.f, 0.f);
      if (row < M) v = *(const float4*)(A + (size_t)row * 256 + kc + c4);
      As[c4 + 0][r] = v.x; As[c4 + 1][r] = v.y;
      As[c4 + 2][r] = v.z; As[c4 + 3][r] = v.w;
    }
#pragma unroll
    for (int i = 0; i < 4; ++i) {
      int idx = tid + i * 256;
      int r = idx >> 5;
      int c4 = (idx & 31) * 4;
      float4 v = *(const float4*)(B + (size_t)(kc + r) * 256 + bn + c4);
      *(float4*)&Bs[r][c4] = v;
    }
    __syncthreads();
#pragma unroll
    for (int kk = 0; kk < GBK; ++kk) {
      float a[8], b[8];
      *(float4*)&a[0] = *(const float4*)&As[kk][ty * 8];
      *(float4*)&a[4] = *(const float4*)&As[kk][ty * 8 + 4];
      *(float4*)&b[0] = *(const float4*)&Bs[kk][tx * 4];
      *(float4*)&b[4] = *(const float4*)&Bs[kk][64 + tx * 4];
#pragma unroll
      for (int i = 0; i < 8; ++i)
#pragma unroll
        for (int j = 0; j < 8; ++j) acc[i][j] = fmaf(a[i], b[j], acc[i][j]);
    }
    __syncthreads();
  }
#pragma unroll
  for (int i = 0; i < 8; ++i) {
    int row = bm + ty * 8 + i;
    if (row < M) {
      *(float4*)(C + (size_t)row * 256 + bn + tx * 4)      = *(float4*)&acc[i][0];
      *(float4*)(C + (size_t)row * 256 + bn + 64 + tx * 4) = *(float4*)&acc[i][4];
    }
  }
}

// ---------------- attention coefficients: a_src/a_dst [N,4] -------------------
__global__ __launch_bounds__(256) void attn_ab(
    const float* __restrict__ h, const float* __restrict__ att_s,
    const float* __restrict__ att_d, float* __restrict__ a_s,
    float* __restrict__ a_d, int N_) {
  const int lane = threadIdx.x & 63;
  const int head = threadIdx.x >> 6;  // 4 waves = 4 heads
  const float ws_ = att_s[head * 64 + lane];
  const float wd_ = att_d[head * 64 + lane];
  int n0 = blockIdx.x * 8;
  int n1 = min(n0 + 8, N_);
  for (int n = n0; n < n1; ++n) {
    float v = h[(size_t)n * 256 + head * 64 + lane];
    float ps = v * ws_, pd = v * wd_;
#pragma unroll
    for (int off = 32; off > 0; off >>= 1) {
      ps += __shfl_xor(ps, off);
      pd += __shfl_xor(pd, off);
    }
    if (lane == 0) { a_s[n * 4 + head] = ps; a_d[n * 4 + head] = pd; }
  }
}

// ---------------- misc init ---------------------------------------------------
__global__ void init_misc(int* __restrict__ count, float* __restrict__ pooled,
                          int N_, int G_) {
  int t = blockIdx.x * 256 + threadIdx.x;
  if (t < N_) count[t] = 1;                 // self loop
  if (t < G_ * 256) pooled[t] = NEG_INF;
}

// ---------------- CSR build ----------------------------------------------------
__global__ void hist_k(const int* __restrict__ dst, int* __restrict__ count, int E_) {
  int t = blockIdx.x * 256 + threadIdx.x;
  if (t < E_) atomicAdd(&count[dst[t]], 1);
}

__global__ __launch_bounds__(256) void scan_counts(
    const int* __restrict__ count, int* __restrict__ rowptr,
    int* __restrict__ nxt, int N_) {
  __shared__ int tmp[256];
  int t = threadIdx.x;
  int chunk = (N_ + 255) / 256;
  int beg = t * chunk, end = min(beg + chunk, N_);
  int s = 0;
  for (int i = beg; i < end; ++i) s += count[i];
  tmp[t] = s;
  __syncthreads();
  for (int off = 1; off < 256; off <<= 1) {
    int u = (t >= off) ? tmp[t - off] : 0;
    __syncthreads();
    tmp[t] += u;
    __syncthreads();
  }
  int run = tmp[t] - s;  // exclusive prefix of this chunk
  for (int i = beg; i < end; ++i) {
    rowptr[i] = run; nxt[i] = run;
    run += count[i];
  }
  if (t == 255) rowptr[N_] = tmp[255];
}

__global__ void scatter_k(const int* __restrict__ src, const int* __restrict__ dst,
                          int* __restrict__ nxt, int* __restrict__ colx,
                          int E_, int N_) {
  int t = blockIdx.x * 256 + threadIdx.x;
  if (t >= E_ + N_) return;
  int s = (t < E_) ? src[t] : (t - E_);
  int d = (t < E_) ? dst[t] : (t - E_);
  int pos = atomicAdd(&nxt[d], 1);
  colx[pos] = s;
}

// ---------------- aggregation: wave-per-node, float4 channels, fused denom ----
// out[n,c] = elu( (sum_e exp(lrelu(a_s[s]+a_d[n])) * h[s,c]) / sum_e exp(..) + bias[c] )
__global__ __launch_bounds__(256) void agg(
    const float* __restrict__ h, const int* __restrict__ rowptr,
    const int* __restrict__ colx, const float* __restrict__ a_s,
    const float* __restrict__ a_d, const float* __restrict__ bias,
    float* __restrict__ out, int N_) {
  const int wave = threadIdx.x >> 6;
  const int lane = threadIdx.x & 63;
  const int n = blockIdx.x * 4 + wave;
  if (n >= N_) return;
  const int head = lane >> 4;           // lane owns channels [4*lane, 4*lane+4)
  const float ad = a_d[n * 4 + head];
  const int e0 = rowptr[n], e1 = rowptr[n + 1];
  float4 acc = make_float4(0.f, 0.f, 0.f, 0.f);
  float dsum = 0.f;
  for (int j = e0; j < e1; ++j) {
    int s = colx[j];
    float l = a_s[s * 4 + head] + ad;
    l = l > 0.f ? l : LRELU_SLOPE * l;
    float e = __expf(l);
    dsum += e;
    float4 hv = *(const float4*)(h + (size_t)s * 256 + lane * 4);
    acc.x = fmaf(e, hv.x, acc.x);
    acc.y = fmaf(e, hv.y, acc.y);
    acc.z = fmaf(e, hv.z, acc.z);
    acc.w = fmaf(e, hv.w, acc.w);
  }
  const float inv = 1.f / (dsum + 1e-16f);
  const float4 b4 = *(const float4*)(bias + lane * 4);
  float v;
  float4 o;
  v = acc.x * inv + b4.x; o.x = v > 0.f ? v : expm1f(v);
  v = acc.y * inv + b4.y; o.y = v > 0.f ? v : expm1f(v);
  v = acc.z * inv + b4.z; o.z = v > 0.f ? v : expm1f(v);
  v = acc.w * inv + b4.w; o.w = v > 0.f ? v : expm1f(v);
  *(float4*)(out + (size_t)n * 256 + lane * 4) = o;
}

// ---------------- graph max-pool (batch is sorted) -----------------------------
#define PNB 128
__global__ __launch_bounds__(256) void pool_max(
    const float* __restrict__ h, const int* __restrict__ batch,
    float* __restrict__ pooled, int N_) {
  int c = threadIdx.x;
  int n0 = blockIdx.x * PNB;
  int n1 = min(n0 + PNB, N_);
  float run = NEG_INF;
  int g = batch[n0];
  for (int n = n0; n < n1; ++n) {
    int gn = batch[n];
    if (gn != g) {
      atomicMaxF(&pooled[(size_t)g * 256 + c], run);
      run = NEG_INF; g = gn;
    }
    run = fmaxf(run, h[(size_t)n * 256 + c]);
  }
  atomicMaxF(&pooled[(size_t)g * 256 + c], run);
}

// ---------------- head: fixup -inf, lin1 (256->128), lin2 (128->2) ------------
__global__ __launch_bounds__(128) void head_k(
    const float* __restrict__ pooled, const float* __restrict__ w1,
    const float* __restrict__ b1, const float* __restrict__ w2,
    const float* __restrict__ b2, float* __restrict__ out) {
  __shared__ float ps[256];
  __shared__ float z1[128];
  int g = blockIdx.x;
  int t = threadIdx.x;
  for (int i = t; i < 256; i += 128) {
    float v = pooled[(size_t)g * 256 + i];
    if (v < -1e37f) v = 0.f;   // empty-graph guard (isneginf -> 0)
    ps[i] = v;
  }
  __syncthreads();
  float a = b1[t];
  for (int k = 0; k < 256; ++k) a = fmaf(ps[k], w1[k * 128 + t], a);
  z1[t] = a;
  __syncthreads();
  if (t < 2) {
    float a2 = b2[t];
    for (int j = 0; j < 128; ++j) a2 = fmaf(z1[j], w2[j * 2 + t], a2);
    out[g * 2 + t] = a2;
  }
}

// ---------------- driver --------------------------------------------------------
extern "C" void kernel_launch(void* const* d_in, const int* in_sizes, int n_in,
                              void* d_out, int out_size, void* d_ws, size_t ws_size,
                              hipStream_t stream) {
  const int N = in_sizes[2];         // batch array length = #nodes
  const int E = in_sizes[1] / 2;     // edge_index is [2,E]
  const int G = out_size / 2;        // output [G,2]

  const float* x     = (const float*)d_in[0];
  const int*   ei    = (const int*)d_in[1];
  const int*   src   = ei;
  const int*   dst   = ei + E;
  const int*   batch = (const int*)d_in[2];
  const float* W1    = (const float*)d_in[3];
  const float* atts1 = (const float*)d_in[4];
  const float* attd1 = (const float*)d_in[5];
  const float* b1    = (const float*)d_in[6];
  const float* W2    = (const float*)d_in[7];
  const float* atts2 = (const float*)d_in[8];
  const float* attd2 = (const float*)d_in[9];
  const float* b2    = (const float*)d_in[10];
  const float* l1w   = (const float*)d_in[11];
  const float* l1b   = (const float*)d_in[12];
  const float* l2w   = (const float*)d_in[13];
  const float* l2b   = (const float*)d_in[14];

  uintptr_t p = (uintptr_t)d_ws;
  auto alloc = [&](size_t bytes) -> void* {
    p = (p + 255) & ~(uintptr_t)255;
    void* r = (void*)p;
    p += bytes;
    return r;
  };
  float* hbuf   = (float*)alloc((size_t)N * 256 * 4);
  float* fbuf   = (float*)alloc((size_t)N * 256 * 4);
  float* a_s    = (float*)alloc((size_t)N * 4 * 4);
  float* a_d    = (float*)alloc((size_t)N * 4 * 4);
  float* pooled = (float*)alloc((size_t)G * 256 * 4);
  int*   count  = (int*)alloc((size_t)N * 4);
  int*   rowptr = (int*)alloc((size_t)(N + 1) * 4);
  int*   nxt    = (int*)alloc((size_t)N * 4);
  int*   colx   = (int*)alloc((size_t)(E + N) * 4);

  dim3 blk(256);
  dim3 gemmGrid((N + GBM - 1) / GBM, 2);
  int initRange = max(N, G * 256);

  // CSR build (shared by both layers) + init
  init_misc<<<(initRange + 255) / 256, blk, 0, stream>>>(count, pooled, N, G);
  hist_k<<<(E + 255) / 256, blk, 0, stream>>>(dst, count, E);
  scan_counts<<<1, blk, 0, stream>>>(count, rowptr, nxt, N);
  scatter_k<<<(E + N + 255) / 256, blk, 0, stream>>>(src, dst, nxt, colx, E, N);

  // ---- layer 1
  gemm_f32<<<gemmGrid, blk, 0, stream>>>(x, W1, hbuf, N);
  attn_ab<<<(N + 7) / 8, blk, 0, stream>>>(hbuf, atts1, attd1, a_s, a_d, N);
  agg<<<(N + 3) / 4, blk, 0, stream>>>(hbuf, rowptr, colx, a_s, a_d, b1, fbuf, N);

  // ---- layer 2
  gemm_f32<<<gemmGrid, blk, 0, stream>>>(fbuf, W2, hbuf, N);
  attn_ab<<<(N + 7) / 8, blk, 0, stream>>>(hbuf, atts2, attd2, a_s, a_d, N);
  agg<<<(N + 3) / 4, blk, 0, stream>>>(hbuf, rowptr, colx, a_s, a_d, b2, fbuf, N);

  // ---- pool + head
  pool_max<<<(N + PNB - 1) / PNB, blk, 0, stream>>>(fbuf, batch, pooled, N);
  head_k<<<G, 128, 0, stream>>>(pooled, l1w, l1b, l2w, l2b, (float*)d_out);
}

// Round 3
// 507.316 us; speedup vs baseline: 1.7800x; 1.2191x over previous
//
#include <hip/hip_runtime.h>
#include <math.h>

#define LRELU_SLOPE 0.2f
#define NEG_INF __int_as_float(0xff800000)

__device__ __forceinline__ void atomicMaxF(float* addr, float v) {
  if (v >= 0.f) atomicMax((int*)addr, __float_as_int(v));
  else atomicMin((unsigned int*)addr, (unsigned int)__float_as_int(v));
}

// ---------------- GEMM: C[M,256] = A[M,256] @ B[256,256] (row-major, fp32) ----
#define GBM 128
#define GBN 128
#define GBK 32
#define LDP 132  // padded LDS leading dim

__global__ __launch_bounds__(256) void gemm_f32(
    const float* __restrict__ A, const float* __restrict__ B,
    float* __restrict__ C, int M) {
  __shared__ float As[GBK][LDP];  // As[k][m]  (A tile transposed)
  __shared__ float Bs[GBK][LDP];  // Bs[k][n]
  const int tid = threadIdx.x;
  const int tx = tid & 15, ty = tid >> 4;
  const int bm = blockIdx.x * GBM;
  const int bn = blockIdx.y * GBN;
  float acc[8][8];
#pragma unroll
  for (int i = 0; i < 8; ++i)
#pragma unroll
    for (int j = 0; j < 8; ++j) acc[i][j] = 0.f;

  for (int kc = 0; kc < 256; kc += GBK) {
#pragma unroll
    for (int i = 0; i < 4; ++i) {
      int idx = tid + i * 256;
      int r = idx >> 3;
      int c4 = (idx & 7) * 4;
      int row = bm + r;
      float4 v = make_float4(0.f, 0.f, 0.f, 0.f);
      if (row < M) v = *(const float4*)(A + (size_t)row * 256 + kc + c4);
      As[c4 + 0][r] = v.x; As[c4 + 1][r] = v.y;
      As[c4 + 2][r] = v.z; As[c4 + 3][r] = v.w;
    }
#pragma unroll
    for (int i = 0; i < 4; ++i) {
      int idx = tid + i * 256;
      int r = idx >> 5;
      int c4 = (idx & 31) * 4;
      float4 v = *(const float4*)(B + (size_t)(kc + r) * 256 + bn + c4);
      *(float4*)&Bs[r][c4] = v;
    }
    __syncthreads();
#pragma unroll
    for (int kk = 0; kk < GBK; ++kk) {
      float a[8], b[8];
      *(float4*)&a[0] = *(const float4*)&As[kk][ty * 8];
      *(float4*)&a[4] = *(const float4*)&As[kk][ty * 8 + 4];
      *(float4*)&b[0] = *(const float4*)&Bs[kk][tx * 4];
      *(float4*)&b[4] = *(const float4*)&Bs[kk][64 + tx * 4];
#pragma unroll
      for (int i = 0; i < 8; ++i)
#pragma unroll
        for (int j = 0; j < 8; ++j) acc[i][j] = fmaf(a[i], b[j], acc[i][j]);
    }
    __syncthreads();
  }
#pragma unroll
  for (int i = 0; i < 8; ++i) {
    int row = bm + ty * 8 + i;
    if (row < M) {
      *(float4*)(C + (size_t)row * 256 + bn + tx * 4)      = *(float4*)&acc[i][0];
      *(float4*)(C + (size_t)row * 256 + bn + 64 + tx * 4) = *(float4*)&acc[i][4];
    }
  }
}

// ---------------- attention coefficients: a_src/a_dst [N,4] -------------------
__global__ __launch_bounds__(256) void attn_ab(
    const float* __restrict__ h, const float* __restrict__ att_s,
    const float* __restrict__ att_d, float* __restrict__ a_s,
    float* __restrict__ a_d, int N_) {
  const int lane = threadIdx.x & 63;
  const int head = threadIdx.x >> 6;  // 4 waves = 4 heads
  const float ws_ = att_s[head * 64 + lane];
  const float wd_ = att_d[head * 64 + lane];
  int n0 = blockIdx.x * 8;
  int n1 = min(n0 + 8, N_);
  for (int n = n0; n < n1; ++n) {
    float v = h[(size_t)n * 256 + head * 64 + lane];
    float ps = v * ws_, pd = v * wd_;
#pragma unroll
    for (int off = 32; off > 0; off >>= 1) {
      ps += __shfl_xor(ps, off);
      pd += __shfl_xor(pd, off);
    }
    if (lane == 0) { a_s[n * 4 + head] = ps; a_d[n * 4 + head] = pd; }
  }
}

// ---------------- misc init ---------------------------------------------------
__global__ void init_misc(int* __restrict__ count, float* __restrict__ pooled,
                          int N_, int G_) {
  int t = blockIdx.x * 256 + threadIdx.x;
  if (t < N_) count[t] = 1;                 // self loop
  if (t < G_ * 256) pooled[t] = NEG_INF;
}

// ---------------- CSR build ----------------------------------------------------
__global__ void hist_k(const int* __restrict__ dst, int* __restrict__ count, int E_) {
  int t = blockIdx.x * 256 + threadIdx.x;
  if (t < E_) atomicAdd(&count[dst[t]], 1);
}

// 3-phase parallel exclusive scan of count[0..N) -> rowptr/nxt, SCB elems/block
#define SCB 1024

__global__ __launch_bounds__(256) void scan_phaseA(
    const int* __restrict__ count, int* __restrict__ bsum, int N_) {
  int t = threadIdx.x;
  int base = blockIdx.x * SCB + t * 4;
  int s = 0;
  if (base + 3 < N_) {
    int4 v = *(const int4*)(count + base);
    s = v.x + v.y + v.z + v.w;
  } else {
#pragma unroll
    for (int k = 0; k < 4; ++k) if (base + k < N_) s += count[base + k];
  }
#pragma unroll
  for (int off = 32; off > 0; off >>= 1) s += __shfl_xor(s, off);
  __shared__ int red[4];
  int wave = t >> 6, lane = t & 63;
  if (lane == 0) red[wave] = s;
  __syncthreads();
  if (t == 0) bsum[blockIdx.x] = red[0] + red[1] + red[2] + red[3];
}

__global__ __launch_bounds__(256) void scan_phaseB(
    const int* __restrict__ bsum, int* __restrict__ boff, int nb) {
  __shared__ int tmp[256];
  int t = threadIdx.x;
  int v = (t < nb) ? bsum[t] : 0;
  tmp[t] = v;
  __syncthreads();
  for (int off = 1; off < 256; off <<= 1) {
    int u = (t >= off) ? tmp[t - off] : 0;
    __syncthreads();
    tmp[t] += u;
    __syncthreads();
  }
  if (t < nb) boff[t] = tmp[t] - v;  // exclusive
  if (t == 0) boff[nb] = tmp[255];   // grand total
}

__global__ __launch_bounds__(256) void scan_phaseC(
    const int* __restrict__ count, const int* __restrict__ boff,
    int* __restrict__ rowptr, int* __restrict__ nxt, int N_, int nb) {
  __shared__ int tmp[256];
  int t = threadIdx.x;
  int base = blockIdx.x * SCB + t * 4;
  int4 v = make_int4(0, 0, 0, 0);
  if (base + 3 < N_) {
    v = *(const int4*)(count + base);
  } else {
    if (base + 0 < N_) v.x = count[base + 0];
    if (base + 1 < N_) v.y = count[base + 1];
    if (base + 2 < N_) v.z = count[base + 2];
  }
  int s = v.x + v.y + v.z + v.w;
  tmp[t] = s;
  __syncthreads();
  for (int off = 1; off < 256; off <<= 1) {
    int u = (t >= off) ? tmp[t - off] : 0;
    __syncthreads();
    tmp[t] += u;
    __syncthreads();
  }
  int run = boff[blockIdx.x] + tmp[t] - s;
  int4 rp;
  rp.x = run; run += v.x;
  rp.y = run; run += v.y;
  rp.z = run; run += v.z;
  rp.w = run;
  if (base + 3 < N_) {
    *(int4*)(rowptr + base) = rp;
    *(int4*)(nxt + base) = rp;
  } else {
    if (base + 0 < N_) { rowptr[base + 0] = rp.x; nxt[base + 0] = rp.x; }
    if (base + 1 < N_) { rowptr[base + 1] = rp.y; nxt[base + 1] = rp.y; }
    if (base + 2 < N_) { rowptr[base + 2] = rp.z; nxt[base + 2] = rp.z; }
  }
  if (blockIdx.x == 0 && t == 0) rowptr[N_] = boff[nb];
}

__global__ void scatter_k(const int* __restrict__ src, const int* __restrict__ dst,
                          int* __restrict__ nxt, int* __restrict__ colx,
                          int E_, int N_) {
  int t = blockIdx.x * 256 + threadIdx.x;
  if (t >= E_ + N_) return;
  int s = (t < E_) ? src[t] : (t - E_);
  int d = (t < E_) ? dst[t] : (t - E_);
  int pos = atomicAdd(&nxt[d], 1);
  colx[pos] = s;
}

// ---------------- aggregation: wave-per-node, float4 channels, fused denom ----
__global__ __launch_bounds__(256) void agg(
    const float* __restrict__ h, const int* __restrict__ rowptr,
    const int* __restrict__ colx, const float* __restrict__ a_s,
    const float* __restrict__ a_d, const float* __restrict__ bias,
    float* __restrict__ out, int N_) {
  const int wave = threadIdx.x >> 6;
  const int lane = threadIdx.x & 63;
  const int n = blockIdx.x * 4 + wave;
  if (n >= N_) return;
  const int head = lane >> 4;           // lane owns channels [4*lane, 4*lane+4)
  const float ad = a_d[n * 4 + head];
  const int e0 = rowptr[n], e1 = rowptr[n + 1];
  float4 acc = make_float4(0.f, 0.f, 0.f, 0.f);
  float dsum = 0.f;
  for (int j = e0; j < e1; ++j) {
    int s = colx[j];
    float l = a_s[s * 4 + head] + ad;
    l = l > 0.f ? l : LRELU_SLOPE * l;
    float e = __expf(l);
    dsum += e;
    float4 hv = *(const float4*)(h + (size_t)s * 256 + lane * 4);
    acc.x = fmaf(e, hv.x, acc.x);
    acc.y = fmaf(e, hv.y, acc.y);
    acc.z = fmaf(e, hv.z, acc.z);
    acc.w = fmaf(e, hv.w, acc.w);
  }
  const float inv = 1.f / (dsum + 1e-16f);
  const float4 b4 = *(const float4*)(bias + lane * 4);
  float v;
  float4 o;
  v = acc.x * inv + b4.x; o.x = v > 0.f ? v : expm1f(v);
  v = acc.y * inv + b4.y; o.y = v > 0.f ? v : expm1f(v);
  v = acc.z * inv + b4.z; o.z = v > 0.f ? v : expm1f(v);
  v = acc.w * inv + b4.w; o.w = v > 0.f ? v : expm1f(v);
  *(float4*)(out + (size_t)n * 256 + lane * 4) = o;
}

// ---------------- graph max-pool (batch is sorted) -----------------------------
#define PNB 128
__global__ __launch_bounds__(256) void pool_max(
    const float* __restrict__ h, const int* __restrict__ batch,
    float* __restrict__ pooled, int N_) {
  int c = threadIdx.x;
  int n0 = blockIdx.x * PNB;
  int n1 = min(n0 + PNB, N_);
  float run = NEG_INF;
  int g = batch[n0];
  for (int n = n0; n < n1; ++n) {
    int gn = batch[n];
    if (gn != g) {
      atomicMaxF(&pooled[(size_t)g * 256 + c], run);
      run = NEG_INF; g = gn;
    }
    run = fmaxf(run, h[(size_t)n * 256 + c]);
  }
  atomicMaxF(&pooled[(size_t)g * 256 + c], run);
}

// ---------------- head: fixup -inf, lin1 (256->128), lin2 (128->2) ------------
__global__ __launch_bounds__(128) void head_k(
    const float* __restrict__ pooled, const float* __restrict__ w1,
    const float* __restrict__ b1, const float* __restrict__ w2,
    const float* __restrict__ b2, float* __restrict__ out) {
  __shared__ float ps[256];
  __shared__ float z1[128];
  int g = blockIdx.x;
  int t = threadIdx.x;
  for (int i = t; i < 256; i += 128) {
    float v = pooled[(size_t)g * 256 + i];
    if (v < -1e37f) v = 0.f;   // empty-graph guard (isneginf -> 0)
    ps[i] = v;
  }
  __syncthreads();
  float a = b1[t];
  for (int k = 0; k < 256; ++k) a = fmaf(ps[k], w1[k * 128 + t], a);
  z1[t] = a;
  __syncthreads();
  if (t < 2) {
    float a2 = b2[t];
    for (int j = 0; j < 128; ++j) a2 = fmaf(z1[j], w2[j * 2 + t], a2);
    out[g * 2 + t] = a2;
  }
}

// ---------------- driver --------------------------------------------------------
extern "C" void kernel_launch(void* const* d_in, const int* in_sizes, int n_in,
                              void* d_out, int out_size, void* d_ws, size_t ws_size,
                              hipStream_t stream) {
  const int N = in_sizes[2];         // batch array length = #nodes
  const int E = in_sizes[1] / 2;     // edge_index is [2,E]
  const int G = out_size / 2;        // output [G,2]

  const float* x     = (const float*)d_in[0];
  const int*   ei    = (const int*)d_in[1];
  const int*   src   = ei;
  const int*   dst   = ei + E;
  const int*   batch = (const int*)d_in[2];
  const float* W1    = (const float*)d_in[3];
  const float* atts1 = (const float*)d_in[4];
  const float* attd1 = (const float*)d_in[5];
  const float* b1    = (const float*)d_in[6];
  const float* W2    = (const float*)d_in[7];
  const float* atts2 = (const float*)d_in[8];
  const float* attd2 = (const float*)d_in[9];
  const float* b2    = (const float*)d_in[10];
  const float* l1w   = (const float*)d_in[11];
  const float* l1b   = (const float*)d_in[12];
  const float* l2w   = (const float*)d_in[13];
  const float* l2b   = (const float*)d_in[14];

  uintptr_t p = (uintptr_t)d_ws;
  auto alloc = [&](size_t bytes) -> void* {
    p = (p + 255) & ~(uintptr_t)255;
    void* r = (void*)p;
    p += bytes;
    return r;
  };
  const int nb = (N + SCB - 1) / SCB;
  float* hbuf   = (float*)alloc((size_t)N * 256 * 4);
  float* fbuf   = (float*)alloc((size_t)N * 256 * 4);
  float* a_s    = (float*)alloc((size_t)N * 4 * 4);
  float* a_d    = (float*)alloc((size_t)N * 4 * 4);
  float* pooled = (float*)alloc((size_t)G * 256 * 4);
  int*   count  = (int*)alloc((size_t)N * 4);
  int*   rowptr = (int*)alloc((size_t)(N + 1) * 4);
  int*   nxt    = (int*)alloc((size_t)N * 4);
  int*   colx   = (int*)alloc((size_t)(E + N) * 4);
  int*   bsum   = (int*)alloc((size_t)nb * 4);
  int*   boff   = (int*)alloc((size_t)(nb + 1) * 4);

  dim3 blk(256);
  dim3 gemmGrid((N + GBM - 1) / GBM, 2);
  int initRange = max(N, G * 256);

  // CSR build (shared by both layers) + init
  init_misc<<<(initRange + 255) / 256, blk, 0, stream>>>(count, pooled, N, G);
  hist_k<<<(E + 255) / 256, blk, 0, stream>>>(dst, count, E);
  scan_phaseA<<<nb, blk, 0, stream>>>(count, bsum, N);
  scan_phaseB<<<1, blk, 0, stream>>>(bsum, boff, nb);
  scan_phaseC<<<nb, blk, 0, stream>>>(count, boff, rowptr, nxt, N, nb);
  scatter_k<<<(E + N + 255) / 256, blk, 0, stream>>>(src, dst, nxt, colx, E, N);

  // ---- layer 1
  gemm_f32<<<gemmGrid, blk, 0, stream>>>(x, W1, hbuf, N);
  attn_ab<<<(N + 7) / 8, blk, 0, stream>>>(hbuf, atts1, attd1, a_s, a_d, N);
  agg<<<(N + 3) / 4, blk, 0, stream>>>(hbuf, rowptr, colx, a_s, a_d, b1, fbuf, N);

  // ---- layer 2
  gemm_f32<<<gemmGrid, blk, 0, stream>>>(fbuf, W2, hbuf, N);
  attn_ab<<<(N + 7) / 8, blk, 0, stream>>>(hbuf, atts2, attd2, a_s, a_d, N);
  agg<<<(N + 3) / 4, blk, 0, stream>>>(hbuf, rowptr, colx, a_s, a_d, b2, fbuf, N);

  // ---- pool + head
  pool_max<<<(N + PNB - 1) / PNB, blk, 0, stream>>>(fbuf, batch, pooled, N);
  head_k<<<G, 128, 0, stream>>>(pooled, l1w, l1b, l2w, l2b, (float*)d_out);
}

// Round 4
// 409.551 us; speedup vs baseline: 2.2049x; 1.2387x over previous
//
#include <hip/hip_runtime.h>
#include <math.h>

#define LRELU_SLOPE 0.2f
#define NEG_INF __int_as_float(0xff800000)

typedef float f32x4 __attribute__((ext_vector_type(4)));
typedef __bf16 bf16x8 __attribute__((ext_vector_type(8)));
typedef unsigned short us8 __attribute__((ext_vector_type(8)));

union BfCast { us8 u; bf16x8 b; };

__device__ __forceinline__ void atomicMaxF(float* addr, float v) {
  if (v >= 0.f) atomicMax((int*)addr, __float_as_int(v));
  else atomicMin((unsigned int*)addr, (unsigned int)__float_as_int(v));
}

__device__ __forceinline__ unsigned short bf_rne(float f) {
  unsigned int u = __float_as_uint(f);
  u += 0x7FFFu + ((u >> 16) & 1u);
  return (unsigned short)(u >> 16);
}

__device__ __forceinline__ void split_bf16(float f, unsigned short& hi, unsigned short& lo) {
  hi = bf_rne(f);
  float hif = __uint_as_float(((unsigned int)hi) << 16);
  lo = bf_rne(f - hif);
}

// ---------------- W pre-pass: transpose + split to bf16 hi/lo ------------------
// W[k][n] f32 (256x256) -> Wt_hi/Wt_lo [n][k] bf16
__global__ void conv_w(const float* __restrict__ W1, const float* __restrict__ W2,
                       unsigned short* __restrict__ t1h, unsigned short* __restrict__ t1l,
                       unsigned short* __restrict__ t2h, unsigned short* __restrict__ t2l) {
  const float* W = blockIdx.y ? W2 : W1;
  unsigned short* th = blockIdx.y ? t2h : t1h;
  unsigned short* tl = blockIdx.y ? t2l : t1l;
  int k = blockIdx.x, n = threadIdx.x;
  float f = W[k * 256 + n];
  unsigned short hi, lo;
  split_bf16(f, hi, lo);
  th[n * 256 + k] = hi;
  tl[n * 256 + k] = lo;
}

// ---------------- GEMM: C[M,256] = A[M,256] @ B[256,256] via split-bf16 MFMA ---
// A f32 converted to hi/lo bf16 during staging. Bt_* are [n][k] bf16.
__global__ __launch_bounds__(256) void gemm_mfma(
    const float* __restrict__ A, const unsigned short* __restrict__ Bt_hi,
    const unsigned short* __restrict__ Bt_lo, float* __restrict__ C, int M) {
  __shared__ __align__(16) unsigned short As_hi[128][72];
  __shared__ __align__(16) unsigned short As_lo[128][72];
  __shared__ __align__(16) unsigned short Bs_hi[128][72];
  __shared__ __align__(16) unsigned short Bs_lo[128][72];
  const int tid = threadIdx.x;
  const int lane = tid & 63;
  const int wave = tid >> 6;
  const int wr = wave >> 1, wc = wave & 1;
  const int bm = blockIdx.x * 128;
  const int bn = blockIdx.y * 128;

  f32x4 acc[4][4];
#pragma unroll
  for (int i = 0; i < 4; ++i)
#pragma unroll
    for (int j = 0; j < 4; ++j) acc[i][j] = (f32x4){0.f, 0.f, 0.f, 0.f};

  for (int kc = 0; kc < 256; kc += 64) {
    // stage A: 128 rows x 64 k, f32 -> bf16 hi/lo
#pragma unroll
    for (int i = 0; i < 8; ++i) {
      int idx = tid + i * 256;
      int r = idx >> 4;
      int c4 = (idx & 15) << 2;
      int row = bm + r;
      float4 v = make_float4(0.f, 0.f, 0.f, 0.f);
      if (row < M) v = *(const float4*)(A + (size_t)row * 256 + kc + c4);
      ushort4 h, l;
      split_bf16(v.x, h.x, l.x);
      split_bf16(v.y, h.y, l.y);
      split_bf16(v.z, h.z, l.z);
      split_bf16(v.w, h.w, l.w);
      *(ushort4*)&As_hi[r][c4] = h;
      *(ushort4*)&As_lo[r][c4] = l;
    }
    // stage B: 128 n-rows x 64 k, straight bf16 copies
#pragma unroll
    for (int i = 0; i < 4; ++i) {
      int idx = tid + i * 256;
      int r = idx >> 3;
      int c8 = (idx & 7) << 3;
      *(us8*)&Bs_hi[r][c8] = *(const us8*)(Bt_hi + (size_t)(bn + r) * 256 + kc + c8);
      *(us8*)&Bs_lo[r][c8] = *(const us8*)(Bt_lo + (size_t)(bn + r) * 256 + kc + c8);
    }
    __syncthreads();
#pragma unroll
    for (int ks = 0; ks < 64; ks += 32) {
      const int kr = ks + ((lane >> 4) << 3);
      bf16x8 ah[4], al[4], bh[4], bl[4];
#pragma unroll
      for (int f = 0; f < 4; ++f) {
        int ar = wr * 64 + f * 16 + (lane & 15);
        int br = wc * 64 + f * 16 + (lane & 15);
        BfCast c0, c1, c2, c3;
        c0.u = *(const us8*)&As_hi[ar][kr]; ah[f] = c0.b;
        c1.u = *(const us8*)&As_lo[ar][kr]; al[f] = c1.b;
        c2.u = *(const us8*)&Bs_hi[br][kr]; bh[f] = c2.b;
        c3.u = *(const us8*)&Bs_lo[br][kr]; bl[f] = c3.b;
      }
#pragma unroll
      for (int i = 0; i < 4; ++i)
#pragma unroll
        for (int j = 0; j < 4; ++j) {
          acc[i][j] = __builtin_amdgcn_mfma_f32_16x16x32_bf16(ah[i], bh[j], acc[i][j], 0, 0, 0);
          acc[i][j] = __builtin_amdgcn_mfma_f32_16x16x32_bf16(al[i], bh[j], acc[i][j], 0, 0, 0);
          acc[i][j] = __builtin_amdgcn_mfma_f32_16x16x32_bf16(ah[i], bl[j], acc[i][j], 0, 0, 0);
        }
    }
    __syncthreads();
  }
  // epilogue: C[m][n], m=(lane>>4)*4+reg, n=lane&15 within each 16x16 frag
#pragma unroll
  for (int i = 0; i < 4; ++i) {
#pragma unroll
    for (int r = 0; r < 4; ++r) {
      int row = bm + wr * 64 + i * 16 + ((lane >> 4) << 2) + r;
      if (row < M) {
#pragma unroll
        for (int j = 0; j < 4; ++j)
          C[(size_t)row * 256 + bn + wc * 64 + j * 16 + (lane & 15)] = acc[i][j][r];
      }
    }
  }
}

// ---------------- attention coefficients: a_src/a_dst [N,4] -------------------
__global__ __launch_bounds__(256) void attn_ab(
    const float* __restrict__ h, const float* __restrict__ att_s,
    const float* __restrict__ att_d, float* __restrict__ a_s,
    float* __restrict__ a_d, int N_) {
  const int lane = threadIdx.x & 63;
  const int head = threadIdx.x >> 6;  // 4 waves = 4 heads
  const float ws_ = att_s[head * 64 + lane];
  const float wd_ = att_d[head * 64 + lane];
  int n0 = blockIdx.x * 8;
  int n1 = min(n0 + 8, N_);
  for (int n = n0; n < n1; ++n) {
    float v = h[(size_t)n * 256 + head * 64 + lane];
    float ps = v * ws_, pd = v * wd_;
#pragma unroll
    for (int off = 32; off > 0; off >>= 1) {
      ps += __shfl_xor(ps, off);
      pd += __shfl_xor(pd, off);
    }
    if (lane == 0) { a_s[n * 4 + head] = ps; a_d[n * 4 + head] = pd; }
  }
}

// ---------------- misc init ---------------------------------------------------
__global__ void init_misc(int* __restrict__ count, float* __restrict__ pooled,
                          int N_, int G_) {
  int t = blockIdx.x * 256 + threadIdx.x;
  if (t < N_) count[t] = 1;                 // self loop
  if (t < G_ * 256) pooled[t] = NEG_INF;
}

// ---------------- CSR build ----------------------------------------------------
__global__ void hist_k(const int* __restrict__ dst, int* __restrict__ count, int E_) {
  int t = blockIdx.x * 256 + threadIdx.x;
  if (t < E_) atomicAdd(&count[dst[t]], 1);
}

// 3-phase parallel exclusive scan of count[0..N) -> rowptr/nxt, SCB elems/block
#define SCB 1024

__global__ __launch_bounds__(256) void scan_phaseA(
    const int* __restrict__ count, int* __restrict__ bsum, int N_) {
  int t = threadIdx.x;
  int base = blockIdx.x * SCB + t * 4;
  int s = 0;
  if (base + 3 < N_) {
    int4 v = *(const int4*)(count + base);
    s = v.x + v.y + v.z + v.w;
  } else {
#pragma unroll
    for (int k = 0; k < 4; ++k) if (base + k < N_) s += count[base + k];
  }
#pragma unroll
  for (int off = 32; off > 0; off >>= 1) s += __shfl_xor(s, off);
  __shared__ int red[4];
  int wave = t >> 6, lane = t & 63;
  if (lane == 0) red[wave] = s;
  __syncthreads();
  if (t == 0) bsum[blockIdx.x] = red[0] + red[1] + red[2] + red[3];
}

__global__ __launch_bounds__(256) void scan_phaseB(
    const int* __restrict__ bsum, int* __restrict__ boff, int nb) {
  __shared__ int tmp[256];
  int t = threadIdx.x;
  int v = (t < nb) ? bsum[t] : 0;
  tmp[t] = v;
  __syncthreads();
  for (int off = 1; off < 256; off <<= 1) {
    int u = (t >= off) ? tmp[t - off] : 0;
    __syncthreads();
    tmp[t] += u;
    __syncthreads();
  }
  if (t < nb) boff[t] = tmp[t] - v;  // exclusive
  if (t == 0) boff[nb] = tmp[255];   // grand total
}

__global__ __launch_bounds__(256) void scan_phaseC(
    const int* __restrict__ count, const int* __restrict__ boff,
    int* __restrict__ rowptr, int* __restrict__ nxt, int N_, int nb) {
  __shared__ int tmp[256];
  int t = threadIdx.x;
  int base = blockIdx.x * SCB + t * 4;
  int4 v = make_int4(0, 0, 0, 0);
  if (base + 3 < N_) {
    v = *(const int4*)(count + base);
  } else {
    if (base + 0 < N_) v.x = count[base + 0];
    if (base + 1 < N_) v.y = count[base + 1];
    if (base + 2 < N_) v.z = count[base + 2];
  }
  int s = v.x + v.y + v.z + v.w;
  tmp[t] = s;
  __syncthreads();
  for (int off = 1; off < 256; off <<= 1) {
    int u = (t >= off) ? tmp[t - off] : 0;
    __syncthreads();
    tmp[t] += u;
    __syncthreads();
  }
  int run = boff[blockIdx.x] + tmp[t] - s;
  int4 rp;
  rp.x = run; run += v.x;
  rp.y = run; run += v.y;
  rp.z = run; run += v.z;
  rp.w = run;
  if (base + 3 < N_) {
    *(int4*)(rowptr + base) = rp;
    *(int4*)(nxt + base) = rp;
  } else {
    if (base + 0 < N_) { rowptr[base + 0] = rp.x; nxt[base + 0] = rp.x; }
    if (base + 1 < N_) { rowptr[base + 1] = rp.y; nxt[base + 1] = rp.y; }
    if (base + 2 < N_) { rowptr[base + 2] = rp.z; nxt[base + 2] = rp.z; }
  }
  if (blockIdx.x == 0 && t == 0) rowptr[N_] = boff[nb];
}

__global__ void scatter_k(const int* __restrict__ src, const int* __restrict__ dst,
                          int* __restrict__ nxt, int* __restrict__ colx,
                          int E_, int N_) {
  int t = blockIdx.x * 256 + threadIdx.x;
  if (t >= E_ + N_) return;
  int s = (t < E_) ? src[t] : (t - E_);
  int d = (t < E_) ? dst[t] : (t - E_);
  int pos = atomicAdd(&nxt[d], 1);
  colx[pos] = s;
}

// ---------------- aggregation: wave-per-node, float4 channels, fused denom ----
__global__ __launch_bounds__(256) void agg(
    const float* __restrict__ h, const int* __restrict__ rowptr,
    const int* __restrict__ colx, const float* __restrict__ a_s,
    const float* __restrict__ a_d, const float* __restrict__ bias,
    float* __restrict__ out, int N_) {
  const int wave = threadIdx.x >> 6;
  const int lane = threadIdx.x & 63;
  const int n = blockIdx.x * 4 + wave;
  if (n >= N_) return;
  const int head = lane >> 4;           // lane owns channels [4*lane, 4*lane+4)
  const float ad = a_d[n * 4 + head];
  const int e0 = rowptr[n], e1 = rowptr[n + 1];
  float4 acc = make_float4(0.f, 0.f, 0.f, 0.f);
  float dsum = 0.f;
  for (int j = e0; j < e1; ++j) {
    int s = colx[j];
    float l = a_s[s * 4 + head] + ad;
    l = l > 0.f ? l : LRELU_SLOPE * l;
    float e = __expf(l);
    dsum += e;
    float4 hv = *(const float4*)(h + (size_t)s * 256 + lane * 4);
    acc.x = fmaf(e, hv.x, acc.x);
    acc.y = fmaf(e, hv.y, acc.y);
    acc.z = fmaf(e, hv.z, acc.z);
    acc.w = fmaf(e, hv.w, acc.w);
  }
  const float inv = 1.f / (dsum + 1e-16f);
  const float4 b4 = *(const float4*)(bias + lane * 4);
  float v;
  float4 o;
  v = acc.x * inv + b4.x; o.x = v > 0.f ? v : expm1f(v);
  v = acc.y * inv + b4.y; o.y = v > 0.f ? v : expm1f(v);
  v = acc.z * inv + b4.z; o.z = v > 0.f ? v : expm1f(v);
  v = acc.w * inv + b4.w; o.w = v > 0.f ? v : expm1f(v);
  *(float4*)(out + (size_t)n * 256 + lane * 4) = o;
}

// ---------------- graph max-pool (batch is sorted) -----------------------------
#define PNB 128
__global__ __launch_bounds__(256) void pool_max(
    const float* __restrict__ h, const int* __restrict__ batch,
    float* __restrict__ pooled, int N_) {
  int c = threadIdx.x;
  int n0 = blockIdx.x * PNB;
  int n1 = min(n0 + PNB, N_);
  float run = NEG_INF;
  int g = batch[n0];
  for (int n = n0; n < n1; ++n) {
    int gn = batch[n];
    if (gn != g) {
      atomicMaxF(&pooled[(size_t)g * 256 + c], run);
      run = NEG_INF; g = gn;
    }
    run = fmaxf(run, h[(size_t)n * 256 + c]);
  }
  atomicMaxF(&pooled[(size_t)g * 256 + c], run);
}

// ---------------- head: fixup -inf, lin1 (256->128), lin2 (128->2) ------------
__global__ __launch_bounds__(128) void head_k(
    const float* __restrict__ pooled, const float* __restrict__ w1,
    const float* __restrict__ b1, const float* __restrict__ w2,
    const float* __restrict__ b2, float* __restrict__ out) {
  __shared__ float ps[256];
  __shared__ float z1[128];
  int g = blockIdx.x;
  int t = threadIdx.x;
  for (int i = t; i < 256; i += 128) {
    float v = pooled[(size_t)g * 256 + i];
    if (v < -1e37f) v = 0.f;   // empty-graph guard (isneginf -> 0)
    ps[i] = v;
  }
  __syncthreads();
  float a = b1[t];
  for (int k = 0; k < 256; ++k) a = fmaf(ps[k], w1[k * 128 + t], a);
  z1[t] = a;
  __syncthreads();
  if (t < 2) {
    float a2 = b2[t];
    for (int j = 0; j < 128; ++j) a2 = fmaf(z1[j], w2[j * 2 + t], a2);
    out[g * 2 + t] = a2;
  }
}

// ---------------- driver --------------------------------------------------------
extern "C" void kernel_launch(void* const* d_in, const int* in_sizes, int n_in,
                              void* d_out, int out_size, void* d_ws, size_t ws_size,
                              hipStream_t stream) {
  const int N = in_sizes[2];         // batch array length = #nodes
  const int E = in_sizes[1] / 2;     // edge_index is [2,E]
  const int G = out_size / 2;        // output [G,2]

  const float* x     = (const float*)d_in[0];
  const int*   ei    = (const int*)d_in[1];
  const int*   src   = ei;
  const int*   dst   = ei + E;
  const int*   batch = (const int*)d_in[2];
  const float* W1    = (const float*)d_in[3];
  const float* atts1 = (const float*)d_in[4];
  const float* attd1 = (const float*)d_in[5];
  const float* b1    = (const float*)d_in[6];
  const float* W2    = (const float*)d_in[7];
  const float* atts2 = (const float*)d_in[8];
  const float* attd2 = (const float*)d_in[9];
  const float* b2    = (const float*)d_in[10];
  const float* l1w   = (const float*)d_in[11];
  const float* l1b   = (const float*)d_in[12];
  const float* l2w   = (const float*)d_in[13];
  const float* l2b   = (const float*)d_in[14];

  uintptr_t p = (uintptr_t)d_ws;
  auto alloc = [&](size_t bytes) -> void* {
    p = (p + 255) & ~(uintptr_t)255;
    void* r = (void*)p;
    p += bytes;
    return r;
  };
  const int nb = (N + SCB - 1) / SCB;
  float* hbuf   = (float*)alloc((size_t)N * 256 * 4);
  float* fbuf   = (float*)alloc((size_t)N * 256 * 4);
  float* a_s    = (float*)alloc((size_t)N * 4 * 4);
  float* a_d    = (float*)alloc((size_t)N * 4 * 4);
  float* pooled = (float*)alloc((size_t)G * 256 * 4);
  int*   count  = (int*)alloc((size_t)N * 4);
  int*   rowptr = (int*)alloc((size_t)(N + 1) * 4);
  int*   nxt    = (int*)alloc((size_t)N * 4);
  int*   colx   = (int*)alloc((size_t)(E + N) * 4);
  int*   bsum   = (int*)alloc((size_t)nb * 4);
  int*   boff   = (int*)alloc((size_t)(nb + 1) * 4);
  unsigned short* wt1h = (unsigned short*)alloc(256 * 256 * 2);
  unsigned short* wt1l = (unsigned short*)alloc(256 * 256 * 2);
  unsigned short* wt2h = (unsigned short*)alloc(256 * 256 * 2);
  unsigned short* wt2l = (unsigned short*)alloc(256 * 256 * 2);

  dim3 blk(256);
  dim3 gemmGrid((N + 127) / 128, 2);
  int initRange = max(N, G * 256);

  // W pre-pass + CSR build (shared by both layers) + init
  conv_w<<<dim3(256, 2), blk, 0, stream>>>(W1, W2, wt1h, wt1l, wt2h, wt2l);
  init_misc<<<(initRange + 255) / 256, blk, 0, stream>>>(count, pooled, N, G);
  hist_k<<<(E + 255) / 256, blk, 0, stream>>>(dst, count, E);
  scan_phaseA<<<nb, blk, 0, stream>>>(count, bsum, N);
  scan_phaseB<<<1, blk, 0, stream>>>(bsum, boff, nb);
  scan_phaseC<<<nb, blk, 0, stream>>>(count, boff, rowptr, nxt, N, nb);
  scatter_k<<<(E + N + 255) / 256, blk, 0, stream>>>(src, dst, nxt, colx, E, N);

  // ---- layer 1
  gemm_mfma<<<gemmGrid, blk, 0, stream>>>(x, wt1h, wt1l, hbuf, N);
  attn_ab<<<(N + 7) / 8, blk, 0, stream>>>(hbuf, atts1, attd1, a_s, a_d, N);
  agg<<<(N + 3) / 4, blk, 0, stream>>>(hbuf, rowptr, colx, a_s, a_d, b1, fbuf, N);

  // ---- layer 2
  gemm_mfma<<<gemmGrid, blk, 0, stream>>>(fbuf, wt2h, wt2l, hbuf, N);
  attn_ab<<<(N + 7) / 8, blk, 0, stream>>>(hbuf, atts2, attd2, a_s, a_d, N);
  agg<<<(N + 3) / 4, blk, 0, stream>>>(hbuf, rowptr, colx, a_s, a_d, b2, fbuf, N);

  // ---- pool + head
  pool_max<<<(N + PNB - 1) / PNB, blk, 0, stream>>>(fbuf, batch, pooled, N);
  head_k<<<G, 128, 0, stream>>>(pooled, l1w, l1b, l2w, l2b, (float*)d_out);
}

// Round 5
// 352.743 us; speedup vs baseline: 2.5599x; 1.1610x over previous
//
#include <hip/hip_runtime.h>
#include <math.h>

#define LRELU_SLOPE 0.2f
#define NEG_INF __int_as_float(0xff800000)

typedef float f32x4 __attribute__((ext_vector_type(4)));
typedef __bf16 bf16x8 __attribute__((ext_vector_type(8)));
typedef unsigned short us8 __attribute__((ext_vector_type(8)));

union BfCast { us8 u; bf16x8 b; };

__device__ __forceinline__ void atomicMaxF(float* addr, float v) {
  if (v >= 0.f) atomicMax((int*)addr, __float_as_int(v));
  else atomicMin((unsigned int*)addr, (unsigned int)__float_as_int(v));
}

__device__ __forceinline__ unsigned short bf_rne(float f) {
  unsigned int u = __float_as_uint(f);
  u += 0x7FFFu + ((u >> 16) & 1u);
  return (unsigned short)(u >> 16);
}

__device__ __forceinline__ void split_bf16(float f, unsigned short& hi, unsigned short& lo) {
  hi = bf_rne(f);
  float hif = __uint_as_float(((unsigned int)hi) << 16);
  lo = bf_rne(f - hif);
}

// unpack packed bf16 pair (little-endian: .x = low ushort = even channel)
__device__ __forceinline__ float bf_lo(unsigned int u) { return __uint_as_float(u << 16); }
__device__ __forceinline__ float bf_hi(unsigned int u) { return __uint_as_float(u & 0xffff0000u); }

// ---------------- W pre-pass: transpose + split to bf16 hi/lo ------------------
__global__ void conv_w(const float* __restrict__ W1, const float* __restrict__ W2,
                       unsigned short* __restrict__ t1h, unsigned short* __restrict__ t1l,
                       unsigned short* __restrict__ t2h, unsigned short* __restrict__ t2l) {
  const float* W = blockIdx.y ? W2 : W1;
  unsigned short* th = blockIdx.y ? t2h : t1h;
  unsigned short* tl = blockIdx.y ? t2l : t1l;
  int k = blockIdx.x, n = threadIdx.x;
  float f = W[k * 256 + n];
  unsigned short hi, lo;
  split_bf16(f, hi, lo);
  th[n * 256 + k] = hi;
  tl[n * 256 + k] = lo;
}

// ---------------- GEMM: Cbf16[M,256] = A[M,256] @ B[256,256] via split-bf16 MFMA
__global__ __launch_bounds__(256) void gemm_mfma(
    const float* __restrict__ A, const unsigned short* __restrict__ Bt_hi,
    const unsigned short* __restrict__ Bt_lo, unsigned short* __restrict__ C, int M) {
  __shared__ __align__(16) unsigned short As_hi[128][72];
  __shared__ __align__(16) unsigned short As_lo[128][72];
  __shared__ __align__(16) unsigned short Bs_hi[128][72];
  __shared__ __align__(16) unsigned short Bs_lo[128][72];
  const int tid = threadIdx.x;
  const int lane = tid & 63;
  const int wave = tid >> 6;
  const int wr = wave >> 1, wc = wave & 1;
  const int bm = blockIdx.x * 128;
  const int bn = blockIdx.y * 128;

  f32x4 acc[4][4];
#pragma unroll
  for (int i = 0; i < 4; ++i)
#pragma unroll
    for (int j = 0; j < 4; ++j) acc[i][j] = (f32x4){0.f, 0.f, 0.f, 0.f};

  for (int kc = 0; kc < 256; kc += 64) {
#pragma unroll
    for (int i = 0; i < 8; ++i) {
      int idx = tid + i * 256;
      int r = idx >> 4;
      int c4 = (idx & 15) << 2;
      int row = bm + r;
      float4 v = make_float4(0.f, 0.f, 0.f, 0.f);
      if (row < M) v = *(const float4*)(A + (size_t)row * 256 + kc + c4);
      ushort4 h, l;
      split_bf16(v.x, h.x, l.x);
      split_bf16(v.y, h.y, l.y);
      split_bf16(v.z, h.z, l.z);
      split_bf16(v.w, h.w, l.w);
      *(ushort4*)&As_hi[r][c4] = h;
      *(ushort4*)&As_lo[r][c4] = l;
    }
#pragma unroll
    for (int i = 0; i < 4; ++i) {
      int idx = tid + i * 256;
      int r = idx >> 3;
      int c8 = (idx & 7) << 3;
      *(us8*)&Bs_hi[r][c8] = *(const us8*)(Bt_hi + (size_t)(bn + r) * 256 + kc + c8);
      *(us8*)&Bs_lo[r][c8] = *(const us8*)(Bt_lo + (size_t)(bn + r) * 256 + kc + c8);
    }
    __syncthreads();
#pragma unroll
    for (int ks = 0; ks < 64; ks += 32) {
      const int kr = ks + ((lane >> 4) << 3);
      bf16x8 ah[4], al[4], bh[4], bl[4];
#pragma unroll
      for (int f = 0; f < 4; ++f) {
        int ar = wr * 64 + f * 16 + (lane & 15);
        int br = wc * 64 + f * 16 + (lane & 15);
        BfCast c0, c1, c2, c3;
        c0.u = *(const us8*)&As_hi[ar][kr]; ah[f] = c0.b;
        c1.u = *(const us8*)&As_lo[ar][kr]; al[f] = c1.b;
        c2.u = *(const us8*)&Bs_hi[br][kr]; bh[f] = c2.b;
        c3.u = *(const us8*)&Bs_lo[br][kr]; bl[f] = c3.b;
      }
#pragma unroll
      for (int i = 0; i < 4; ++i)
#pragma unroll
        for (int j = 0; j < 4; ++j) {
          acc[i][j] = __builtin_amdgcn_mfma_f32_16x16x32_bf16(ah[i], bh[j], acc[i][j], 0, 0, 0);
          acc[i][j] = __builtin_amdgcn_mfma_f32_16x16x32_bf16(al[i], bh[j], acc[i][j], 0, 0, 0);
          acc[i][j] = __builtin_amdgcn_mfma_f32_16x16x32_bf16(ah[i], bl[j], acc[i][j], 0, 0, 0);
        }
    }
    __syncthreads();
  }
  // epilogue: bf16 store. m=(lane>>4)*4+reg, n=lane&15 within each 16x16 frag
#pragma unroll
  for (int i = 0; i < 4; ++i) {
#pragma unroll
    for (int r = 0; r < 4; ++r) {
      int row = bm + wr * 64 + i * 16 + ((lane >> 4) << 2) + r;
      if (row < M) {
#pragma unroll
        for (int j = 0; j < 4; ++j)
          C[(size_t)row * 256 + bn + wc * 64 + j * 16 + (lane & 15)] = bf_rne(acc[i][j][r]);
      }
    }
  }
}

// ---------------- attention coefficients from bf16 h: a_src/a_dst [N,4] -------
// 2 node-slots x 128 threads; thread k: head=k>>5, channel pair (k&31)*2
__global__ __launch_bounds__(256) void attn_ab(
    const unsigned short* __restrict__ h, const float* __restrict__ att_s,
    const float* __restrict__ att_d, float* __restrict__ a_s,
    float* __restrict__ a_d, int N_) {
  const int slot = threadIdx.x >> 7;
  const int k = threadIdx.x & 127;
  const int head = k >> 5;
  const int c2 = k & 31;
  const float2 ws2 = *(const float2*)(att_s + head * 64 + c2 * 2);
  const float2 wd2 = *(const float2*)(att_d + head * 64 + c2 * 2);
  int n0 = blockIdx.x * 16 + slot * 8;
  int n1 = min(n0 + 8, N_);
  for (int n = n0; n < n1; ++n) {
    unsigned int w = *(const unsigned int*)(h + (size_t)n * 256 + head * 64 + c2 * 2);
    float x0 = bf_lo(w), x1 = bf_hi(w);
    float ps = x0 * ws2.x + x1 * ws2.y;
    float pd = x0 * wd2.x + x1 * wd2.y;
#pragma unroll
    for (int off = 16; off > 0; off >>= 1) {
      ps += __shfl_xor(ps, off);
      pd += __shfl_xor(pd, off);
    }
    if (c2 == 0) { a_s[n * 4 + head] = ps; a_d[n * 4 + head] = pd; }
  }
}

// ---------------- misc init ---------------------------------------------------
__global__ void init_misc(int* __restrict__ count, float* __restrict__ pooled,
                          int N_, int G_) {
  int t = blockIdx.x * 256 + threadIdx.x;
  if (t < N_) count[t] = 1;                 // self loop
  if (t < G_ * 256) pooled[t] = NEG_INF;
}

// ---------------- CSR build ----------------------------------------------------
__global__ void hist_k(const int* __restrict__ dst, int* __restrict__ count, int E_) {
  int t = blockIdx.x * 256 + threadIdx.x;
  if (t < E_) atomicAdd(&count[dst[t]], 1);
}

#define SCB 1024

__global__ __launch_bounds__(256) void scan_phaseA(
    const int* __restrict__ count, int* __restrict__ bsum, int N_) {
  int t = threadIdx.x;
  int base = blockIdx.x * SCB + t * 4;
  int s = 0;
  if (base + 3 < N_) {
    int4 v = *(const int4*)(count + base);
    s = v.x + v.y + v.z + v.w;
  } else {
#pragma unroll
    for (int k = 0; k < 4; ++k) if (base + k < N_) s += count[base + k];
  }
#pragma unroll
  for (int off = 32; off > 0; off >>= 1) s += __shfl_xor(s, off);
  __shared__ int red[4];
  int wave = t >> 6, lane = t & 63;
  if (lane == 0) red[wave] = s;
  __syncthreads();
  if (t == 0) bsum[blockIdx.x] = red[0] + red[1] + red[2] + red[3];
}

__global__ __launch_bounds__(256) void scan_phaseB(
    const int* __restrict__ bsum, int* __restrict__ boff, int nb) {
  __shared__ int tmp[256];
  int t = threadIdx.x;
  int v = (t < nb) ? bsum[t] : 0;
  tmp[t] = v;
  __syncthreads();
  for (int off = 1; off < 256; off <<= 1) {
    int u = (t >= off) ? tmp[t - off] : 0;
    __syncthreads();
    tmp[t] += u;
    __syncthreads();
  }
  if (t < nb) boff[t] = tmp[t] - v;  // exclusive
  if (t == 0) boff[nb] = tmp[255];   // grand total
}

__global__ __launch_bounds__(256) void scan_phaseC(
    const int* __restrict__ count, const int* __restrict__ boff,
    int* __restrict__ rowptr, int* __restrict__ nxt, int N_, int nb) {
  __shared__ int tmp[256];
  int t = threadIdx.x;
  int base = blockIdx.x * SCB + t * 4;
  int4 v = make_int4(0, 0, 0, 0);
  if (base + 3 < N_) {
    v = *(const int4*)(count + base);
  } else {
    if (base + 0 < N_) v.x = count[base + 0];
    if (base + 1 < N_) v.y = count[base + 1];
    if (base + 2 < N_) v.z = count[base + 2];
  }
  int s = v.x + v.y + v.z + v.w;
  tmp[t] = s;
  __syncthreads();
  for (int off = 1; off < 256; off <<= 1) {
    int u = (t >= off) ? tmp[t - off] : 0;
    __syncthreads();
    tmp[t] += u;
    __syncthreads();
  }
  int run = boff[blockIdx.x] + tmp[t] - s;
  int4 rp;
  rp.x = run; run += v.x;
  rp.y = run; run += v.y;
  rp.z = run; run += v.z;
  rp.w = run;
  if (base + 3 < N_) {
    *(int4*)(rowptr + base) = rp;
    *(int4*)(nxt + base) = rp;
  } else {
    if (base + 0 < N_) { rowptr[base + 0] = rp.x; nxt[base + 0] = rp.x; }
    if (base + 1 < N_) { rowptr[base + 1] = rp.y; nxt[base + 1] = rp.y; }
    if (base + 2 < N_) { rowptr[base + 2] = rp.z; nxt[base + 2] = rp.z; }
  }
  if (blockIdx.x == 0 && t == 0) rowptr[N_] = boff[nb];
}

__global__ void scatter_k(const int* __restrict__ src, const int* __restrict__ dst,
                          int* __restrict__ nxt, int* __restrict__ colx,
                          int E_, int N_) {
  int t = blockIdx.x * 256 + threadIdx.x;
  if (t >= E_ + N_) return;
  int s = (t < E_) ? src[t] : (t - E_);
  int d = (t < E_) ? dst[t] : (t - E_);
  int pos = atomicAdd(&nxt[d], 1);
  colx[pos] = s;
}

// ---------------- aggregation: wave-per-node, bf16 payload, fused denom -------
__global__ __launch_bounds__(256) void agg(
    const unsigned short* __restrict__ h, const int* __restrict__ rowptr,
    const int* __restrict__ colx, const float* __restrict__ a_s,
    const float* __restrict__ a_d, const float* __restrict__ bias,
    float* __restrict__ out, int N_) {
  const int wave = threadIdx.x >> 6;
  const int lane = threadIdx.x & 63;
  const int n = blockIdx.x * 4 + wave;
  if (n >= N_) return;
  const int head = lane >> 4;           // lane owns channels [4*lane, 4*lane+4)
  const float ad = a_d[n * 4 + head];
  const int e0 = rowptr[n], e1 = rowptr[n + 1];
  float4 acc = make_float4(0.f, 0.f, 0.f, 0.f);
  float dsum = 0.f;
  for (int j = e0; j < e1; ++j) {
    int s = colx[j];
    float l = a_s[s * 4 + head] + ad;
    l = l > 0.f ? l : LRELU_SLOPE * l;
    float e = __expf(l);
    dsum += e;
    uint2 w = *(const uint2*)(h + (size_t)s * 256 + lane * 4);
    acc.x = fmaf(e, bf_lo(w.x), acc.x);
    acc.y = fmaf(e, bf_hi(w.x), acc.y);
    acc.z = fmaf(e, bf_lo(w.y), acc.z);
    acc.w = fmaf(e, bf_hi(w.y), acc.w);
  }
  const float inv = 1.f / (dsum + 1e-16f);
  const float4 b4 = *(const float4*)(bias + lane * 4);
  float v;
  float4 o;
  v = acc.x * inv + b4.x; o.x = v > 0.f ? v : expm1f(v);
  v = acc.y * inv + b4.y; o.y = v > 0.f ? v : expm1f(v);
  v = acc.z * inv + b4.z; o.z = v > 0.f ? v : expm1f(v);
  v = acc.w * inv + b4.w; o.w = v > 0.f ? v : expm1f(v);
  *(float4*)(out + (size_t)n * 256 + lane * 4) = o;
}

// ---------------- graph max-pool (batch is sorted) -----------------------------
#define PNB 128
__global__ __launch_bounds__(256) void pool_max(
    const float* __restrict__ h, const int* __restrict__ batch,
    float* __restrict__ pooled, int N_) {
  int c = threadIdx.x;
  int n0 = blockIdx.x * PNB;
  int n1 = min(n0 + PNB, N_);
  float run = NEG_INF;
  int g = batch[n0];
  for (int n = n0; n < n1; ++n) {
    int gn = batch[n];
    if (gn != g) {
      atomicMaxF(&pooled[(size_t)g * 256 + c], run);
      run = NEG_INF; g = gn;
    }
    run = fmaxf(run, h[(size_t)n * 256 + c]);
  }
  atomicMaxF(&pooled[(size_t)g * 256 + c], run);
}

// ---------------- head: fixup -inf, lin1 (256->128), lin2 (128->2) ------------
__global__ __launch_bounds__(128) void head_k(
    const float* __restrict__ pooled, const float* __restrict__ w1,
    const float* __restrict__ b1, const float* __restrict__ w2,
    const float* __restrict__ b2, float* __restrict__ out) {
  __shared__ float ps[256];
  __shared__ float z1[128];
  int g = blockIdx.x;
  int t = threadIdx.x;
  for (int i = t; i < 256; i += 128) {
    float v = pooled[(size_t)g * 256 + i];
    if (v < -1e37f) v = 0.f;   // empty-graph guard (isneginf -> 0)
    ps[i] = v;
  }
  __syncthreads();
  float a = b1[t];
  for (int k = 0; k < 256; ++k) a = fmaf(ps[k], w1[k * 128 + t], a);
  z1[t] = a;
  __syncthreads();
  if (t < 2) {
    float a2 = b2[t];
    for (int j = 0; j < 128; ++j) a2 = fmaf(z1[j], w2[j * 2 + t], a2);
    out[g * 2 + t] = a2;
  }
}

// ---------------- driver --------------------------------------------------------
extern "C" void kernel_launch(void* const* d_in, const int* in_sizes, int n_in,
                              void* d_out, int out_size, void* d_ws, size_t ws_size,
                              hipStream_t stream) {
  const int N = in_sizes[2];         // batch array length = #nodes
  const int E = in_sizes[1] / 2;     // edge_index is [2,E]
  const int G = out_size / 2;        // output [G,2]

  const float* x     = (const float*)d_in[0];
  const int*   ei    = (const int*)d_in[1];
  const int*   src   = ei;
  const int*   dst   = ei + E;
  const int*   batch = (const int*)d_in[2];
  const float* W1    = (const float*)d_in[3];
  const float* atts1 = (const float*)d_in[4];
  const float* attd1 = (const float*)d_in[5];
  const float* b1    = (const float*)d_in[6];
  const float* W2    = (const float*)d_in[7];
  const float* atts2 = (const float*)d_in[8];
  const float* attd2 = (const float*)d_in[9];
  const float* b2    = (const float*)d_in[10];
  const float* l1w   = (const float*)d_in[11];
  const float* l1b   = (const float*)d_in[12];
  const float* l2w   = (const float*)d_in[13];
  const float* l2b   = (const float*)d_in[14];

  uintptr_t p = (uintptr_t)d_ws;
  auto alloc = [&](size_t bytes) -> void* {
    p = (p + 255) & ~(uintptr_t)255;
    void* r = (void*)p;
    p += bytes;
    return r;
  };
  const int nb = (N + SCB - 1) / SCB;
  unsigned short* hbuf = (unsigned short*)alloc((size_t)N * 256 * 2);  // bf16 h
  float* fbuf   = (float*)alloc((size_t)N * 256 * 4);
  float* a_s    = (float*)alloc((size_t)N * 4 * 4);
  float* a_d    = (float*)alloc((size_t)N * 4 * 4);
  float* pooled = (float*)alloc((size_t)G * 256 * 4);
  int*   count  = (int*)alloc((size_t)N * 4);
  int*   rowptr = (int*)alloc((size_t)(N + 1) * 4);
  int*   nxt    = (int*)alloc((size_t)N * 4);
  int*   colx   = (int*)alloc((size_t)(E + N) * 4);
  int*   bsum   = (int*)alloc((size_t)nb * 4);
  int*   boff   = (int*)alloc((size_t)(nb + 1) * 4);
  unsigned short* wt1h = (unsigned short*)alloc(256 * 256 * 2);
  unsigned short* wt1l = (unsigned short*)alloc(256 * 256 * 2);
  unsigned short* wt2h = (unsigned short*)alloc(256 * 256 * 2);
  unsigned short* wt2l = (unsigned short*)alloc(256 * 256 * 2);

  dim3 blk(256);
  dim3 gemmGrid((N + 127) / 128, 2);
  int initRange = max(N, G * 256);

  // W pre-pass + CSR build (shared by both layers) + init
  conv_w<<<dim3(256, 2), blk, 0, stream>>>(W1, W2, wt1h, wt1l, wt2h, wt2l);
  init_misc<<<(initRange + 255) / 256, blk, 0, stream>>>(count, pooled, N, G);
  hist_k<<<(E + 255) / 256, blk, 0, stream>>>(dst, count, E);
  scan_phaseA<<<nb, blk, 0, stream>>>(count, bsum, N);
  scan_phaseB<<<1, blk, 0, stream>>>(bsum, boff, nb);
  scan_phaseC<<<nb, blk, 0, stream>>>(count, boff, rowptr, nxt, N, nb);
  scatter_k<<<(E + N + 255) / 256, blk, 0, stream>>>(src, dst, nxt, colx, E, N);

  // ---- layer 1
  gemm_mfma<<<gemmGrid, blk, 0, stream>>>(x, wt1h, wt1l, hbuf, N);
  attn_ab<<<(N + 15) / 16, blk, 0, stream>>>(hbuf, atts1, attd1, a_s, a_d, N);
  agg<<<(N + 3) / 4, blk, 0, stream>>>(hbuf, rowptr, colx, a_s, a_d, b1, fbuf, N);

  // ---- layer 2
  gemm_mfma<<<gemmGrid, blk, 0, stream>>>(fbuf, wt2h, wt2l, hbuf, N);
  attn_ab<<<(N + 15) / 16, blk, 0, stream>>>(hbuf, atts2, attd2, a_s, a_d, N);
  agg<<<(N + 3) / 4, blk, 0, stream>>>(hbuf, rowptr, colx, a_s, a_d, b2, fbuf, N);

  // ---- pool + head
  pool_max<<<(N + PNB - 1) / PNB, blk, 0, stream>>>(fbuf, batch, pooled, N);
  head_k<<<G, 128, 0, stream>>>(pooled, l1w, l1b, l2w, l2b, (float*)d_out);
}

// Round 6
// 325.325 us; speedup vs baseline: 2.7757x; 1.0843x over previous
//
#include <hip/hip_runtime.h>
#include <math.h>

#define LRELU_SLOPE 0.2f
#define NEG_INF __int_as_float(0xff800000)

typedef float f32x4 __attribute__((ext_vector_type(4)));
typedef __bf16 bf16x8 __attribute__((ext_vector_type(8)));
typedef unsigned short us8 __attribute__((ext_vector_type(8)));

union BfCast { us8 u; bf16x8 b; };

__device__ __forceinline__ void atomicMaxF(float* addr, float v) {
  if (v >= 0.f) atomicMax((int*)addr, __float_as_int(v));
  else atomicMin((unsigned int*)addr, (unsigned int)__float_as_int(v));
}

__device__ __forceinline__ unsigned short bf_rne(float f) {
  unsigned int u = __float_as_uint(f);
  u += 0x7FFFu + ((u >> 16) & 1u);
  return (unsigned short)(u >> 16);
}

__device__ __forceinline__ void split_bf16(float f, unsigned short& hi, unsigned short& lo) {
  hi = bf_rne(f);
  float hif = __uint_as_float(((unsigned int)hi) << 16);
  lo = bf_rne(f - hif);
}

// unpack packed bf16 pair (little-endian: low ushort = even channel)
__device__ __forceinline__ float bf_lo(unsigned int u) { return __uint_as_float(u << 16); }
__device__ __forceinline__ float bf_hi(unsigned int u) { return __uint_as_float(u & 0xffff0000u); }

// ---------------- W pre-pass: transpose + split to bf16 hi/lo ------------------
__global__ void conv_w(const float* __restrict__ W1, const float* __restrict__ W2,
                       unsigned short* __restrict__ t1h, unsigned short* __restrict__ t1l,
                       unsigned short* __restrict__ t2h, unsigned short* __restrict__ t2l) {
  const float* W = blockIdx.y ? W2 : W1;
  unsigned short* th = blockIdx.y ? t2h : t1h;
  unsigned short* tl = blockIdx.y ? t2l : t1l;
  int k = blockIdx.x, n = threadIdx.x;
  float f = W[k * 256 + n];
  unsigned short hi, lo;
  split_bf16(f, hi, lo);
  th[n * 256 + k] = hi;
  tl[n * 256 + k] = lo;
}

// ---------------- GEMM: Cbf16[M,256] = A[M,256] @ B[256,256] via split-bf16 MFMA
__global__ __launch_bounds__(256) void gemm_mfma(
    const float* __restrict__ A, const unsigned short* __restrict__ Bt_hi,
    const unsigned short* __restrict__ Bt_lo, unsigned short* __restrict__ C, int M) {
  __shared__ __align__(16) unsigned short As_hi[128][72];
  __shared__ __align__(16) unsigned short As_lo[128][72];
  __shared__ __align__(16) unsigned short Bs_hi[128][72];
  __shared__ __align__(16) unsigned short Bs_lo[128][72];
  const int tid = threadIdx.x;
  const int lane = tid & 63;
  const int wave = tid >> 6;
  const int wr = wave >> 1, wc = wave & 1;
  const int bm = blockIdx.x * 128;
  const int bn = blockIdx.y * 128;

  f32x4 acc[4][4];
#pragma unroll
  for (int i = 0; i < 4; ++i)
#pragma unroll
    for (int j = 0; j < 4; ++j) acc[i][j] = (f32x4){0.f, 0.f, 0.f, 0.f};

  for (int kc = 0; kc < 256; kc += 64) {
#pragma unroll
    for (int i = 0; i < 8; ++i) {
      int idx = tid + i * 256;
      int r = idx >> 4;
      int c4 = (idx & 15) << 2;
      int row = bm + r;
      float4 v = make_float4(0.f, 0.f, 0.f, 0.f);
      if (row < M) v = *(const float4*)(A + (size_t)row * 256 + kc + c4);
      ushort4 h, l;
      split_bf16(v.x, h.x, l.x);
      split_bf16(v.y, h.y, l.y);
      split_bf16(v.z, h.z, l.z);
      split_bf16(v.w, h.w, l.w);
      *(ushort4*)&As_hi[r][c4] = h;
      *(ushort4*)&As_lo[r][c4] = l;
    }
#pragma unroll
    for (int i = 0; i < 4; ++i) {
      int idx = tid + i * 256;
      int r = idx >> 3;
      int c8 = (idx & 7) << 3;
      *(us8*)&Bs_hi[r][c8] = *(const us8*)(Bt_hi + (size_t)(bn + r) * 256 + kc + c8);
      *(us8*)&Bs_lo[r][c8] = *(const us8*)(Bt_lo + (size_t)(bn + r) * 256 + kc + c8);
    }
    __syncthreads();
#pragma unroll
    for (int ks = 0; ks < 64; ks += 32) {
      const int kr = ks + ((lane >> 4) << 3);
      bf16x8 ah[4], al[4], bh[4], bl[4];
#pragma unroll
      for (int f = 0; f < 4; ++f) {
        int ar = wr * 64 + f * 16 + (lane & 15);
        int br = wc * 64 + f * 16 + (lane & 15);
        BfCast c0, c1, c2, c3;
        c0.u = *(const us8*)&As_hi[ar][kr]; ah[f] = c0.b;
        c1.u = *(const us8*)&As_lo[ar][kr]; al[f] = c1.b;
        c2.u = *(const us8*)&Bs_hi[br][kr]; bh[f] = c2.b;
        c3.u = *(const us8*)&Bs_lo[br][kr]; bl[f] = c3.b;
      }
#pragma unroll
      for (int i = 0; i < 4; ++i)
#pragma unroll
        for (int j = 0; j < 4; ++j) {
          acc[i][j] = __builtin_amdgcn_mfma_f32_16x16x32_bf16(ah[i], bh[j], acc[i][j], 0, 0, 0);
          acc[i][j] = __builtin_amdgcn_mfma_f32_16x16x32_bf16(al[i], bh[j], acc[i][j], 0, 0, 0);
          acc[i][j] = __builtin_amdgcn_mfma_f32_16x16x32_bf16(ah[i], bl[j], acc[i][j], 0, 0, 0);
        }
    }
    __syncthreads();
  }
  // epilogue: bf16 store. m=(lane>>4)*4+reg, n=lane&15 within each 16x16 frag
#pragma unroll
  for (int i = 0; i < 4; ++i) {
#pragma unroll
    for (int r = 0; r < 4; ++r) {
      int row = bm + wr * 64 + i * 16 + ((lane >> 4) << 2) + r;
      if (row < M) {
#pragma unroll
        for (int j = 0; j < 4; ++j)
          C[(size_t)row * 256 + bn + wc * 64 + j * 16 + (lane & 15)] = bf_rne(acc[i][j][r]);
      }
    }
  }
}

// ---------------- attention coefficients from bf16 h: a_src/a_dst [N,4] -------
__global__ __launch_bounds__(256) void attn_ab(
    const unsigned short* __restrict__ h, const float* __restrict__ att_s,
    const float* __restrict__ att_d, float* __restrict__ a_s,
    float* __restrict__ a_d, int N_) {
  const int slot = threadIdx.x >> 7;
  const int k = threadIdx.x & 127;
  const int head = k >> 5;
  const int c2 = k & 31;
  const float2 ws2 = *(const float2*)(att_s + head * 64 + c2 * 2);
  const float2 wd2 = *(const float2*)(att_d + head * 64 + c2 * 2);
  int n0 = blockIdx.x * 16 + slot * 8;
  int n1 = min(n0 + 8, N_);
  for (int n = n0; n < n1; ++n) {
    unsigned int w = *(const unsigned int*)(h + (size_t)n * 256 + head * 64 + c2 * 2);
    float x0 = bf_lo(w), x1 = bf_hi(w);
    float ps = x0 * ws2.x + x1 * ws2.y;
    float pd = x0 * wd2.x + x1 * wd2.y;
#pragma unroll
    for (int off = 16; off > 0; off >>= 1) {
      ps += __shfl_xor(ps, off);
      pd += __shfl_xor(pd, off);
    }
    if (c2 == 0) { a_s[n * 4 + head] = ps; a_d[n * 4 + head] = pd; }
  }
}

// ---------------- misc init ---------------------------------------------------
__global__ void init_misc(int* __restrict__ count, float* __restrict__ pooled,
                          int N_, int G_) {
  int t = blockIdx.x * 256 + threadIdx.x;
  if (t < N_) count[t] = 1;                 // self loop
  if (t < G_ * 256) pooled[t] = NEG_INF;
}

// ---------------- CSR build ----------------------------------------------------
__global__ void hist_k(const int* __restrict__ dst, int* __restrict__ count, int E_) {
  int t = blockIdx.x * 256 + threadIdx.x;
  if (t < E_) atomicAdd(&count[dst[t]], 1);
}

#define SCB 1024

__global__ __launch_bounds__(256) void scan_phaseA(
    const int* __restrict__ count, int* __restrict__ bsum, int N_) {
  int t = threadIdx.x;
  int base = blockIdx.x * SCB + t * 4;
  int s = 0;
  if (base + 3 < N_) {
    int4 v = *(const int4*)(count + base);
    s = v.x + v.y + v.z + v.w;
  } else {
#pragma unroll
    for (int k = 0; k < 4; ++k) if (base + k < N_) s += count[base + k];
  }
#pragma unroll
  for (int off = 32; off > 0; off >>= 1) s += __shfl_xor(s, off);
  __shared__ int red[4];
  int wave = t >> 6, lane = t & 63;
  if (lane == 0) red[wave] = s;
  __syncthreads();
  if (t == 0) bsum[blockIdx.x] = red[0] + red[1] + red[2] + red[3];
}

__global__ __launch_bounds__(256) void scan_phaseB(
    const int* __restrict__ bsum, int* __restrict__ boff, int nb) {
  __shared__ int tmp[256];
  int t = threadIdx.x;
  int v = (t < nb) ? bsum[t] : 0;
  tmp[t] = v;
  __syncthreads();
  for (int off = 1; off < 256; off <<= 1) {
    int u = (t >= off) ? tmp[t - off] : 0;
    __syncthreads();
    tmp[t] += u;
    __syncthreads();
  }
  if (t < nb) boff[t] = tmp[t] - v;  // exclusive
  if (t == 0) boff[nb] = tmp[255];   // grand total
}

__global__ __launch_bounds__(256) void scan_phaseC(
    const int* __restrict__ count, const int* __restrict__ boff,
    int* __restrict__ rowptr, int* __restrict__ nxt, int N_, int nb) {
  __shared__ int tmp[256];
  int t = threadIdx.x;
  int base = blockIdx.x * SCB + t * 4;
  int4 v = make_int4(0, 0, 0, 0);
  if (base + 3 < N_) {
    v = *(const int4*)(count + base);
  } else {
    if (base + 0 < N_) v.x = count[base + 0];
    if (base + 1 < N_) v.y = count[base + 1];
    if (base + 2 < N_) v.z = count[base + 2];
  }
  int s = v.x + v.y + v.z + v.w;
  tmp[t] = s;
  __syncthreads();
  for (int off = 1; off < 256; off <<= 1) {
    int u = (t >= off) ? tmp[t - off] : 0;
    __syncthreads();
    tmp[t] += u;
    __syncthreads();
  }
  int run = boff[blockIdx.x] + tmp[t] - s;
  int4 rp;
  rp.x = run; run += v.x;
  rp.y = run; run += v.y;
  rp.z = run; run += v.z;
  rp.w = run;
  if (base + 3 < N_) {
    *(int4*)(rowptr + base) = rp;
    *(int4*)(nxt + base) = rp;
  } else {
    if (base + 0 < N_) { rowptr[base + 0] = rp.x; nxt[base + 0] = rp.x; }
    if (base + 1 < N_) { rowptr[base + 1] = rp.y; nxt[base + 1] = rp.y; }
    if (base + 2 < N_) { rowptr[base + 2] = rp.z; nxt[base + 2] = rp.z; }
  }
  if (blockIdx.x == 0 && t == 0) rowptr[N_] = boff[nb];
}

__global__ void scatter_k(const int* __restrict__ src, const int* __restrict__ dst,
                          int* __restrict__ nxt, int* __restrict__ colx,
                          int* __restrict__ rowx, int E_, int N_) {
  int t = blockIdx.x * 256 + threadIdx.x;
  if (t >= E_ + N_) return;
  int s = (t < E_) ? src[t] : (t - E_);
  int d = (t < E_) ? dst[t] : (t - E_);
  int pos = atomicAdd(&nxt[d], 1);
  colx[pos] = s;
  rowx[pos] = d;
}

// ---------------- per-slot softmax weights: ew[j][4] ---------------------------
__global__ __launch_bounds__(256) void edge_w(
    const int* __restrict__ colx, const int* __restrict__ rowx,
    const float* __restrict__ a_s, const float* __restrict__ a_d,
    float* __restrict__ ew, int T) {
  int t = blockIdx.x * 256 + threadIdx.x;
  if (t >= T) return;
  int s = colx[t], d = rowx[t];
  float4 as4 = *(const float4*)(a_s + (size_t)s * 4);
  float4 ad4 = *(const float4*)(a_d + (size_t)d * 4);
  float l;
  float4 w;
  l = as4.x + ad4.x; l = l > 0.f ? l : LRELU_SLOPE * l; w.x = __expf(l);
  l = as4.y + ad4.y; l = l > 0.f ? l : LRELU_SLOPE * l; w.y = __expf(l);
  l = as4.z + ad4.z; l = l > 0.f ? l : LRELU_SLOPE * l; w.z = __expf(l);
  l = as4.w + ad4.w; l = l > 0.f ? l : LRELU_SLOPE * l; w.w = __expf(l);
  *(float4*)(ew + (size_t)t * 4) = w;
}

// ---------------- aggregation: wave-per-node, 4x-unrolled gather loop ---------
__global__ __launch_bounds__(256) void agg(
    const unsigned short* __restrict__ h, const int* __restrict__ rowptr,
    const int* __restrict__ colx, const float* __restrict__ ew,
    const float* __restrict__ bias, float* __restrict__ out, int N_) {
  const int wave = threadIdx.x >> 6;
  const int lane = threadIdx.x & 63;
  const int n = blockIdx.x * 4 + wave;
  if (n >= N_) return;
  const int head = lane >> 4;           // lane owns channels [4*lane, 4*lane+4)
  const size_t coff = (size_t)lane * 4;
  const int e0 = rowptr[n], e1 = rowptr[n + 1];
  float4 acc = make_float4(0.f, 0.f, 0.f, 0.f);
  float dsum = 0.f;
  int j = e0;
  for (; j + 4 <= e1; j += 4) {
    int s0 = colx[j + 0], s1 = colx[j + 1], s2 = colx[j + 2], s3 = colx[j + 3];
    float w0 = ew[(size_t)(j + 0) * 4 + head];
    float w1 = ew[(size_t)(j + 1) * 4 + head];
    float w2 = ew[(size_t)(j + 2) * 4 + head];
    float w3 = ew[(size_t)(j + 3) * 4 + head];
    uint2 g0 = *(const uint2*)(h + (size_t)s0 * 256 + coff);
    uint2 g1 = *(const uint2*)(h + (size_t)s1 * 256 + coff);
    uint2 g2 = *(const uint2*)(h + (size_t)s2 * 256 + coff);
    uint2 g3 = *(const uint2*)(h + (size_t)s3 * 256 + coff);
    dsum += (w0 + w1) + (w2 + w3);
    acc.x = fmaf(w0, bf_lo(g0.x), acc.x); acc.y = fmaf(w0, bf_hi(g0.x), acc.y);
    acc.z = fmaf(w0, bf_lo(g0.y), acc.z); acc.w = fmaf(w0, bf_hi(g0.y), acc.w);
    acc.x = fmaf(w1, bf_lo(g1.x), acc.x); acc.y = fmaf(w1, bf_hi(g1.x), acc.y);
    acc.z = fmaf(w1, bf_lo(g1.y), acc.z); acc.w = fmaf(w1, bf_hi(g1.y), acc.w);
    acc.x = fmaf(w2, bf_lo(g2.x), acc.x); acc.y = fmaf(w2, bf_hi(g2.x), acc.y);
    acc.z = fmaf(w2, bf_lo(g2.y), acc.z); acc.w = fmaf(w2, bf_hi(g2.y), acc.w);
    acc.x = fmaf(w3, bf_lo(g3.x), acc.x); acc.y = fmaf(w3, bf_hi(g3.x), acc.y);
    acc.z = fmaf(w3, bf_lo(g3.y), acc.z); acc.w = fmaf(w3, bf_hi(g3.y), acc.w);
  }
  for (; j < e1; ++j) {
    int s = colx[j];
    float w = ew[(size_t)j * 4 + head];
    uint2 g = *(const uint2*)(h + (size_t)s * 256 + coff);
    dsum += w;
    acc.x = fmaf(w, bf_lo(g.x), acc.x); acc.y = fmaf(w, bf_hi(g.x), acc.y);
    acc.z = fmaf(w, bf_lo(g.y), acc.z); acc.w = fmaf(w, bf_hi(g.y), acc.w);
  }
  const float inv = 1.f / (dsum + 1e-16f);
  const float4 b4 = *(const float4*)(bias + coff);
  float v;
  float4 o;
  v = acc.x * inv + b4.x; o.x = v > 0.f ? v : expm1f(v);
  v = acc.y * inv + b4.y; o.y = v > 0.f ? v : expm1f(v);
  v = acc.z * inv + b4.z; o.z = v > 0.f ? v : expm1f(v);
  v = acc.w * inv + b4.w; o.w = v > 0.f ? v : expm1f(v);
  *(float4*)(out + (size_t)n * 256 + coff) = o;
}

// ---------------- graph max-pool (batch is sorted) -----------------------------
#define PNB 128
__global__ __launch_bounds__(256) void pool_max(
    const float* __restrict__ h, const int* __restrict__ batch,
    float* __restrict__ pooled, int N_) {
  int c = threadIdx.x;
  int n0 = blockIdx.x * PNB;
  int n1 = min(n0 + PNB, N_);
  float run = NEG_INF;
  int g = batch[n0];
  for (int n = n0; n < n1; ++n) {
    int gn = batch[n];
    if (gn != g) {
      atomicMaxF(&pooled[(size_t)g * 256 + c], run);
      run = NEG_INF; g = gn;
    }
    run = fmaxf(run, h[(size_t)n * 256 + c]);
  }
  atomicMaxF(&pooled[(size_t)g * 256 + c], run);
}

// ---------------- head: fixup -inf, lin1 (256->128), lin2 (128->2) ------------
__global__ __launch_bounds__(128) void head_k(
    const float* __restrict__ pooled, const float* __restrict__ w1,
    const float* __restrict__ b1, const float* __restrict__ w2,
    const float* __restrict__ b2, float* __restrict__ out) {
  __shared__ float ps[256];
  __shared__ float z1[128];
  int g = blockIdx.x;
  int t = threadIdx.x;
  for (int i = t; i < 256; i += 128) {
    float v = pooled[(size_t)g * 256 + i];
    if (v < -1e37f) v = 0.f;   // empty-graph guard (isneginf -> 0)
    ps[i] = v;
  }
  __syncthreads();
  float a = b1[t];
  for (int k = 0; k < 256; ++k) a = fmaf(ps[k], w1[k * 128 + t], a);
  z1[t] = a;
  __syncthreads();
  if (t < 2) {
    float a2 = b2[t];
    for (int j = 0; j < 128; ++j) a2 = fmaf(z1[j], w2[j * 2 + t], a2);
    out[g * 2 + t] = a2;
  }
}

// ---------------- driver --------------------------------------------------------
extern "C" void kernel_launch(void* const* d_in, const int* in_sizes, int n_in,
                              void* d_out, int out_size, void* d_ws, size_t ws_size,
                              hipStream_t stream) {
  const int N = in_sizes[2];         // batch array length = #nodes
  const int E = in_sizes[1] / 2;     // edge_index is [2,E]
  const int G = out_size / 2;        // output [G,2]
  const int T = E + N;               // CSR slots (incl. self loops)

  const float* x     = (const float*)d_in[0];
  const int*   ei    = (const int*)d_in[1];
  const int*   src   = ei;
  const int*   dst   = ei + E;
  const int*   batch = (const int*)d_in[2];
  const float* W1    = (const float*)d_in[3];
  const float* atts1 = (const float*)d_in[4];
  const float* attd1 = (const float*)d_in[5];
  const float* b1    = (const float*)d_in[6];
  const float* W2    = (const float*)d_in[7];
  const float* atts2 = (const float*)d_in[8];
  const float* attd2 = (const float*)d_in[9];
  const float* b2    = (const float*)d_in[10];
  const float* l1w   = (const float*)d_in[11];
  const float* l1b   = (const float*)d_in[12];
  const float* l2w   = (const float*)d_in[13];
  const float* l2b   = (const float*)d_in[14];

  uintptr_t p = (uintptr_t)d_ws;
  auto alloc = [&](size_t bytes) -> void* {
    p = (p + 255) & ~(uintptr_t)255;
    void* r = (void*)p;
    p += bytes;
    return r;
  };
  const int nb = (N + SCB - 1) / SCB;
  unsigned short* hbuf = (unsigned short*)alloc((size_t)N * 256 * 2);  // bf16 h
  float* fbuf   = (float*)alloc((size_t)N * 256 * 4);
  float* a_s    = (float*)alloc((size_t)N * 4 * 4);
  float* a_d    = (float*)alloc((size_t)N * 4 * 4);
  float* pooled = (float*)alloc((size_t)G * 256 * 4);
  int*   count  = (int*)alloc((size_t)N * 4);
  int*   rowptr = (int*)alloc((size_t)(N + 1) * 4);
  int*   nxt    = (int*)alloc((size_t)N * 4);
  int*   colx   = (int*)alloc((size_t)T * 4);
  int*   rowx   = (int*)alloc((size_t)T * 4);
  float* ew     = (float*)alloc((size_t)T * 4 * 4);
  int*   bsum   = (int*)alloc((size_t)nb * 4);
  int*   boff   = (int*)alloc((size_t)(nb + 1) * 4);
  unsigned short* wt1h = (unsigned short*)alloc(256 * 256 * 2);
  unsigned short* wt1l = (unsigned short*)alloc(256 * 256 * 2);
  unsigned short* wt2h = (unsigned short*)alloc(256 * 256 * 2);
  unsigned short* wt2l = (unsigned short*)alloc(256 * 256 * 2);

  dim3 blk(256);
  dim3 gemmGrid((N + 127) / 128, 2);
  int initRange = max(N, G * 256);

  // W pre-pass + CSR build (shared by both layers) + init
  conv_w<<<dim3(256, 2), blk, 0, stream>>>(W1, W2, wt1h, wt1l, wt2h, wt2l);
  init_misc<<<(initRange + 255) / 256, blk, 0, stream>>>(count, pooled, N, G);
  hist_k<<<(E + 255) / 256, blk, 0, stream>>>(dst, count, E);
  scan_phaseA<<<nb, blk, 0, stream>>>(count, bsum, N);
  scan_phaseB<<<1, blk, 0, stream>>>(bsum, boff, nb);
  scan_phaseC<<<nb, blk, 0, stream>>>(count, boff, rowptr, nxt, N, nb);
  scatter_k<<<(T + 255) / 256, blk, 0, stream>>>(src, dst, nxt, colx, rowx, E, N);

  // ---- layer 1
  gemm_mfma<<<gemmGrid, blk, 0, stream>>>(x, wt1h, wt1l, hbuf, N);
  attn_ab<<<(N + 15) / 16, blk, 0, stream>>>(hbuf, atts1, attd1, a_s, a_d, N);
  edge_w<<<(T + 255) / 256, blk, 0, stream>>>(colx, rowx, a_s, a_d, ew, T);
  agg<<<(N + 3) / 4, blk, 0, stream>>>(hbuf, rowptr, colx, ew, b1, fbuf, N);

  // ---- layer 2
  gemm_mfma<<<gemmGrid, blk, 0, stream>>>(fbuf, wt2h, wt2l, hbuf, N);
  attn_ab<<<(N + 15) / 16, blk, 0, stream>>>(hbuf, atts2, attd2, a_s, a_d, N);
  edge_w<<<(T + 255) / 256, blk, 0, stream>>>(colx, rowx, a_s, a_d, ew, T);
  agg<<<(N + 3) / 4, blk, 0, stream>>>(hbuf, rowptr, colx, ew, b2, fbuf, N);

  // ---- pool + head
  pool_max<<<(N + PNB - 1) / PNB, blk, 0, stream>>>(fbuf, batch, pooled, N);
  head_k<<<G, 128, 0, stream>>>(pooled, l1w, l1b, l2w, l2b, (float*)d_out);
}

// Round 7
// 318.739 us; speedup vs baseline: 2.8330x; 1.0207x over previous
//
#include <hip/hip_runtime.h>
#include <math.h>

#define LRELU_SLOPE 0.2f
#define NEG_INF __int_as_float(0xff800000)

typedef float f32x4 __attribute__((ext_vector_type(4)));
typedef __bf16 bf16x8 __attribute__((ext_vector_type(8)));
typedef unsigned short us8 __attribute__((ext_vector_type(8)));

union BfCast { us8 u; bf16x8 b; };

__device__ __forceinline__ void atomicMaxF(float* addr, float v) {
  if (v >= 0.f) atomicMax((int*)addr, __float_as_int(v));
  else atomicMin((unsigned int*)addr, (unsigned int)__float_as_int(v));
}

__device__ __forceinline__ unsigned short bf_rne(float f) {
  unsigned int u = __float_as_uint(f);
  u += 0x7FFFu + ((u >> 16) & 1u);
  return (unsigned short)(u >> 16);
}

__device__ __forceinline__ void split_bf16(float f, unsigned short& hi, unsigned short& lo) {
  hi = bf_rne(f);
  float hif = __uint_as_float(((unsigned int)hi) << 16);
  lo = bf_rne(f - hif);
}

// unpack packed bf16 pair (little-endian: low ushort = even channel)
__device__ __forceinline__ float bf_lo(unsigned int u) { return __uint_as_float(u << 16); }
__device__ __forceinline__ float bf_hi(unsigned int u) { return __uint_as_float(u & 0xffff0000u); }
__device__ __forceinline__ float bf_f(unsigned short u) { return __uint_as_float(((unsigned int)u) << 16); }

// async global->LDS, 16B per lane; LDS dest must be the wave-uniform base
__device__ __forceinline__ void async_copy16(const unsigned short* g, unsigned short* l) {
  __builtin_amdgcn_global_load_lds(
      (const __attribute__((address_space(1))) void*)g,
      (__attribute__((address_space(3))) void*)l, 16, 0, 0);
}

// ---------------- W pre-pass: transpose + split to bf16 hi/lo ------------------
__global__ void conv_w(const float* __restrict__ W1, const float* __restrict__ W2,
                       unsigned short* __restrict__ t1h, unsigned short* __restrict__ t1l,
                       unsigned short* __restrict__ t2h, unsigned short* __restrict__ t2l) {
  const float* W = blockIdx.y ? W2 : W1;
  unsigned short* th = blockIdx.y ? t2h : t1h;
  unsigned short* tl = blockIdx.y ? t2l : t1l;
  int k = blockIdx.x, n = threadIdx.x;
  float f = W[k * 256 + n];
  unsigned short hi, lo;
  split_bf16(f, hi, lo);
  th[n * 256 + k] = hi;
  tl[n * 256 + k] = lo;
}

// ---------------- X pre-pass: split f32 -> bf16 hi/lo --------------------------
__global__ __launch_bounds__(256) void conv_x(
    const float* __restrict__ x, unsigned short* __restrict__ xh,
    unsigned short* __restrict__ xl, int total) {
  int base = (blockIdx.x * 256 + threadIdx.x) * 4;
  if (base >= total) return;
  float4 v = *(const float4*)(x + base);
  ushort4 h, l;
  split_bf16(v.x, h.x, l.x);
  split_bf16(v.y, h.y, l.y);
  split_bf16(v.z, h.z, l.z);
  split_bf16(v.w, h.w, l.w);
  *(ushort4*)(xh + base) = h;
  *(ushort4*)(xl + base) = l;
}

// ---------------- GEMM: Cbf16[M,256] = (Ah+Al) @ (Bh+Bl)^T via split-bf16 MFMA -
// A pre-split bf16 [Mpad,256]; Bt pre-split transposed [256n,256k].
// LDS linear [128][64] per matrix, XOR-swizzled (byte ^= (row&7)<<4) via
// pre-swizzled global source column + swizzled ds_read (rule #21).
__global__ __launch_bounds__(256) void gemm_mfma(
    const unsigned short* __restrict__ Ah, const unsigned short* __restrict__ Al,
    const unsigned short* __restrict__ Bh, const unsigned short* __restrict__ Bl,
    unsigned short* __restrict__ C, int M) {
  __shared__ __align__(16) unsigned short sAh[128 * 64];
  __shared__ __align__(16) unsigned short sAl[128 * 64];
  __shared__ __align__(16) unsigned short sBh[128 * 64];
  __shared__ __align__(16) unsigned short sBl[128 * 64];
  const int tid = threadIdx.x;
  const int lane = tid & 63;
  const int wave = tid >> 6;
  const int wr = wave >> 1, wc = wave & 1;
  const int bm = blockIdx.x * 128;
  const int bn = blockIdx.y * 128;

  // staging geometry: inst covers 8 rows; lane l -> row +(l>>3), col (l&7)*8,
  // global source col pre-swizzled so LDS[row][c] = G[row][c ^ ((row&7)<<3)]
  const int srow = lane >> 3;                          // 0..7
  const int scol = (((lane & 7) ^ (lane >> 3)) << 3);  // swizzled ushort col

  f32x4 acc[4][4];
#pragma unroll
  for (int i = 0; i < 4; ++i)
#pragma unroll
    for (int j = 0; j < 4; ++j) acc[i][j] = (f32x4){0.f, 0.f, 0.f, 0.f};

  for (int kc = 0; kc < 256; kc += 64) {
#pragma unroll
    for (int i = 0; i < 4; ++i) {
      const int r0 = wave * 32 + i * 8;                 // LDS/global row base
      const size_t ga = (size_t)(bm + r0 + srow) * 256 + kc + scol;
      const size_t gb = (size_t)(bn + r0 + srow) * 256 + kc + scol;
      async_copy16(Ah + ga, &sAh[r0 * 64]);
      async_copy16(Al + ga, &sAl[r0 * 64]);
      async_copy16(Bh + gb, &sBh[r0 * 64]);
      async_copy16(Bl + gb, &sBl[r0 * 64]);
    }
    __syncthreads();
#pragma unroll
    for (int ks = 0; ks < 64; ks += 32) {
      const int kbase = ks + ((lane >> 4) << 3);
      const int kx = kbase ^ ((lane & 7) << 3);  // swizzled read col (row&7 == lane&7)
      bf16x8 ah[4], al[4], bh[4], bl[4];
#pragma unroll
      for (int f = 0; f < 4; ++f) {
        int ar = wr * 64 + f * 16 + (lane & 15);
        int br = wc * 64 + f * 16 + (lane & 15);
        BfCast c0, c1, c2, c3;
        c0.u = *(const us8*)&sAh[ar * 64 + kx]; ah[f] = c0.b;
        c1.u = *(const us8*)&sAl[ar * 64 + kx]; al[f] = c1.b;
        c2.u = *(const us8*)&sBh[br * 64 + kx]; bh[f] = c2.b;
        c3.u = *(const us8*)&sBl[br * 64 + kx]; bl[f] = c3.b;
      }
#pragma unroll
      for (int i = 0; i < 4; ++i)
#pragma unroll
        for (int j = 0; j < 4; ++j) {
          acc[i][j] = __builtin_amdgcn_mfma_f32_16x16x32_bf16(ah[i], bh[j], acc[i][j], 0, 0, 0);
          acc[i][j] = __builtin_amdgcn_mfma_f32_16x16x32_bf16(al[i], bh[j], acc[i][j], 0, 0, 0);
          acc[i][j] = __builtin_amdgcn_mfma_f32_16x16x32_bf16(ah[i], bl[j], acc[i][j], 0, 0, 0);
        }
    }
    __syncthreads();
  }
  // epilogue: bf16 store. m=(lane>>4)*4+reg, n=lane&15 within each 16x16 frag
#pragma unroll
  for (int i = 0; i < 4; ++i) {
#pragma unroll
    for (int r = 0; r < 4; ++r) {
      int row = bm + wr * 64 + i * 16 + ((lane >> 4) << 2) + r;
      if (row < M) {
#pragma unroll
        for (int j = 0; j < 4; ++j)
          C[(size_t)row * 256 + bn + wc * 64 + j * 16 + (lane & 15)] = bf_rne(acc[i][j][r]);
      }
    }
  }
}

// ---------------- attention coefficients from bf16 h: a_src/a_dst [N,4] -------
__global__ __launch_bounds__(256) void attn_ab(
    const unsigned short* __restrict__ h, const float* __restrict__ att_s,
    const float* __restrict__ att_d, float* __restrict__ a_s,
    float* __restrict__ a_d, int N_) {
  const int slot = threadIdx.x >> 7;
  const int k = threadIdx.x & 127;
  const int head = k >> 5;
  const int c2 = k & 31;
  const float2 ws2 = *(const float2*)(att_s + head * 64 + c2 * 2);
  const float2 wd2 = *(const float2*)(att_d + head * 64 + c2 * 2);
  int n0 = blockIdx.x * 16 + slot * 8;
  int n1 = min(n0 + 8, N_);
  for (int n = n0; n < n1; ++n) {
    unsigned int w = *(const unsigned int*)(h + (size_t)n * 256 + head * 64 + c2 * 2);
    float x0 = bf_lo(w), x1 = bf_hi(w);
    float ps = x0 * ws2.x + x1 * ws2.y;
    float pd = x0 * wd2.x + x1 * wd2.y;
#pragma unroll
    for (int off = 16; off > 0; off >>= 1) {
      ps += __shfl_xor(ps, off);
      pd += __shfl_xor(pd, off);
    }
    if (c2 == 0) { a_s[n * 4 + head] = ps; a_d[n * 4 + head] = pd; }
  }
}

// ---------------- misc init ---------------------------------------------------
__global__ void init_misc(int* __restrict__ count, float* __restrict__ pooled,
                          int N_, int G_) {
  int t = blockIdx.x * 256 + threadIdx.x;
  if (t < N_) count[t] = 1;                 // self loop
  if (t < G_ * 256) pooled[t] = NEG_INF;
}

// ---------------- CSR build ----------------------------------------------------
__global__ void hist_k(const int* __restrict__ dst, int* __restrict__ count, int E_) {
  int t = blockIdx.x * 256 + threadIdx.x;
  if (t < E_) atomicAdd(&count[dst[t]], 1);
}

#define SCB 1024

__global__ __launch_bounds__(256) void scan_phaseA(
    const int* __restrict__ count, int* __restrict__ bsum, int N_) {
  int t = threadIdx.x;
  int base = blockIdx.x * SCB + t * 4;
  int s = 0;
  if (base + 3 < N_) {
    int4 v = *(const int4*)(count + base);
    s = v.x + v.y + v.z + v.w;
  } else {
#pragma unroll
    for (int k = 0; k < 4; ++k) if (base + k < N_) s += count[base + k];
  }
#pragma unroll
  for (int off = 32; off > 0; off >>= 1) s += __shfl_xor(s, off);
  __shared__ int red[4];
  int wave = t >> 6, lane = t & 63;
  if (lane == 0) red[wave] = s;
  __syncthreads();
  if (t == 0) bsum[blockIdx.x] = red[0] + red[1] + red[2] + red[3];
}

__global__ __launch_bounds__(256) void scan_phaseB(
    const int* __restrict__ bsum, int* __restrict__ boff, int nb) {
  __shared__ int tmp[256];
  int t = threadIdx.x;
  int v = (t < nb) ? bsum[t] : 0;
  tmp[t] = v;
  __syncthreads();
  for (int off = 1; off < 256; off <<= 1) {
    int u = (t >= off) ? tmp[t - off] : 0;
    __syncthreads();
    tmp[t] += u;
    __syncthreads();
  }
  if (t < nb) boff[t] = tmp[t] - v;  // exclusive
  if (t == 0) boff[nb] = tmp[255];   // grand total
}

__global__ __launch_bounds__(256) void scan_phaseC(
    const int* __restrict__ count, const int* __restrict__ boff,
    int* __restrict__ rowptr, int* __restrict__ nxt, int N_, int nb) {
  __shared__ int tmp[256];
  int t = threadIdx.x;
  int base = blockIdx.x * SCB + t * 4;
  int4 v = make_int4(0, 0, 0, 0);
  if (base + 3 < N_) {
    v = *(const int4*)(count + base);
  } else {
    if (base + 0 < N_) v.x = count[base + 0];
    if (base + 1 < N_) v.y = count[base + 1];
    if (base + 2 < N_) v.z = count[base + 2];
  }
  int s = v.x + v.y + v.z + v.w;
  tmp[t] = s;
  __syncthreads();
  for (int off = 1; off < 256; off <<= 1) {
    int u = (t >= off) ? tmp[t - off] : 0;
    __syncthreads();
    tmp[t] += u;
    __syncthreads();
  }
  int run = boff[blockIdx.x] + tmp[t] - s;
  int4 rp;
  rp.x = run; run += v.x;
  rp.y = run; run += v.y;
  rp.z = run; run += v.z;
  rp.w = run;
  if (base + 3 < N_) {
    *(int4*)(rowptr + base) = rp;
    *(int4*)(nxt + base) = rp;
  } else {
    if (base + 0 < N_) { rowptr[base + 0] = rp.x; nxt[base + 0] = rp.x; }
    if (base + 1 < N_) { rowptr[base + 1] = rp.y; nxt[base + 1] = rp.y; }
    if (base + 2 < N_) { rowptr[base + 2] = rp.z; nxt[base + 2] = rp.z; }
  }
  if (blockIdx.x == 0 && t == 0) rowptr[N_] = boff[nb];
}

__global__ void scatter_k(const int* __restrict__ src, const int* __restrict__ dst,
                          int* __restrict__ nxt, int* __restrict__ colx,
                          int* __restrict__ rowx, int E_, int N_) {
  int t = blockIdx.x * 256 + threadIdx.x;
  if (t >= E_ + N_) return;
  int s = (t < E_) ? src[t] : (t - E_);
  int d = (t < E_) ? dst[t] : (t - E_);
  int pos = atomicAdd(&nxt[d], 1);
  colx[pos] = s;
  rowx[pos] = d;
}

// ---------------- per-slot softmax weights: ew[j][4] ---------------------------
__global__ __launch_bounds__(256) void edge_w(
    const int* __restrict__ colx, const int* __restrict__ rowx,
    const float* __restrict__ a_s, const float* __restrict__ a_d,
    float* __restrict__ ew, int T) {
  int t = blockIdx.x * 256 + threadIdx.x;
  if (t >= T) return;
  int s = colx[t], d = rowx[t];
  float4 as4 = *(const float4*)(a_s + (size_t)s * 4);
  float4 ad4 = *(const float4*)(a_d + (size_t)d * 4);
  float l;
  float4 w;
  l = as4.x + ad4.x; l = l > 0.f ? l : LRELU_SLOPE * l; w.x = __expf(l);
  l = as4.y + ad4.y; l = l > 0.f ? l : LRELU_SLOPE * l; w.y = __expf(l);
  l = as4.z + ad4.z; l = l > 0.f ? l : LRELU_SLOPE * l; w.z = __expf(l);
  l = as4.w + ad4.w; l = l > 0.f ? l : LRELU_SLOPE * l; w.w = __expf(l);
  *(float4*)(ew + (size_t)t * 4) = w;
}

// ---------------- aggregation: wave-per-node, writes split hi/lo bf16 ---------
__global__ __launch_bounds__(256) void agg(
    const unsigned short* __restrict__ h, const int* __restrict__ rowptr,
    const int* __restrict__ colx, const float* __restrict__ ew,
    const float* __restrict__ bias, unsigned short* __restrict__ out_h,
    unsigned short* __restrict__ out_l, int N_) {
  const int wave = threadIdx.x >> 6;
  const int lane = threadIdx.x & 63;
  const int n = blockIdx.x * 4 + wave;
  if (n >= N_) return;
  const int head = lane >> 4;           // lane owns channels [4*lane, 4*lane+4)
  const size_t coff = (size_t)lane * 4;
  const int e0 = rowptr[n], e1 = rowptr[n + 1];
  float4 acc = make_float4(0.f, 0.f, 0.f, 0.f);
  float dsum = 0.f;
  int j = e0;
  for (; j + 4 <= e1; j += 4) {
    int s0 = colx[j + 0], s1 = colx[j + 1], s2 = colx[j + 2], s3 = colx[j + 3];
    float w0 = ew[(size_t)(j + 0) * 4 + head];
    float w1 = ew[(size_t)(j + 1) * 4 + head];
    float w2 = ew[(size_t)(j + 2) * 4 + head];
    float w3 = ew[(size_t)(j + 3) * 4 + head];
    uint2 g0 = *(const uint2*)(h + (size_t)s0 * 256 + coff);
    uint2 g1 = *(const uint2*)(h + (size_t)s1 * 256 + coff);
    uint2 g2 = *(const uint2*)(h + (size_t)s2 * 256 + coff);
    uint2 g3 = *(const uint2*)(h + (size_t)s3 * 256 + coff);
    dsum += (w0 + w1) + (w2 + w3);
    acc.x = fmaf(w0, bf_lo(g0.x), acc.x); acc.y = fmaf(w0, bf_hi(g0.x), acc.y);
    acc.z = fmaf(w0, bf_lo(g0.y), acc.z); acc.w = fmaf(w0, bf_hi(g0.y), acc.w);
    acc.x = fmaf(w1, bf_lo(g1.x), acc.x); acc.y = fmaf(w1, bf_hi(g1.x), acc.y);
    acc.z = fmaf(w1, bf_lo(g1.y), acc.z); acc.w = fmaf(w1, bf_hi(g1.y), acc.w);
    acc.x = fmaf(w2, bf_lo(g2.x), acc.x); acc.y = fmaf(w2, bf_hi(g2.x), acc.y);
    acc.z = fmaf(w2, bf_lo(g2.y), acc.z); acc.w = fmaf(w2, bf_hi(g2.y), acc.w);
    acc.x = fmaf(w3, bf_lo(g3.x), acc.x); acc.y = fmaf(w3, bf_hi(g3.x), acc.y);
    acc.z = fmaf(w3, bf_lo(g3.y), acc.z); acc.w = fmaf(w3, bf_hi(g3.y), acc.w);
  }
  for (; j < e1; ++j) {
    int s = colx[j];
    float w = ew[(size_t)j * 4 + head];
    uint2 g = *(const uint2*)(h + (size_t)s * 256 + coff);
    dsum += w;
    acc.x = fmaf(w, bf_lo(g.x), acc.x); acc.y = fmaf(w, bf_hi(g.x), acc.y);
    acc.z = fmaf(w, bf_lo(g.y), acc.z); acc.w = fmaf(w, bf_hi(g.y), acc.w);
  }
  const float inv = 1.f / (dsum + 1e-16f);
  const float4 b4 = *(const float4*)(bias + coff);
  float v;
  float4 o;
  v = acc.x * inv + b4.x; o.x = v > 0.f ? v : expm1f(v);
  v = acc.y * inv + b4.y; o.y = v > 0.f ? v : expm1f(v);
  v = acc.z * inv + b4.z; o.z = v > 0.f ? v : expm1f(v);
  v = acc.w * inv + b4.w; o.w = v > 0.f ? v : expm1f(v);
  ushort4 oh, ol;
  split_bf16(o.x, oh.x, ol.x);
  split_bf16(o.y, oh.y, ol.y);
  split_bf16(o.z, oh.z, ol.z);
  split_bf16(o.w, oh.w, ol.w);
  *(ushort4*)(out_h + (size_t)n * 256 + coff) = oh;
  *(ushort4*)(out_l + (size_t)n * 256 + coff) = ol;
}

// ---------------- graph max-pool from split hi/lo (batch is sorted) -----------
#define PNB 128
__global__ __launch_bounds__(128) void pool_max(
    const unsigned short* __restrict__ fh, const unsigned short* __restrict__ fl,
    const int* __restrict__ batch, float* __restrict__ pooled, int N_) {
  int c2 = threadIdx.x;               // channels 2*c2, 2*c2+1
  int n0 = blockIdx.x * PNB;
  int n1 = min(n0 + PNB, N_);
  float r0 = NEG_INF, r1 = NEG_INF;
  int g = batch[n0];
  for (int n = n0; n < n1; ++n) {
    int gn = batch[n];
    if (gn != g) {
      atomicMaxF(&pooled[(size_t)g * 256 + c2 * 2], r0);
      atomicMaxF(&pooled[(size_t)g * 256 + c2 * 2 + 1], r1);
      r0 = r1 = NEG_INF; g = gn;
    }
    unsigned int wh = *(const unsigned int*)(fh + (size_t)n * 256 + c2 * 2);
    unsigned int wl = *(const unsigned int*)(fl + (size_t)n * 256 + c2 * 2);
    r0 = fmaxf(r0, bf_lo(wh) + bf_lo(wl));
    r1 = fmaxf(r1, bf_hi(wh) + bf_hi(wl));
  }
  atomicMaxF(&pooled[(size_t)g * 256 + c2 * 2], r0);
  atomicMaxF(&pooled[(size_t)g * 256 + c2 * 2 + 1], r1);
}

// ---------------- head: fixup -inf, lin1 (256->128), lin2 (128->2) ------------
__global__ __launch_bounds__(128) void head_k(
    const float* __restrict__ pooled, const float* __restrict__ w1,
    const float* __restrict__ b1, const float* __restrict__ w2,
    const float* __restrict__ b2, float* __restrict__ out) {
  __shared__ float ps[256];
  __shared__ float z1[128];
  int g = blockIdx.x;
  int t = threadIdx.x;
  for (int i = t; i < 256; i += 128) {
    float v = pooled[(size_t)g * 256 + i];
    if (v < -1e37f) v = 0.f;   // empty-graph guard (isneginf -> 0)
    ps[i] = v;
  }
  __syncthreads();
  float a = b1[t];
  for (int k = 0; k < 256; ++k) a = fmaf(ps[k], w1[k * 128 + t], a);
  z1[t] = a;
  __syncthreads();
  if (t < 2) {
    float a2 = b2[t];
    for (int j = 0; j < 128; ++j) a2 = fmaf(z1[j], w2[j * 2 + t], a2);
    out[g * 2 + t] = a2;
  }
}

// ---------------- driver --------------------------------------------------------
extern "C" void kernel_launch(void* const* d_in, const int* in_sizes, int n_in,
                              void* d_out, int out_size, void* d_ws, size_t ws_size,
                              hipStream_t stream) {
  const int N = in_sizes[2];         // batch array length = #nodes
  const int E = in_sizes[1] / 2;     // edge_index is [2,E]
  const int G = out_size / 2;        // output [G,2]
  const int T = E + N;               // CSR slots (incl. self loops)
  const int Npad = ((N + 127) / 128) * 128;

  const float* x     = (const float*)d_in[0];
  const int*   ei    = (const int*)d_in[1];
  const int*   src   = ei;
  const int*   dst   = ei + E;
  const int*   batch = (const int*)d_in[2];
  const float* W1    = (const float*)d_in[3];
  const float* atts1 = (const float*)d_in[4];
  const float* attd1 = (const float*)d_in[5];
  const float* b1    = (const float*)d_in[6];
  const float* W2    = (const float*)d_in[7];
  const float* atts2 = (const float*)d_in[8];
  const float* attd2 = (const float*)d_in[9];
  const float* b2    = (const float*)d_in[10];
  const float* l1w   = (const float*)d_in[11];
  const float* l1b   = (const float*)d_in[12];
  const float* l2w   = (const float*)d_in[13];
  const float* l2b   = (const float*)d_in[14];

  uintptr_t p = (uintptr_t)d_ws;
  auto alloc = [&](size_t bytes) -> void* {
    p = (p + 255) & ~(uintptr_t)255;
    void* r = (void*)p;
    p += bytes;
    return r;
  };
  const int nb = (N + SCB - 1) / SCB;
  unsigned short* hbuf = (unsigned short*)alloc((size_t)N * 256 * 2);     // bf16 h (GEMM out)
  unsigned short* xh   = (unsigned short*)alloc((size_t)Npad * 256 * 2);  // split x
  unsigned short* xl   = (unsigned short*)alloc((size_t)Npad * 256 * 2);
  unsigned short* fh   = (unsigned short*)alloc((size_t)Npad * 256 * 2);  // split agg out
  unsigned short* fl   = (unsigned short*)alloc((size_t)Npad * 256 * 2);
  float* a_s    = (float*)alloc((size_t)N * 4 * 4);
  float* a_d    = (float*)alloc((size_t)N * 4 * 4);
  float* pooled = (float*)alloc((size_t)G * 256 * 4);
  int*   count  = (int*)alloc((size_t)N * 4);
  int*   rowptr = (int*)alloc((size_t)(N + 1) * 4);
  int*   nxt    = (int*)alloc((size_t)N * 4);
  int*   colx   = (int*)alloc((size_t)T * 4);
  int*   rowx   = (int*)alloc((size_t)T * 4);
  float* ew     = (float*)alloc((size_t)T * 4 * 4);
  int*   bsum   = (int*)alloc((size_t)nb * 4);
  int*   boff   = (int*)alloc((size_t)(nb + 1) * 4);
  unsigned short* wt1h = (unsigned short*)alloc(256 * 256 * 2);
  unsigned short* wt1l = (unsigned short*)alloc(256 * 256 * 2);
  unsigned short* wt2h = (unsigned short*)alloc(256 * 256 * 2);
  unsigned short* wt2l = (unsigned short*)alloc(256 * 256 * 2);

  dim3 blk(256);
  dim3 gemmGrid(Npad / 128, 2);
  int initRange = max(N, G * 256);
  int xtot = N * 256;

  // pre-passes + CSR build (shared by both layers) + init
  conv_w<<<dim3(256, 2), blk, 0, stream>>>(W1, W2, wt1h, wt1l, wt2h, wt2l);
  conv_x<<<(xtot / 4 + 255) / 256, blk, 0, stream>>>(x, xh, xl, xtot);
  init_misc<<<(initRange + 255) / 256, blk, 0, stream>>>(count, pooled, N, G);
  hist_k<<<(E + 255) / 256, blk, 0, stream>>>(dst, count, E);
  scan_phaseA<<<nb, blk, 0, stream>>>(count, bsum, N);
  scan_phaseB<<<1, blk, 0, stream>>>(bsum, boff, nb);
  scan_phaseC<<<nb, blk, 0, stream>>>(count, boff, rowptr, nxt, N, nb);
  scatter_k<<<(T + 255) / 256, blk, 0, stream>>>(src, dst, nxt, colx, rowx, E, N);

  // ---- layer 1
  gemm_mfma<<<gemmGrid, blk, 0, stream>>>(xh, xl, wt1h, wt1l, hbuf, N);
  attn_ab<<<(N + 15) / 16, blk, 0, stream>>>(hbuf, atts1, attd1, a_s, a_d, N);
  edge_w<<<(T + 255) / 256, blk, 0, stream>>>(colx, rowx, a_s, a_d, ew, T);
  agg<<<(N + 3) / 4, blk, 0, stream>>>(hbuf, rowptr, colx, ew, b1, fh, fl, N);

  // ---- layer 2
  gemm_mfma<<<gemmGrid, blk, 0, stream>>>(fh, fl, wt2h, wt2l, hbuf, N);
  attn_ab<<<(N + 15) / 16, blk, 0, stream>>>(hbuf, atts2, attd2, a_s, a_d, N);
  edge_w<<<(T + 255) / 256, blk, 0, stream>>>(colx, rowx, a_s, a_d, ew, T);
  agg<<<(N + 3) / 4, blk, 0, stream>>>(hbuf, rowptr, colx, ew, b2, fh, fl, N);

  // ---- pool + head
  pool_max<<<(N + PNB - 1) / PNB, 128, 0, stream>>>(fh, fl, batch, pooled, N);
  head_k<<<G, 128, 0, stream>>>(pooled, l1w, l1b, l2w, l2b, (float*)d_out);
}

// Round 8
// 286.884 us; speedup vs baseline: 3.1476x; 1.1110x over previous
//
#include <hip/hip_runtime.h>
#include <math.h>

#define LRELU_SLOPE 0.2f
#define NEG_INF __int_as_float(0xff800000)

typedef float f32x4 __attribute__((ext_vector_type(4)));
typedef __bf16 bf16x8 __attribute__((ext_vector_type(8)));
typedef unsigned short us8 __attribute__((ext_vector_type(8)));

union BfCast { us8 u; bf16x8 b; };

__device__ __forceinline__ void atomicMaxF(float* addr, float v) {
  if (v >= 0.f) atomicMax((int*)addr, __float_as_int(v));
  else atomicMin((unsigned int*)addr, (unsigned int)__float_as_int(v));
}

__device__ __forceinline__ unsigned short bf_rne(float f) {
  unsigned int u = __float_as_uint(f);
  u += 0x7FFFu + ((u >> 16) & 1u);
  return (unsigned short)(u >> 16);
}

__device__ __forceinline__ void split_bf16(float f, unsigned short& hi, unsigned short& lo) {
  hi = bf_rne(f);
  float hif = __uint_as_float(((unsigned int)hi) << 16);
  lo = bf_rne(f - hif);
}

// unpack packed bf16 pair (little-endian: low ushort = even channel)
__device__ __forceinline__ float bf_lo(unsigned int u) { return __uint_as_float(u << 16); }
__device__ __forceinline__ float bf_hi(unsigned int u) { return __uint_as_float(u & 0xffff0000u); }

// async global->LDS, 16B per lane; LDS dest must be the wave-uniform base
__device__ __forceinline__ void async_copy16(const unsigned short* g, unsigned short* l) {
  __builtin_amdgcn_global_load_lds(
      (const __attribute__((address_space(1))) void*)g,
      (__attribute__((address_space(3))) void*)l, 16, 0, 0);
}

// ---------------- W pre-pass: transpose + split to bf16 hi/lo ------------------
__global__ void conv_w(const float* __restrict__ W1, const float* __restrict__ W2,
                       unsigned short* __restrict__ t1h, unsigned short* __restrict__ t1l,
                       unsigned short* __restrict__ t2h, unsigned short* __restrict__ t2l) {
  const float* W = blockIdx.y ? W2 : W1;
  unsigned short* th = blockIdx.y ? t2h : t1h;
  unsigned short* tl = blockIdx.y ? t2l : t1l;
  int k = blockIdx.x, n = threadIdx.x;
  float f = W[k * 256 + n];
  unsigned short hi, lo;
  split_bf16(f, hi, lo);
  th[n * 256 + k] = hi;
  tl[n * 256 + k] = lo;
}

// ---------------- X pre-pass: split f32 -> bf16 hi/lo --------------------------
__global__ __launch_bounds__(256) void conv_x(
    const float* __restrict__ x, unsigned short* __restrict__ xh,
    unsigned short* __restrict__ xl, int total) {
  int base = (blockIdx.x * 256 + threadIdx.x) * 4;
  if (base >= total) return;
  float4 v = *(const float4*)(x + base);
  ushort4 h, l;
  split_bf16(v.x, h.x, l.x);
  split_bf16(v.y, h.y, l.y);
  split_bf16(v.z, h.z, l.z);
  split_bf16(v.w, h.w, l.w);
  *(ushort4*)(xh + base) = h;
  *(ushort4*)(xl + base) = l;
}

// ---------------- GEMM: Cbf16[M,256] = (Ah+Al) @ (Bh+Bl)^T via split-bf16 MFMA -
__global__ __launch_bounds__(256) void gemm_mfma(
    const unsigned short* __restrict__ Ah, const unsigned short* __restrict__ Al,
    const unsigned short* __restrict__ Bh, const unsigned short* __restrict__ Bl,
    unsigned short* __restrict__ C, int M) {
  __shared__ __align__(16) unsigned short sAh[128 * 64];
  __shared__ __align__(16) unsigned short sAl[128 * 64];
  __shared__ __align__(16) unsigned short sBh[128 * 64];
  __shared__ __align__(16) unsigned short sBl[128 * 64];
  const int tid = threadIdx.x;
  const int lane = tid & 63;
  const int wave = tid >> 6;
  const int wr = wave >> 1, wc = wave & 1;
  const int bm = blockIdx.x * 128;
  const int bn = blockIdx.y * 128;

  const int srow = lane >> 3;                          // 0..7
  const int scol = (((lane & 7) ^ (lane >> 3)) << 3);  // swizzled ushort col

  f32x4 acc[4][4];
#pragma unroll
  for (int i = 0; i < 4; ++i)
#pragma unroll
    for (int j = 0; j < 4; ++j) acc[i][j] = (f32x4){0.f, 0.f, 0.f, 0.f};

  for (int kc = 0; kc < 256; kc += 64) {
#pragma unroll
    for (int i = 0; i < 4; ++i) {
      const int r0 = wave * 32 + i * 8;
      const size_t ga = (size_t)(bm + r0 + srow) * 256 + kc + scol;
      const size_t gb = (size_t)(bn + r0 + srow) * 256 + kc + scol;
      async_copy16(Ah + ga, &sAh[r0 * 64]);
      async_copy16(Al + ga, &sAl[r0 * 64]);
      async_copy16(Bh + gb, &sBh[r0 * 64]);
      async_copy16(Bl + gb, &sBl[r0 * 64]);
    }
    __syncthreads();
#pragma unroll
    for (int ks = 0; ks < 64; ks += 32) {
      const int kbase = ks + ((lane >> 4) << 3);
      const int kx = kbase ^ ((lane & 7) << 3);
      bf16x8 ah[4], al[4], bh[4], bl[4];
#pragma unroll
      for (int f = 0; f < 4; ++f) {
        int ar = wr * 64 + f * 16 + (lane & 15);
        int br = wc * 64 + f * 16 + (lane & 15);
        BfCast c0, c1, c2, c3;
        c0.u = *(const us8*)&sAh[ar * 64 + kx]; ah[f] = c0.b;
        c1.u = *(const us8*)&sAl[ar * 64 + kx]; al[f] = c1.b;
        c2.u = *(const us8*)&sBh[br * 64 + kx]; bh[f] = c2.b;
        c3.u = *(const us8*)&sBl[br * 64 + kx]; bl[f] = c3.b;
      }
#pragma unroll
      for (int i = 0; i < 4; ++i)
#pragma unroll
        for (int j = 0; j < 4; ++j) {
          acc[i][j] = __builtin_amdgcn_mfma_f32_16x16x32_bf16(ah[i], bh[j], acc[i][j], 0, 0, 0);
          acc[i][j] = __builtin_amdgcn_mfma_f32_16x16x32_bf16(al[i], bh[j], acc[i][j], 0, 0, 0);
          acc[i][j] = __builtin_amdgcn_mfma_f32_16x16x32_bf16(ah[i], bl[j], acc[i][j], 0, 0, 0);
        }
    }
    __syncthreads();
  }
#pragma unroll
  for (int i = 0; i < 4; ++i) {
#pragma unroll
    for (int r = 0; r < 4; ++r) {
      int row = bm + wr * 64 + i * 16 + ((lane >> 4) << 2) + r;
      if (row < M) {
#pragma unroll
        for (int j = 0; j < 4; ++j)
          C[(size_t)row * 256 + bn + wc * 64 + j * 16 + (lane & 15)] = bf_rne(acc[i][j][r]);
      }
    }
  }
}

// ---------------- attention coefficients from bf16 h: a_src/a_dst [N,4] -------
__global__ __launch_bounds__(256) void attn_ab(
    const unsigned short* __restrict__ h, const float* __restrict__ att_s,
    const float* __restrict__ att_d, float* __restrict__ a_s,
    float* __restrict__ a_d, int N_) {
  const int slot = threadIdx.x >> 7;
  const int k = threadIdx.x & 127;
  const int head = k >> 5;
  const int c2 = k & 31;
  const float2 ws2 = *(const float2*)(att_s + head * 64 + c2 * 2);
  const float2 wd2 = *(const float2*)(att_d + head * 64 + c2 * 2);
  int n0 = blockIdx.x * 16 + slot * 8;
  int n1 = min(n0 + 8, N_);
  for (int n = n0; n < n1; ++n) {
    unsigned int w = *(const unsigned int*)(h + (size_t)n * 256 + head * 64 + c2 * 2);
    float x0 = bf_lo(w), x1 = bf_hi(w);
    float ps = x0 * ws2.x + x1 * ws2.y;
    float pd = x0 * wd2.x + x1 * wd2.y;
#pragma unroll
    for (int off = 16; off > 0; off >>= 1) {
      ps += __shfl_xor(ps, off);
      pd += __shfl_xor(pd, off);
    }
    if (c2 == 0) { a_s[n * 4 + head] = ps; a_d[n * 4 + head] = pd; }
  }
}

// ---------------- misc init ---------------------------------------------------
__global__ void init_misc(int* __restrict__ count, float* __restrict__ pooled,
                          int N_, int G_) {
  int t = blockIdx.x * 256 + threadIdx.x;
  if (t < N_) count[t] = 1;                 // self loop
  if (t < G_ * 256) pooled[t] = NEG_INF;
}

// ---------------- CSR build ----------------------------------------------------
__global__ void hist_k(const int* __restrict__ dst, int* __restrict__ count, int E_) {
  int t = blockIdx.x * 256 + threadIdx.x;
  if (t < E_) atomicAdd(&count[dst[t]], 1);
}

#define SCB 1024

__global__ __launch_bounds__(256) void scan_phaseA(
    const int* __restrict__ count, int* __restrict__ bsum, int N_) {
  int t = threadIdx.x;
  int base = blockIdx.x * SCB + t * 4;
  int s = 0;
  if (base + 3 < N_) {
    int4 v = *(const int4*)(count + base);
    s = v.x + v.y + v.z + v.w;
  } else {
#pragma unroll
    for (int k = 0; k < 4; ++k) if (base + k < N_) s += count[base + k];
  }
#pragma unroll
  for (int off = 32; off > 0; off >>= 1) s += __shfl_xor(s, off);
  __shared__ int red[4];
  int wave = t >> 6, lane = t & 63;
  if (lane == 0) red[wave] = s;
  __syncthreads();
  if (t == 0) bsum[blockIdx.x] = red[0] + red[1] + red[2] + red[3];
}

__global__ __launch_bounds__(256) void scan_phaseB(
    const int* __restrict__ bsum, int* __restrict__ boff, int nb) {
  __shared__ int tmp[256];
  int t = threadIdx.x;
  int v = (t < nb) ? bsum[t] : 0;
  tmp[t] = v;
  __syncthreads();
  for (int off = 1; off < 256; off <<= 1) {
    int u = (t >= off) ? tmp[t - off] : 0;
    __syncthreads();
    tmp[t] += u;
    __syncthreads();
  }
  if (t < nb) boff[t] = tmp[t] - v;  // exclusive
  if (t == 0) boff[nb] = tmp[255];   // grand total
}

__global__ __launch_bounds__(256) void scan_phaseC(
    const int* __restrict__ count, const int* __restrict__ boff,
    int* __restrict__ rowptr, int* __restrict__ nxt, int N_, int nb) {
  __shared__ int tmp[256];
  int t = threadIdx.x;
  int base = blockIdx.x * SCB + t * 4;
  int4 v = make_int4(0, 0, 0, 0);
  if (base + 3 < N_) {
    v = *(const int4*)(count + base);
  } else {
    if (base + 0 < N_) v.x = count[base + 0];
    if (base + 1 < N_) v.y = count[base + 1];
    if (base + 2 < N_) v.z = count[base + 2];
  }
  int s = v.x + v.y + v.z + v.w;
  tmp[t] = s;
  __syncthreads();
  for (int off = 1; off < 256; off <<= 1) {
    int u = (t >= off) ? tmp[t - off] : 0;
    __syncthreads();
    tmp[t] += u;
    __syncthreads();
  }
  int run = boff[blockIdx.x] + tmp[t] - s;
  int4 rp;
  rp.x = run; run += v.x;
  rp.y = run; run += v.y;
  rp.z = run; run += v.z;
  rp.w = run;
  if (base + 3 < N_) {
    *(int4*)(rowptr + base) = rp;
    *(int4*)(nxt + base) = rp;
  } else {
    if (base + 0 < N_) { rowptr[base + 0] = rp.x; nxt[base + 0] = rp.x; }
    if (base + 1 < N_) { rowptr[base + 1] = rp.y; nxt[base + 1] = rp.y; }
    if (base + 2 < N_) { rowptr[base + 2] = rp.z; nxt[base + 2] = rp.z; }
  }
  if (blockIdx.x == 0 && t == 0) rowptr[N_] = boff[nb];
}

__global__ void scatter_k(const int* __restrict__ src, const int* __restrict__ dst,
                          int* __restrict__ nxt, int* __restrict__ colx,
                          int* __restrict__ rowx, int E_, int N_) {
  int t = blockIdx.x * 256 + threadIdx.x;
  if (t >= E_ + N_) return;
  int s = (t < E_) ? src[t] : (t - E_);
  int d = (t < E_) ? dst[t] : (t - E_);
  int pos = atomicAdd(&nxt[d], 1);
  colx[pos] = s;
  rowx[pos] = d;
}

// ---------------- per-slot softmax weights: ew[j][4] ---------------------------
__global__ __launch_bounds__(256) void edge_w(
    const int* __restrict__ colx, const int* __restrict__ rowx,
    const float* __restrict__ a_s, const float* __restrict__ a_d,
    float* __restrict__ ew, int T) {
  int t = blockIdx.x * 256 + threadIdx.x;
  if (t >= T) return;
  int s = colx[t], d = rowx[t];
  float4 as4 = *(const float4*)(a_s + (size_t)s * 4);
  float4 ad4 = *(const float4*)(a_d + (size_t)d * 4);
  float l;
  float4 w;
  l = as4.x + ad4.x; l = l > 0.f ? l : LRELU_SLOPE * l; w.x = __expf(l);
  l = as4.y + ad4.y; l = l > 0.f ? l : LRELU_SLOPE * l; w.y = __expf(l);
  l = as4.z + ad4.z; l = l > 0.f ? l : LRELU_SLOPE * l; w.z = __expf(l);
  l = as4.w + ad4.w; l = l > 0.f ? l : LRELU_SLOPE * l; w.w = __expf(l);
  *(float4*)(ew + (size_t)t * 4) = w;
}

// ---------------- aggregation: wave-per-node, writes split hi/lo bf16 ---------
__global__ __launch_bounds__(256) void agg(
    const unsigned short* __restrict__ h, const int* __restrict__ rowptr,
    const int* __restrict__ colx, const float* __restrict__ ew,
    const float* __restrict__ bias, unsigned short* __restrict__ out_h,
    unsigned short* __restrict__ out_l, int N_) {
  const int wave = threadIdx.x >> 6;
  const int lane = threadIdx.x & 63;
  const int n = blockIdx.x * 4 + wave;
  if (n >= N_) return;
  const int head = lane >> 4;           // lane owns channels [4*lane, 4*lane+4)
  const size_t coff = (size_t)lane * 4;
  const int e0 = rowptr[n], e1 = rowptr[n + 1];
  float4 acc = make_float4(0.f, 0.f, 0.f, 0.f);
  float dsum = 0.f;
  int j = e0;
  for (; j + 4 <= e1; j += 4) {
    int s0 = colx[j + 0], s1 = colx[j + 1], s2 = colx[j + 2], s3 = colx[j + 3];
    float w0 = ew[(size_t)(j + 0) * 4 + head];
    float w1 = ew[(size_t)(j + 1) * 4 + head];
    float w2 = ew[(size_t)(j + 2) * 4 + head];
    float w3 = ew[(size_t)(j + 3) * 4 + head];
    uint2 g0 = *(const uint2*)(h + (size_t)s0 * 256 + coff);
    uint2 g1 = *(const uint2*)(h + (size_t)s1 * 256 + coff);
    uint2 g2 = *(const uint2*)(h + (size_t)s2 * 256 + coff);
    uint2 g3 = *(const uint2*)(h + (size_t)s3 * 256 + coff);
    dsum += (w0 + w1) + (w2 + w3);
    acc.x = fmaf(w0, bf_lo(g0.x), acc.x); acc.y = fmaf(w0, bf_hi(g0.x), acc.y);
    acc.z = fmaf(w0, bf_lo(g0.y), acc.z); acc.w = fmaf(w0, bf_hi(g0.y), acc.w);
    acc.x = fmaf(w1, bf_lo(g1.x), acc.x); acc.y = fmaf(w1, bf_hi(g1.x), acc.y);
    acc.z = fmaf(w1, bf_lo(g1.y), acc.z); acc.w = fmaf(w1, bf_hi(g1.y), acc.w);
    acc.x = fmaf(w2, bf_lo(g2.x), acc.x); acc.y = fmaf(w2, bf_hi(g2.x), acc.y);
    acc.z = fmaf(w2, bf_lo(g2.y), acc.z); acc.w = fmaf(w2, bf_hi(g2.y), acc.w);
    acc.x = fmaf(w3, bf_lo(g3.x), acc.x); acc.y = fmaf(w3, bf_hi(g3.x), acc.y);
    acc.z = fmaf(w3, bf_lo(g3.y), acc.z); acc.w = fmaf(w3, bf_hi(g3.y), acc.w);
  }
  for (; j < e1; ++j) {
    int s = colx[j];
    float w = ew[(size_t)j * 4 + head];
    uint2 g = *(const uint2*)(h + (size_t)s * 256 + coff);
    dsum += w;
    acc.x = fmaf(w, bf_lo(g.x), acc.x); acc.y = fmaf(w, bf_hi(g.x), acc.y);
    acc.z = fmaf(w, bf_lo(g.y), acc.z); acc.w = fmaf(w, bf_hi(g.y), acc.w);
  }
  const float inv = 1.f / (dsum + 1e-16f);
  const float4 b4 = *(const float4*)(bias + coff);
  float v;
  float4 o;
  v = acc.x * inv + b4.x; o.x = v > 0.f ? v : expm1f(v);
  v = acc.y * inv + b4.y; o.y = v > 0.f ? v : expm1f(v);
  v = acc.z * inv + b4.z; o.z = v > 0.f ? v : expm1f(v);
  v = acc.w * inv + b4.w; o.w = v > 0.f ? v : expm1f(v);
  ushort4 oh, ol;
  split_bf16(o.x, oh.x, ol.x);
  split_bf16(o.y, oh.y, ol.y);
  split_bf16(o.z, oh.z, ol.z);
  split_bf16(o.w, oh.w, ol.w);
  *(ushort4*)(out_h + (size_t)n * 256 + coff) = oh;
  *(ushort4*)(out_l + (size_t)n * 256 + coff) = ol;
}

// ---------------- graph max-pool from split hi/lo (batch is sorted) -----------
// 32 nodes/block, 2 node-slots x 128 channel-pairs; running max + boundary flush
#define PNB 32
__global__ __launch_bounds__(256) void pool_max(
    const unsigned short* __restrict__ fh, const unsigned short* __restrict__ fl,
    const int* __restrict__ batch, float* __restrict__ pooled, int N_) {
  const int c2 = threadIdx.x & 127;        // channels 2*c2, 2*c2+1
  const int slot = threadIdx.x >> 7;       // 2 slots x 16 nodes
  const int ns = blockIdx.x * PNB + slot * 16;
  const int ne = min(ns + 16, N_);
  if (ns >= N_) return;
  float r0 = NEG_INF, r1 = NEG_INF;
  int g = batch[ns];
#pragma unroll 4
  for (int n = ns; n < ne; ++n) {
    int gn = batch[n];
    unsigned int wh = *(const unsigned int*)(fh + (size_t)n * 256 + c2 * 2);
    unsigned int wl = *(const unsigned int*)(fl + (size_t)n * 256 + c2 * 2);
    if (gn != g) {
      atomicMaxF(&pooled[(size_t)g * 256 + c2 * 2], r0);
      atomicMaxF(&pooled[(size_t)g * 256 + c2 * 2 + 1], r1);
      r0 = r1 = NEG_INF; g = gn;
    }
    r0 = fmaxf(r0, bf_lo(wh) + bf_lo(wl));
    r1 = fmaxf(r1, bf_hi(wh) + bf_hi(wl));
  }
  atomicMaxF(&pooled[(size_t)g * 256 + c2 * 2], r0);
  atomicMaxF(&pooled[(size_t)g * 256 + c2 * 2 + 1], r1);
}

// ---------------- head: fixup -inf, lin1 (256->128), lin2 (128->2) ------------
__global__ __launch_bounds__(128) void head_k(
    const float* __restrict__ pooled, const float* __restrict__ w1,
    const float* __restrict__ b1, const float* __restrict__ w2,
    const float* __restrict__ b2, float* __restrict__ out) {
  __shared__ float ps[256];
  __shared__ float z1[128];
  int g = blockIdx.x;
  int t = threadIdx.x;
  for (int i = t; i < 256; i += 128) {
    float v = pooled[(size_t)g * 256 + i];
    if (v < -1e37f) v = 0.f;   // empty-graph guard (isneginf -> 0)
    ps[i] = v;
  }
  __syncthreads();
  float a = b1[t];
  for (int k = 0; k < 256; ++k) a = fmaf(ps[k], w1[k * 128 + t], a);
  z1[t] = a;
  __syncthreads();
  if (t < 2) {
    float a2 = b2[t];
    for (int j = 0; j < 128; ++j) a2 = fmaf(z1[j], w2[j * 2 + t], a2);
    out[g * 2 + t] = a2;
  }
}

// ---------------- driver --------------------------------------------------------
extern "C" void kernel_launch(void* const* d_in, const int* in_sizes, int n_in,
                              void* d_out, int out_size, void* d_ws, size_t ws_size,
                              hipStream_t stream) {
  const int N = in_sizes[2];         // batch array length = #nodes
  const int E = in_sizes[1] / 2;     // edge_index is [2,E]
  const int G = out_size / 2;        // output [G,2]
  const int T = E + N;               // CSR slots (incl. self loops)
  const int Npad = ((N + 127) / 128) * 128;

  const float* x     = (const float*)d_in[0];
  const int*   ei    = (const int*)d_in[1];
  const int*   src   = ei;
  const int*   dst   = ei + E;
  const int*   batch = (const int*)d_in[2];
  const float* W1    = (const float*)d_in[3];
  const float* atts1 = (const float*)d_in[4];
  const float* attd1 = (const float*)d_in[5];
  const float* b1    = (const float*)d_in[6];
  const float* W2    = (const float*)d_in[7];
  const float* atts2 = (const float*)d_in[8];
  const float* attd2 = (const float*)d_in[9];
  const float* b2    = (const float*)d_in[10];
  const float* l1w   = (const float*)d_in[11];
  const float* l1b   = (const float*)d_in[12];
  const float* l2w   = (const float*)d_in[13];
  const float* l2b   = (const float*)d_in[14];

  uintptr_t p = (uintptr_t)d_ws;
  auto alloc = [&](size_t bytes) -> void* {
    p = (p + 255) & ~(uintptr_t)255;
    void* r = (void*)p;
    p += bytes;
    return r;
  };
  const int nb = (N + SCB - 1) / SCB;
  unsigned short* hbuf = (unsigned short*)alloc((size_t)N * 256 * 2);     // bf16 h (GEMM out)
  unsigned short* xh   = (unsigned short*)alloc((size_t)Npad * 256 * 2);  // split x
  unsigned short* xl   = (unsigned short*)alloc((size_t)Npad * 256 * 2);
  unsigned short* fh   = (unsigned short*)alloc((size_t)Npad * 256 * 2);  // split agg out
  unsigned short* fl   = (unsigned short*)alloc((size_t)Npad * 256 * 2);
  float* a_s    = (float*)alloc((size_t)N * 4 * 4);
  float* a_d    = (float*)alloc((size_t)N * 4 * 4);
  float* pooled = (float*)alloc((size_t)G * 256 * 4);
  int*   count  = (int*)alloc((size_t)N * 4);
  int*   rowptr = (int*)alloc((size_t)(N + 1) * 4);
  int*   nxt    = (int*)alloc((size_t)N * 4);
  int*   colx   = (int*)alloc((size_t)T * 4);
  int*   rowx   = (int*)alloc((size_t)T * 4);
  float* ew     = (float*)alloc((size_t)T * 4 * 4);
  int*   bsum   = (int*)alloc((size_t)nb * 4);
  int*   boff   = (int*)alloc((size_t)(nb + 1) * 4);
  unsigned short* wt1h = (unsigned short*)alloc(256 * 256 * 2);
  unsigned short* wt1l = (unsigned short*)alloc(256 * 256 * 2);
  unsigned short* wt2h = (unsigned short*)alloc(256 * 256 * 2);
  unsigned short* wt2l = (unsigned short*)alloc(256 * 256 * 2);

  dim3 blk(256);
  dim3 gemmGrid(Npad / 128, 2);
  int initRange = max(N, G * 256);
  int xtot = N * 256;

  // pre-passes + CSR build (shared by both layers) + init
  conv_w<<<dim3(256, 2), blk, 0, stream>>>(W1, W2, wt1h, wt1l, wt2h, wt2l);
  conv_x<<<(xtot / 4 + 255) / 256, blk, 0, stream>>>(x, xh, xl, xtot);
  init_misc<<<(initRange + 255) / 256, blk, 0, stream>>>(count, pooled, N, G);
  hist_k<<<(E + 255) / 256, blk, 0, stream>>>(dst, count, E);
  scan_phaseA<<<nb, blk, 0, stream>>>(count, bsum, N);
  scan_phaseB<<<1, blk, 0, stream>>>(bsum, boff, nb);
  scan_phaseC<<<nb, blk, 0, stream>>>(count, boff, rowptr, nxt, N, nb);
  scatter_k<<<(T + 255) / 256, blk, 0, stream>>>(src, dst, nxt, colx, rowx, E, N);

  // ---- layer 1
  gemm_mfma<<<gemmGrid, blk, 0, stream>>>(xh, xl, wt1h, wt1l, hbuf, N);
  attn_ab<<<(N + 15) / 16, blk, 0, stream>>>(hbuf, atts1, attd1, a_s, a_d, N);
  edge_w<<<(T + 255) / 256, blk, 0, stream>>>(colx, rowx, a_s, a_d, ew, T);
  agg<<<(N + 3) / 4, blk, 0, stream>>>(hbuf, rowptr, colx, ew, b1, fh, fl, N);

  // ---- layer 2
  gemm_mfma<<<gemmGrid, blk, 0, stream>>>(fh, fl, wt2h, wt2l, hbuf, N);
  attn_ab<<<(N + 15) / 16, blk, 0, stream>>>(hbuf, atts2, attd2, a_s, a_d, N);
  edge_w<<<(T + 255) / 256, blk, 0, stream>>>(colx, rowx, a_s, a_d, ew, T);
  agg<<<(N + 3) / 4, blk, 0, stream>>>(hbuf, rowptr, colx, ew, b2, fh, fl, N);

  // ---- pool + head
  pool_max<<<(N + PNB - 1) / PNB, blk, 0, stream>>>(fh, fl, batch, pooled, N);
  head_k<<<G, 128, 0, stream>>>(pooled, l1w, l1b, l2w, l2b, (float*)d_out);
}

// Round 9
// 256.447 us; speedup vs baseline: 3.5212x; 1.1187x over previous
//
#include <hip/hip_runtime.h>
#include <math.h>

#define LRELU_SLOPE 0.2f
#define NEG_INF __int_as_float(0xff800000)

typedef float f32x4 __attribute__((ext_vector_type(4)));
typedef _Float16 f16x8 __attribute__((ext_vector_type(8)));
typedef _Float16 f16x2 __attribute__((ext_vector_type(2)));
typedef unsigned short us8 __attribute__((ext_vector_type(8)));

__device__ __forceinline__ void atomicMaxF(float* addr, float v) {
  if (v >= 0.f) atomicMax((int*)addr, __float_as_int(v));
  else atomicMin((unsigned int*)addr, (unsigned int)__float_as_int(v));
}

__device__ __forceinline__ unsigned short f2h(float f) {
  _Float16 h = (_Float16)f;                       // v_cvt_f16_f32 (RNE)
  return __builtin_bit_cast(unsigned short, h);
}
__device__ __forceinline__ float h2f(unsigned short u) {
  return (float)__builtin_bit_cast(_Float16, u);  // v_cvt_f32_f16
}
__device__ __forceinline__ float2 up2(unsigned int u) {
  f16x2 h = __builtin_bit_cast(f16x2, u);
  return make_float2((float)h.x, (float)h.y);
}

// async global->LDS, 16B per lane; LDS dest must be the wave-uniform base
__device__ __forceinline__ void async_copy16(const unsigned short* g, unsigned short* l) {
  __builtin_amdgcn_global_load_lds(
      (const __attribute__((address_space(1))) void*)g,
      (__attribute__((address_space(3))) void*)l, 16, 0, 0);
}

// ---------------- W pre-pass: transpose + cvt to fp16 --------------------------
__global__ void conv_w(const float* __restrict__ W1, const float* __restrict__ W2,
                       unsigned short* __restrict__ t1, unsigned short* __restrict__ t2) {
  const float* W = blockIdx.y ? W2 : W1;
  unsigned short* t = blockIdx.y ? t2 : t1;
  int k = blockIdx.x, n = threadIdx.x;
  t[n * 256 + k] = f2h(W[k * 256 + n]);
}

// ---------------- X pre-pass: f32 -> fp16 --------------------------------------
__global__ __launch_bounds__(256) void conv_x(
    const float* __restrict__ x, unsigned short* __restrict__ xo, int total) {
  int base = (blockIdx.x * 256 + threadIdx.x) * 4;
  if (base >= total) return;
  float4 v = *(const float4*)(x + base);
  ushort4 h;
  h.x = f2h(v.x); h.y = f2h(v.y); h.z = f2h(v.z); h.w = f2h(v.w);
  *(ushort4*)(xo + base) = h;
}

// ---------------- GEMM: Cfp16[M,256] = A[M,256] @ B^T, single fp16 MFMA --------
// A fp16 [Mpad,256]; Bt fp16 [n][k]. LDS linear [128][64], XOR-swizzled via
// pre-swizzled global source column + swizzled ds_read (rule #21).
__global__ __launch_bounds__(256) void gemm_mfma(
    const unsigned short* __restrict__ A, const unsigned short* __restrict__ Bt,
    unsigned short* __restrict__ C, int M) {
  __shared__ __align__(16) unsigned short sA[128 * 64];
  __shared__ __align__(16) unsigned short sB[128 * 64];
  const int tid = threadIdx.x;
  const int lane = tid & 63;
  const int wave = tid >> 6;
  const int wr = wave >> 1, wc = wave & 1;
  const int bm = blockIdx.x * 128;
  const int bn = blockIdx.y * 128;

  const int srow = lane >> 3;                          // 0..7
  const int scol = (((lane & 7) ^ (lane >> 3)) << 3);  // swizzled ushort col

  f32x4 acc[4][4];
#pragma unroll
  for (int i = 0; i < 4; ++i)
#pragma unroll
    for (int j = 0; j < 4; ++j) acc[i][j] = (f32x4){0.f, 0.f, 0.f, 0.f};

  for (int kc = 0; kc < 256; kc += 64) {
#pragma unroll
    for (int i = 0; i < 4; ++i) {
      const int r0 = wave * 32 + i * 8;
      const size_t ga = (size_t)(bm + r0 + srow) * 256 + kc + scol;
      const size_t gb = (size_t)(bn + r0 + srow) * 256 + kc + scol;
      async_copy16(A + ga, &sA[r0 * 64]);
      async_copy16(Bt + gb, &sB[r0 * 64]);
    }
    __syncthreads();
#pragma unroll
    for (int ks = 0; ks < 64; ks += 32) {
      const int kbase = ks + ((lane >> 4) << 3);
      const int kx = kbase ^ ((lane & 7) << 3);
      f16x8 af[4], bf[4];
#pragma unroll
      for (int f = 0; f < 4; ++f) {
        int ar = wr * 64 + f * 16 + (lane & 15);
        int br = wc * 64 + f * 16 + (lane & 15);
        af[f] = __builtin_bit_cast(f16x8, *(const us8*)&sA[ar * 64 + kx]);
        bf[f] = __builtin_bit_cast(f16x8, *(const us8*)&sB[br * 64 + kx]);
      }
#pragma unroll
      for (int i = 0; i < 4; ++i)
#pragma unroll
        for (int j = 0; j < 4; ++j)
          acc[i][j] = __builtin_amdgcn_mfma_f32_16x16x32_f16(af[i], bf[j], acc[i][j], 0, 0, 0);
    }
    __syncthreads();
  }
  // epilogue: fp16 store. m=(lane>>4)*4+reg, n=lane&15 within each 16x16 frag
#pragma unroll
  for (int i = 0; i < 4; ++i) {
#pragma unroll
    for (int r = 0; r < 4; ++r) {
      int row = bm + wr * 64 + i * 16 + ((lane >> 4) << 2) + r;
      if (row < M) {
#pragma unroll
        for (int j = 0; j < 4; ++j)
          C[(size_t)row * 256 + bn + wc * 64 + j * 16 + (lane & 15)] = f2h(acc[i][j][r]);
      }
    }
  }
}

// ---------------- attention coefficients from fp16 h: a_src/a_dst [N,4] -------
__global__ __launch_bounds__(256) void attn_ab(
    const unsigned short* __restrict__ h, const float* __restrict__ att_s,
    const float* __restrict__ att_d, float* __restrict__ a_s,
    float* __restrict__ a_d, int N_) {
  const int slot = threadIdx.x >> 7;
  const int k = threadIdx.x & 127;
  const int head = k >> 5;
  const int c2 = k & 31;
  const float2 ws2 = *(const float2*)(att_s + head * 64 + c2 * 2);
  const float2 wd2 = *(const float2*)(att_d + head * 64 + c2 * 2);
  int n0 = blockIdx.x * 16 + slot * 8;
  int n1 = min(n0 + 8, N_);
  for (int n = n0; n < n1; ++n) {
    unsigned int w = *(const unsigned int*)(h + (size_t)n * 256 + head * 64 + c2 * 2);
    float2 xv = up2(w);
    float ps = xv.x * ws2.x + xv.y * ws2.y;
    float pd = xv.x * wd2.x + xv.y * wd2.y;
#pragma unroll
    for (int off = 16; off > 0; off >>= 1) {
      ps += __shfl_xor(ps, off);
      pd += __shfl_xor(pd, off);
    }
    if (c2 == 0) { a_s[n * 4 + head] = ps; a_d[n * 4 + head] = pd; }
  }
}

// ---------------- misc init ---------------------------------------------------
__global__ void init_misc(int* __restrict__ count, float* __restrict__ pooled,
                          int N_, int G_) {
  int t = blockIdx.x * 256 + threadIdx.x;
  if (t < N_) count[t] = 1;                 // self loop
  if (t < G_ * 256) pooled[t] = NEG_INF;
}

// ---------------- CSR build ----------------------------------------------------
__global__ void hist_k(const int* __restrict__ dst, int* __restrict__ count, int E_) {
  int t = blockIdx.x * 256 + threadIdx.x;
  if (t < E_) atomicAdd(&count[dst[t]], 1);
}

#define SCB 1024

__global__ __launch_bounds__(256) void scan_phaseA(
    const int* __restrict__ count, int* __restrict__ bsum, int N_) {
  int t = threadIdx.x;
  int base = blockIdx.x * SCB + t * 4;
  int s = 0;
  if (base + 3 < N_) {
    int4 v = *(const int4*)(count + base);
    s = v.x + v.y + v.z + v.w;
  } else {
#pragma unroll
    for (int k = 0; k < 4; ++k) if (base + k < N_) s += count[base + k];
  }
#pragma unroll
  for (int off = 32; off > 0; off >>= 1) s += __shfl_xor(s, off);
  __shared__ int red[4];
  int wave = t >> 6, lane = t & 63;
  if (lane == 0) red[wave] = s;
  __syncthreads();
  if (t == 0) bsum[blockIdx.x] = red[0] + red[1] + red[2] + red[3];
}

__global__ __launch_bounds__(256) void scan_phaseB(
    const int* __restrict__ bsum, int* __restrict__ boff, int nb) {
  __shared__ int tmp[256];
  int t = threadIdx.x;
  int v = (t < nb) ? bsum[t] : 0;
  tmp[t] = v;
  __syncthreads();
  for (int off = 1; off < 256; off <<= 1) {
    int u = (t >= off) ? tmp[t - off] : 0;
    __syncthreads();
    tmp[t] += u;
    __syncthreads();
  }
  if (t < nb) boff[t] = tmp[t] - v;  // exclusive
  if (t == 0) boff[nb] = tmp[255];   // grand total
}

__global__ __launch_bounds__(256) void scan_phaseC(
    const int* __restrict__ count, const int* __restrict__ boff,
    int* __restrict__ rowptr, int* __restrict__ nxt, int N_, int nb) {
  __shared__ int tmp[256];
  int t = threadIdx.x;
  int base = blockIdx.x * SCB + t * 4;
  int4 v = make_int4(0, 0, 0, 0);
  if (base + 3 < N_) {
    v = *(const int4*)(count + base);
  } else {
    if (base + 0 < N_) v.x = count[base + 0];
    if (base + 1 < N_) v.y = count[base + 1];
    if (base + 2 < N_) v.z = count[base + 2];
  }
  int s = v.x + v.y + v.z + v.w;
  tmp[t] = s;
  __syncthreads();
  for (int off = 1; off < 256; off <<= 1) {
    int u = (t >= off) ? tmp[t - off] : 0;
    __syncthreads();
    tmp[t] += u;
    __syncthreads();
  }
  int run = boff[blockIdx.x] + tmp[t] - s;
  int4 rp;
  rp.x = run; run += v.x;
  rp.y = run; run += v.y;
  rp.z = run; run += v.z;
  rp.w = run;
  if (base + 3 < N_) {
    *(int4*)(rowptr + base) = rp;
    *(int4*)(nxt + base) = rp;
  } else {
    if (base + 0 < N_) { rowptr[base + 0] = rp.x; nxt[base + 0] = rp.x; }
    if (base + 1 < N_) { rowptr[base + 1] = rp.y; nxt[base + 1] = rp.y; }
    if (base + 2 < N_) { rowptr[base + 2] = rp.z; nxt[base + 2] = rp.z; }
  }
  if (blockIdx.x == 0 && t == 0) rowptr[N_] = boff[nb];
}

__global__ void scatter_k(const int* __restrict__ src, const int* __restrict__ dst,
                          int* __restrict__ nxt, int* __restrict__ colx,
                          int* __restrict__ rowx, int E_, int N_) {
  int t = blockIdx.x * 256 + threadIdx.x;
  if (t >= E_ + N_) return;
  int s = (t < E_) ? src[t] : (t - E_);
  int d = (t < E_) ? dst[t] : (t - E_);
  int pos = atomicAdd(&nxt[d], 1);
  colx[pos] = s;
  rowx[pos] = d;
}

// ---------------- per-slot softmax weights: ew[j][4] ---------------------------
__global__ __launch_bounds__(256) void edge_w(
    const int* __restrict__ colx, const int* __restrict__ rowx,
    const float* __restrict__ a_s, const float* __restrict__ a_d,
    float* __restrict__ ew, int T) {
  int t = blockIdx.x * 256 + threadIdx.x;
  if (t >= T) return;
  int s = colx[t], d = rowx[t];
  float4 as4 = *(const float4*)(a_s + (size_t)s * 4);
  float4 ad4 = *(const float4*)(a_d + (size_t)d * 4);
  float l;
  float4 w;
  l = as4.x + ad4.x; l = l > 0.f ? l : LRELU_SLOPE * l; w.x = __expf(l);
  l = as4.y + ad4.y; l = l > 0.f ? l : LRELU_SLOPE * l; w.y = __expf(l);
  l = as4.z + ad4.z; l = l > 0.f ? l : LRELU_SLOPE * l; w.z = __expf(l);
  l = as4.w + ad4.w; l = l > 0.f ? l : LRELU_SLOPE * l; w.w = __expf(l);
  *(float4*)(ew + (size_t)t * 4) = w;
}

// ---------------- aggregation: wave-per-node, fp16 payload in/out -------------
__global__ __launch_bounds__(256) void agg(
    const unsigned short* __restrict__ h, const int* __restrict__ rowptr,
    const int* __restrict__ colx, const float* __restrict__ ew,
    const float* __restrict__ bias, unsigned short* __restrict__ out, int N_) {
  const int wave = threadIdx.x >> 6;
  const int lane = threadIdx.x & 63;
  const int n = blockIdx.x * 4 + wave;
  if (n >= N_) return;
  const int head = lane >> 4;           // lane owns channels [4*lane, 4*lane+4)
  const size_t coff = (size_t)lane * 4;
  const int e0 = rowptr[n], e1 = rowptr[n + 1];
  float4 acc = make_float4(0.f, 0.f, 0.f, 0.f);
  float dsum = 0.f;
  int j = e0;
  for (; j + 4 <= e1; j += 4) {
    int s0 = colx[j + 0], s1 = colx[j + 1], s2 = colx[j + 2], s3 = colx[j + 3];
    float w0 = ew[(size_t)(j + 0) * 4 + head];
    float w1 = ew[(size_t)(j + 1) * 4 + head];
    float w2 = ew[(size_t)(j + 2) * 4 + head];
    float w3 = ew[(size_t)(j + 3) * 4 + head];
    uint2 g0 = *(const uint2*)(h + (size_t)s0 * 256 + coff);
    uint2 g1 = *(const uint2*)(h + (size_t)s1 * 256 + coff);
    uint2 g2 = *(const uint2*)(h + (size_t)s2 * 256 + coff);
    uint2 g3 = *(const uint2*)(h + (size_t)s3 * 256 + coff);
    dsum += (w0 + w1) + (w2 + w3);
    float2 a0 = up2(g0.x), b0 = up2(g0.y);
    float2 a1 = up2(g1.x), b1 = up2(g1.y);
    float2 a2 = up2(g2.x), b2 = up2(g2.y);
    float2 a3 = up2(g3.x), b3 = up2(g3.y);
    acc.x = fmaf(w0, a0.x, acc.x); acc.y = fmaf(w0, a0.y, acc.y);
    acc.z = fmaf(w0, b0.x, acc.z); acc.w = fmaf(w0, b0.y, acc.w);
    acc.x = fmaf(w1, a1.x, acc.x); acc.y = fmaf(w1, a1.y, acc.y);
    acc.z = fmaf(w1, b1.x, acc.z); acc.w = fmaf(w1, b1.y, acc.w);
    acc.x = fmaf(w2, a2.x, acc.x); acc.y = fmaf(w2, a2.y, acc.y);
    acc.z = fmaf(w2, b2.x, acc.z); acc.w = fmaf(w2, b2.y, acc.w);
    acc.x = fmaf(w3, a3.x, acc.x); acc.y = fmaf(w3, a3.y, acc.y);
    acc.z = fmaf(w3, b3.x, acc.z); acc.w = fmaf(w3, b3.y, acc.w);
  }
  for (; j < e1; ++j) {
    int s = colx[j];
    float w = ew[(size_t)j * 4 + head];
    uint2 g = *(const uint2*)(h + (size_t)s * 256 + coff);
    dsum += w;
    float2 a = up2(g.x), b = up2(g.y);
    acc.x = fmaf(w, a.x, acc.x); acc.y = fmaf(w, a.y, acc.y);
    acc.z = fmaf(w, b.x, acc.z); acc.w = fmaf(w, b.y, acc.w);
  }
  const float inv = 1.f / (dsum + 1e-16f);
  const float4 b4 = *(const float4*)(bias + coff);
  float v;
  float4 o;
  v = acc.x * inv + b4.x; o.x = v > 0.f ? v : expm1f(v);
  v = acc.y * inv + b4.y; o.y = v > 0.f ? v : expm1f(v);
  v = acc.z * inv + b4.z; o.z = v > 0.f ? v : expm1f(v);
  v = acc.w * inv + b4.w; o.w = v > 0.f ? v : expm1f(v);
  ushort4 oh;
  oh.x = f2h(o.x); oh.y = f2h(o.y); oh.z = f2h(o.z); oh.w = f2h(o.w);
  *(ushort4*)(out + (size_t)n * 256 + coff) = oh;
}

// ---------------- graph max-pool from fp16 (batch is sorted) -------------------
// 32 nodes/block, 2 node-slots x 128 channel-pairs; running max + boundary flush
#define PNB 32
__global__ __launch_bounds__(256) void pool_max(
    const unsigned short* __restrict__ fb, const int* __restrict__ batch,
    float* __restrict__ pooled, int N_) {
  const int c2 = threadIdx.x & 127;        // channels 2*c2, 2*c2+1
  const int slot = threadIdx.x >> 7;       // 2 slots x 16 nodes
  const int ns = blockIdx.x * PNB + slot * 16;
  const int ne = min(ns + 16, N_);
  if (ns >= N_) return;
  float r0 = NEG_INF, r1 = NEG_INF;
  int g = batch[ns];
#pragma unroll 4
  for (int n = ns; n < ne; ++n) {
    int gn = batch[n];
    unsigned int w = *(const unsigned int*)(fb + (size_t)n * 256 + c2 * 2);
    if (gn != g) {
      atomicMaxF(&pooled[(size_t)g * 256 + c2 * 2], r0);
      atomicMaxF(&pooled[(size_t)g * 256 + c2 * 2 + 1], r1);
      r0 = r1 = NEG_INF; g = gn;
    }
    float2 xv = up2(w);
    r0 = fmaxf(r0, xv.x);
    r1 = fmaxf(r1, xv.y);
  }
  atomicMaxF(&pooled[(size_t)g * 256 + c2 * 2], r0);
  atomicMaxF(&pooled[(size_t)g * 256 + c2 * 2 + 1], r1);
}

// ---------------- head: fixup -inf, lin1 (256->128), lin2 (128->2) ------------
__global__ __launch_bounds__(128) void head_k(
    const float* __restrict__ pooled, const float* __restrict__ w1,
    const float* __restrict__ b1, const float* __restrict__ w2,
    const float* __restrict__ b2, float* __restrict__ out) {
  __shared__ float ps[256];
  __shared__ float z1[128];
  int g = blockIdx.x;
  int t = threadIdx.x;
  for (int i = t; i < 256; i += 128) {
    float v = pooled[(size_t)g * 256 + i];
    if (v < -1e37f) v = 0.f;   // empty-graph guard (isneginf -> 0)
    ps[i] = v;
  }
  __syncthreads();
  float a = b1[t];
  for (int k = 0; k < 256; ++k) a = fmaf(ps[k], w1[k * 128 + t], a);
  z1[t] = a;
  __syncthreads();
  if (t < 2) {
    float a2 = b2[t];
    for (int j = 0; j < 128; ++j) a2 = fmaf(z1[j], w2[j * 2 + t], a2);
    out[g * 2 + t] = a2;
  }
}

// ---------------- driver --------------------------------------------------------
extern "C" void kernel_launch(void* const* d_in, const int* in_sizes, int n_in,
                              void* d_out, int out_size, void* d_ws, size_t ws_size,
                              hipStream_t stream) {
  const int N = in_sizes[2];         // batch array length = #nodes
  const int E = in_sizes[1] / 2;     // edge_index is [2,E]
  const int G = out_size / 2;        // output [G,2]
  const int T = E + N;               // CSR slots (incl. self loops)
  const int Npad = ((N + 127) / 128) * 128;

  const float* x     = (const float*)d_in[0];
  const int*   ei    = (const int*)d_in[1];
  const int*   src   = ei;
  const int*   dst   = ei + E;
  const int*   batch = (const int*)d_in[2];
  const float* W1    = (const float*)d_in[3];
  const float* atts1 = (const float*)d_in[4];
  const float* attd1 = (const float*)d_in[5];
  const float* b1    = (const float*)d_in[6];
  const float* W2    = (const float*)d_in[7];
  const float* atts2 = (const float*)d_in[8];
  const float* attd2 = (const float*)d_in[9];
  const float* b2    = (const float*)d_in[10];
  const float* l1w   = (const float*)d_in[11];
  const float* l1b   = (const float*)d_in[12];
  const float* l2w   = (const float*)d_in[13];
  const float* l2b   = (const float*)d_in[14];

  uintptr_t p = (uintptr_t)d_ws;
  auto alloc = [&](size_t bytes) -> void* {
    p = (p + 255) & ~(uintptr_t)255;
    void* r = (void*)p;
    p += bytes;
    return r;
  };
  const int nb = (N + SCB - 1) / SCB;
  unsigned short* hbuf = (unsigned short*)alloc((size_t)N * 256 * 2);     // fp16 h (GEMM out)
  unsigned short* xbuf = (unsigned short*)alloc((size_t)Npad * 256 * 2);  // fp16 x
  unsigned short* fbuf = (unsigned short*)alloc((size_t)Npad * 256 * 2);  // fp16 agg out
  float* a_s    = (float*)alloc((size_t)N * 4 * 4);
  float* a_d    = (float*)alloc((size_t)N * 4 * 4);
  float* pooled = (float*)alloc((size_t)G * 256 * 4);
  int*   count  = (int*)alloc((size_t)N * 4);
  int*   rowptr = (int*)alloc((size_t)(N + 1) * 4);
  int*   nxt    = (int*)alloc((size_t)N * 4);
  int*   colx   = (int*)alloc((size_t)T * 4);
  int*   rowx   = (int*)alloc((size_t)T * 4);
  float* ew     = (float*)alloc((size_t)T * 4 * 4);
  int*   bsum   = (int*)alloc((size_t)nb * 4);
  int*   boff   = (int*)alloc((size_t)(nb + 1) * 4);
  unsigned short* wt1 = (unsigned short*)alloc(256 * 256 * 2);
  unsigned short* wt2 = (unsigned short*)alloc(256 * 256 * 2);

  dim3 blk(256);
  dim3 gemmGrid(Npad / 128, 2);
  int initRange = max(N, G * 256);
  int xtot = N * 256;

  // pre-passes + CSR build (shared by both layers) + init
  conv_w<<<dim3(256, 2), blk, 0, stream>>>(W1, W2, wt1, wt2);
  conv_x<<<(xtot / 4 + 255) / 256, blk, 0, stream>>>(x, xbuf, xtot);
  init_misc<<<(initRange + 255) / 256, blk, 0, stream>>>(count, pooled, N, G);
  hist_k<<<(E + 255) / 256, blk, 0, stream>>>(dst, count, E);
  scan_phaseA<<<nb, blk, 0, stream>>>(count, bsum, N);
  scan_phaseB<<<1, blk, 0, stream>>>(bsum, boff, nb);
  scan_phaseC<<<nb, blk, 0, stream>>>(count, boff, rowptr, nxt, N, nb);
  scatter_k<<<(T + 255) / 256, blk, 0, stream>>>(src, dst, nxt, colx, rowx, E, N);

  // ---- layer 1
  gemm_mfma<<<gemmGrid, blk, 0, stream>>>(xbuf, wt1, hbuf, N);
  attn_ab<<<(N + 15) / 16, blk, 0, stream>>>(hbuf, atts1, attd1, a_s, a_d, N);
  edge_w<<<(T + 255) / 256, blk, 0, stream>>>(colx, rowx, a_s, a_d, ew, T);
  agg<<<(N + 3) / 4, blk, 0, stream>>>(hbuf, rowptr, colx, ew, b1, fbuf, N);

  // ---- layer 2
  gemm_mfma<<<gemmGrid, blk, 0, stream>>>(fbuf, wt2, hbuf, N);
  attn_ab<<<(N + 15) / 16, blk, 0, stream>>>(hbuf, atts2, attd2, a_s, a_d, N);
  edge_w<<<(T + 255) / 256, blk, 0, stream>>>(colx, rowx, a_s, a_d, ew, T);
  agg<<<(N + 3) / 4, blk, 0, stream>>>(hbuf, rowptr, colx, ew, b2, fbuf, N);

  // ---- pool + head
  pool_max<<<(N + PNB - 1) / PNB, blk, 0, stream>>>(fbuf, batch, pooled, N);
  head_k<<<G, 128, 0, stream>>>(pooled, l1w, l1b, l2w, l2b, (float*)d_out);
}

// Round 10
// 245.438 us; speedup vs baseline: 3.6791x; 1.0449x over previous
//
#include <hip/hip_runtime.h>
#include <math.h>

#define LRELU_SLOPE 0.2f
#define NEG_INF __int_as_float(0xff800000)

typedef float f32x4 __attribute__((ext_vector_type(4)));
typedef _Float16 f16x8 __attribute__((ext_vector_type(8)));
typedef _Float16 f16x2 __attribute__((ext_vector_type(2)));
typedef unsigned short us8 __attribute__((ext_vector_type(8)));

__device__ __forceinline__ void atomicMaxF(float* addr, float v) {
  if (v >= 0.f) atomicMax((int*)addr, __float_as_int(v));
  else atomicMin((unsigned int*)addr, (unsigned int)__float_as_int(v));
}

__device__ __forceinline__ unsigned short f2h(float f) {
  _Float16 h = (_Float16)f;                       // v_cvt_f16_f32 (RNE)
  return __builtin_bit_cast(unsigned short, h);
}
__device__ __forceinline__ float2 up2(unsigned int u) {
  f16x2 h = __builtin_bit_cast(f16x2, u);
  return make_float2((float)h.x, (float)h.y);
}

// async global->LDS, 16B per lane; LDS dest must be the wave-uniform base
__device__ __forceinline__ void async_copy16(const unsigned short* g, unsigned short* l) {
  __builtin_amdgcn_global_load_lds(
      (const __attribute__((address_space(1))) void*)g,
      (__attribute__((address_space(3))) void*)l, 16, 0, 0);
}

// ---------------- W pre-pass: transpose + cvt to fp16 --------------------------
__global__ void conv_w(const float* __restrict__ W1, const float* __restrict__ W2,
                       unsigned short* __restrict__ t1, unsigned short* __restrict__ t2) {
  const float* W = blockIdx.y ? W2 : W1;
  unsigned short* t = blockIdx.y ? t2 : t1;
  int k = blockIdx.x, n = threadIdx.x;
  t[n * 256 + k] = f2h(W[k * 256 + n]);
}

// ---------------- X pre-pass: f32 -> fp16 --------------------------------------
__global__ __launch_bounds__(256) void conv_x(
    const float* __restrict__ x, unsigned short* __restrict__ xo, int total) {
  int base = (blockIdx.x * 256 + threadIdx.x) * 4;
  if (base >= total) return;
  float4 v = *(const float4*)(x + base);
  ushort4 h;
  h.x = f2h(v.x); h.y = f2h(v.y); h.z = f2h(v.z); h.w = f2h(v.w);
  *(ushort4*)(xo + base) = h;
}

// ---------------- GEMM + fused attention coefficients --------------------------
// Cfp16[M,256] = A[M,256] @ B^T (fp16 MFMA, f32 accum).
// Each wave's 64 output cols = one full head -> a_s/a_d computed exactly from
// f32 acc via 4 FMAs/row + 16-lane shfl reduce, written once (no atomics).
__global__ __launch_bounds__(256) void gemm_mfma(
    const unsigned short* __restrict__ A, const unsigned short* __restrict__ Bt,
    const float* __restrict__ att_s, const float* __restrict__ att_d,
    unsigned short* __restrict__ C, float* __restrict__ a_s,
    float* __restrict__ a_d, int M) {
  __shared__ __align__(16) unsigned short sA[128 * 64];
  __shared__ __align__(16) unsigned short sB[128 * 64];
  const int tid = threadIdx.x;
  const int lane = tid & 63;
  const int wave = tid >> 6;
  const int wr = wave >> 1, wc = wave & 1;
  const int bm = blockIdx.x * 128;
  const int bn = blockIdx.y * 128;

  const int srow = lane >> 3;                          // 0..7
  const int scol = (((lane & 7) ^ (lane >> 3)) << 3);  // swizzled ushort col

  f32x4 acc[4][4];
#pragma unroll
  for (int i = 0; i < 4; ++i)
#pragma unroll
    for (int j = 0; j < 4; ++j) acc[i][j] = (f32x4){0.f, 0.f, 0.f, 0.f};

  for (int kc = 0; kc < 256; kc += 64) {
#pragma unroll
    for (int i = 0; i < 4; ++i) {
      const int r0 = wave * 32 + i * 8;
      const size_t ga = (size_t)(bm + r0 + srow) * 256 + kc + scol;
      const size_t gb = (size_t)(bn + r0 + srow) * 256 + kc + scol;
      async_copy16(A + ga, &sA[r0 * 64]);
      async_copy16(Bt + gb, &sB[r0 * 64]);
    }
    __syncthreads();
#pragma unroll
    for (int ks = 0; ks < 64; ks += 32) {
      const int kbase = ks + ((lane >> 4) << 3);
      const int kx = kbase ^ ((lane & 7) << 3);
      f16x8 af[4], bf[4];
#pragma unroll
      for (int f = 0; f < 4; ++f) {
        int ar = wr * 64 + f * 16 + (lane & 15);
        int br = wc * 64 + f * 16 + (lane & 15);
        af[f] = __builtin_bit_cast(f16x8, *(const us8*)&sA[ar * 64 + kx]);
        bf[f] = __builtin_bit_cast(f16x8, *(const us8*)&sB[br * 64 + kx]);
      }
#pragma unroll
      for (int i = 0; i < 4; ++i)
#pragma unroll
        for (int j = 0; j < 4; ++j)
          acc[i][j] = __builtin_amdgcn_mfma_f32_16x16x32_f16(af[i], bf[j], acc[i][j], 0, 0, 0);
    }
    __syncthreads();
  }

  // ---- fused attention coefficients: head = blockIdx.y*2 + wc
  const int head = blockIdx.y * 2 + wc;
  float ws[4], wd[4];
#pragma unroll
  for (int j = 0; j < 4; ++j) {
    ws[j] = att_s[head * 64 + j * 16 + (lane & 15)];
    wd[j] = att_d[head * 64 + j * 16 + (lane & 15)];
  }
#pragma unroll
  for (int i = 0; i < 4; ++i) {
#pragma unroll
    for (int r = 0; r < 4; ++r) {
      float ps = 0.f, pd = 0.f;
#pragma unroll
      for (int j = 0; j < 4; ++j) {
        ps = fmaf(acc[i][j][r], ws[j], ps);
        pd = fmaf(acc[i][j][r], wd[j], pd);
      }
#pragma unroll
      for (int off = 1; off < 16; off <<= 1) {
        ps += __shfl_xor(ps, off);
        pd += __shfl_xor(pd, off);
      }
      int row = bm + wr * 64 + i * 16 + ((lane >> 4) << 2) + r;
      if ((lane & 15) == 0 && row < M) {
        a_s[row * 4 + head] = ps;
        a_d[row * 4 + head] = pd;
      }
    }
  }

  // ---- C store (fp16). m=(lane>>4)*4+reg, n=lane&15 within each 16x16 frag
#pragma unroll
  for (int i = 0; i < 4; ++i) {
#pragma unroll
    for (int r = 0; r < 4; ++r) {
      int row = bm + wr * 64 + i * 16 + ((lane >> 4) << 2) + r;
      if (row < M) {
#pragma unroll
        for (int j = 0; j < 4; ++j)
          C[(size_t)row * 256 + bn + wc * 64 + j * 16 + (lane & 15)] = f2h(acc[i][j][r]);
      }
    }
  }
}

// ---------------- misc init ---------------------------------------------------
__global__ void init_misc(int* __restrict__ count, float* __restrict__ pooled,
                          int N_, int G_) {
  int t = blockIdx.x * 256 + threadIdx.x;
  if (t < N_) count[t] = 1;                 // self loop
  if (t < G_ * 256) pooled[t] = NEG_INF;
}

// ---------------- CSR build ----------------------------------------------------
__global__ void hist_k(const int* __restrict__ dst, int* __restrict__ count, int E_) {
  int t = blockIdx.x * 256 + threadIdx.x;
  if (t < E_) atomicAdd(&count[dst[t]], 1);
}

#define SCB 1024

__global__ __launch_bounds__(256) void scan_phaseA(
    const int* __restrict__ count, int* __restrict__ bsum, int N_) {
  int t = threadIdx.x;
  int base = blockIdx.x * SCB + t * 4;
  int s = 0;
  if (base + 3 < N_) {
    int4 v = *(const int4*)(count + base);
    s = v.x + v.y + v.z + v.w;
  } else {
#pragma unroll
    for (int k = 0; k < 4; ++k) if (base + k < N_) s += count[base + k];
  }
#pragma unroll
  for (int off = 32; off > 0; off >>= 1) s += __shfl_xor(s, off);
  __shared__ int red[4];
  int wave = t >> 6, lane = t & 63;
  if (lane == 0) red[wave] = s;
  __syncthreads();
  if (t == 0) bsum[blockIdx.x] = red[0] + red[1] + red[2] + red[3];
}

__global__ __launch_bounds__(256) void scan_phaseB(
    const int* __restrict__ bsum, int* __restrict__ boff, int nb) {
  __shared__ int tmp[256];
  int t = threadIdx.x;
  int v = (t < nb) ? bsum[t] : 0;
  tmp[t] = v;
  __syncthreads();
  for (int off = 1; off < 256; off <<= 1) {
    int u = (t >= off) ? tmp[t - off] : 0;
    __syncthreads();
    tmp[t] += u;
    __syncthreads();
  }
  if (t < nb) boff[t] = tmp[t] - v;  // exclusive
  if (t == 0) boff[nb] = tmp[255];   // grand total
}

__global__ __launch_bounds__(256) void scan_phaseC(
    const int* __restrict__ count, const int* __restrict__ boff,
    int* __restrict__ rowptr, int* __restrict__ nxt, int N_, int nb) {
  __shared__ int tmp[256];
  int t = threadIdx.x;
  int base = blockIdx.x * SCB + t * 4;
  int4 v = make_int4(0, 0, 0, 0);
  if (base + 3 < N_) {
    v = *(const int4*)(count + base);
  } else {
    if (base + 0 < N_) v.x = count[base + 0];
    if (base + 1 < N_) v.y = count[base + 1];
    if (base + 2 < N_) v.z = count[base + 2];
  }
  int s = v.x + v.y + v.z + v.w;
  tmp[t] = s;
  __syncthreads();
  for (int off = 1; off < 256; off <<= 1) {
    int u = (t >= off) ? tmp[t - off] : 0;
    __syncthreads();
    tmp[t] += u;
    __syncthreads();
  }
  int run = boff[blockIdx.x] + tmp[t] - s;
  int4 rp;
  rp.x = run; run += v.x;
  rp.y = run; run += v.y;
  rp.z = run; run += v.z;
  rp.w = run;
  if (base + 3 < N_) {
    *(int4*)(rowptr + base) = rp;
    *(int4*)(nxt + base) = rp;
  } else {
    if (base + 0 < N_) { rowptr[base + 0] = rp.x; nxt[base + 0] = rp.x; }
    if (base + 1 < N_) { rowptr[base + 1] = rp.y; nxt[base + 1] = rp.y; }
    if (base + 2 < N_) { rowptr[base + 2] = rp.z; nxt[base + 2] = rp.z; }
  }
  if (blockIdx.x == 0 && t == 0) rowptr[N_] = boff[nb];
}

__global__ void scatter_k(const int* __restrict__ src, const int* __restrict__ dst,
                          int* __restrict__ nxt, int* __restrict__ colx,
                          int* __restrict__ rowx, int E_, int N_) {
  int t = blockIdx.x * 256 + threadIdx.x;
  if (t >= E_ + N_) return;
  int s = (t < E_) ? src[t] : (t - E_);
  int d = (t < E_) ? dst[t] : (t - E_);
  int pos = atomicAdd(&nxt[d], 1);
  colx[pos] = s;
  rowx[pos] = d;
}

// ---------------- per-slot softmax weights: ew[j][4] ---------------------------
__global__ __launch_bounds__(256) void edge_w(
    const int* __restrict__ colx, const int* __restrict__ rowx,
    const float* __restrict__ a_s, const float* __restrict__ a_d,
    float* __restrict__ ew, int T) {
  int t = blockIdx.x * 256 + threadIdx.x;
  if (t >= T) return;
  int s = colx[t], d = rowx[t];
  float4 as4 = *(const float4*)(a_s + (size_t)s * 4);
  float4 ad4 = *(const float4*)(a_d + (size_t)d * 4);
  float l;
  float4 w;
  l = as4.x + ad4.x; l = l > 0.f ? l : LRELU_SLOPE * l; w.x = __expf(l);
  l = as4.y + ad4.y; l = l > 0.f ? l : LRELU_SLOPE * l; w.y = __expf(l);
  l = as4.z + ad4.z; l = l > 0.f ? l : LRELU_SLOPE * l; w.z = __expf(l);
  l = as4.w + ad4.w; l = l > 0.f ? l : LRELU_SLOPE * l; w.w = __expf(l);
  *(float4*)(ew + (size_t)t * 4) = w;
}

// ---------------- aggregation: wave-per-node, 8x-unrolled gather loop ---------
__global__ __launch_bounds__(256) void agg(
    const unsigned short* __restrict__ h, const int* __restrict__ rowptr,
    const int* __restrict__ colx, const float* __restrict__ ew,
    const float* __restrict__ bias, unsigned short* __restrict__ out, int N_) {
  const int wave = threadIdx.x >> 6;
  const int lane = threadIdx.x & 63;
  const int n = blockIdx.x * 4 + wave;
  if (n >= N_) return;
  const int head = lane >> 4;           // lane owns channels [4*lane, 4*lane+4)
  const size_t coff = (size_t)lane * 4;
  const int e0 = rowptr[n], e1 = rowptr[n + 1];
  float4 acc = make_float4(0.f, 0.f, 0.f, 0.f);
  float dsum = 0.f;
  int j = e0;
  for (; j + 8 <= e1; j += 8) {
    int sx[8];
    float wv[8];
    uint2 gv[8];
#pragma unroll
    for (int u = 0; u < 8; ++u) sx[u] = colx[j + u];
#pragma unroll
    for (int u = 0; u < 8; ++u) wv[u] = ew[(size_t)(j + u) * 4 + head];
#pragma unroll
    for (int u = 0; u < 8; ++u) gv[u] = *(const uint2*)(h + (size_t)sx[u] * 256 + coff);
#pragma unroll
    for (int u = 0; u < 8; ++u) {
      dsum += wv[u];
      float2 a = up2(gv[u].x), b = up2(gv[u].y);
      acc.x = fmaf(wv[u], a.x, acc.x); acc.y = fmaf(wv[u], a.y, acc.y);
      acc.z = fmaf(wv[u], b.x, acc.z); acc.w = fmaf(wv[u], b.y, acc.w);
    }
  }
  for (; j < e1; ++j) {
    int s = colx[j];
    float w = ew[(size_t)j * 4 + head];
    uint2 g = *(const uint2*)(h + (size_t)s * 256 + coff);
    dsum += w;
    float2 a = up2(g.x), b = up2(g.y);
    acc.x = fmaf(w, a.x, acc.x); acc.y = fmaf(w, a.y, acc.y);
    acc.z = fmaf(w, b.x, acc.z); acc.w = fmaf(w, b.y, acc.w);
  }
  const float inv = 1.f / (dsum + 1e-16f);
  const float4 b4 = *(const float4*)(bias + coff);
  float v;
  float4 o;
  v = acc.x * inv + b4.x; o.x = v > 0.f ? v : expm1f(v);
  v = acc.y * inv + b4.y; o.y = v > 0.f ? v : expm1f(v);
  v = acc.z * inv + b4.z; o.z = v > 0.f ? v : expm1f(v);
  v = acc.w * inv + b4.w; o.w = v > 0.f ? v : expm1f(v);
  ushort4 oh;
  oh.x = f2h(o.x); oh.y = f2h(o.y); oh.z = f2h(o.z); oh.w = f2h(o.w);
  *(ushort4*)(out + (size_t)n * 256 + coff) = oh;
}

// ---------------- graph max-pool from fp16 (batch is sorted) -------------------
#define PNB 32
__global__ __launch_bounds__(256) void pool_max(
    const unsigned short* __restrict__ fb, const int* __restrict__ batch,
    float* __restrict__ pooled, int N_) {
  const int c2 = threadIdx.x & 127;        // channels 2*c2, 2*c2+1
  const int slot = threadIdx.x >> 7;       // 2 slots x 16 nodes
  const int ns = blockIdx.x * PNB + slot * 16;
  const int ne = min(ns + 16, N_);
  if (ns >= N_) return;
  float r0 = NEG_INF, r1 = NEG_INF;
  int g = batch[ns];
#pragma unroll 4
  for (int n = ns; n < ne; ++n) {
    int gn = batch[n];
    unsigned int w = *(const unsigned int*)(fb + (size_t)n * 256 + c2 * 2);
    if (gn != g) {
      atomicMaxF(&pooled[(size_t)g * 256 + c2 * 2], r0);
      atomicMaxF(&pooled[(size_t)g * 256 + c2 * 2 + 1], r1);
      r0 = r1 = NEG_INF; g = gn;
    }
    float2 xv = up2(w);
    r0 = fmaxf(r0, xv.x);
    r1 = fmaxf(r1, xv.y);
  }
  atomicMaxF(&pooled[(size_t)g * 256 + c2 * 2], r0);
  atomicMaxF(&pooled[(size_t)g * 256 + c2 * 2 + 1], r1);
}

// ---------------- head: fixup -inf, lin1 (256->128), lin2 (128->2) ------------
__global__ __launch_bounds__(128) void head_k(
    const float* __restrict__ pooled, const float* __restrict__ w1,
    const float* __restrict__ b1, const float* __restrict__ w2,
    const float* __restrict__ b2, float* __restrict__ out) {
  __shared__ float ps[256];
  __shared__ float z1[128];
  int g = blockIdx.x;
  int t = threadIdx.x;
  for (int i = t; i < 256; i += 128) {
    float v = pooled[(size_t)g * 256 + i];
    if (v < -1e37f) v = 0.f;   // empty-graph guard (isneginf -> 0)
    ps[i] = v;
  }
  __syncthreads();
  float a = b1[t];
  for (int k = 0; k < 256; ++k) a = fmaf(ps[k], w1[k * 128 + t], a);
  z1[t] = a;
  __syncthreads();
  if (t < 2) {
    float a2 = b2[t];
    for (int j = 0; j < 128; ++j) a2 = fmaf(z1[j], w2[j * 2 + t], a2);
    out[g * 2 + t] = a2;
  }
}

// ---------------- driver --------------------------------------------------------
extern "C" void kernel_launch(void* const* d_in, const int* in_sizes, int n_in,
                              void* d_out, int out_size, void* d_ws, size_t ws_size,
                              hipStream_t stream) {
  const int N = in_sizes[2];         // batch array length = #nodes
  const int E = in_sizes[1] / 2;     // edge_index is [2,E]
  const int G = out_size / 2;        // output [G,2]
  const int T = E + N;               // CSR slots (incl. self loops)
  const int Npad = ((N + 127) / 128) * 128;

  const float* x     = (const float*)d_in[0];
  const int*   ei    = (const int*)d_in[1];
  const int*   src   = ei;
  const int*   dst   = ei + E;
  const int*   batch = (const int*)d_in[2];
  const float* W1    = (const float*)d_in[3];
  const float* atts1 = (const float*)d_in[4];
  const float* attd1 = (const float*)d_in[5];
  const float* b1    = (const float*)d_in[6];
  const float* W2    = (const float*)d_in[7];
  const float* atts2 = (const float*)d_in[8];
  const float* attd2 = (const float*)d_in[9];
  const float* b2    = (const float*)d_in[10];
  const float* l1w   = (const float*)d_in[11];
  const float* l1b   = (const float*)d_in[12];
  const float* l2w   = (const float*)d_in[13];
  const float* l2b   = (const float*)d_in[14];

  uintptr_t p = (uintptr_t)d_ws;
  auto alloc = [&](size_t bytes) -> void* {
    p = (p + 255) & ~(uintptr_t)255;
    void* r = (void*)p;
    p += bytes;
    return r;
  };
  const int nb = (N + SCB - 1) / SCB;
  unsigned short* hbuf = (unsigned short*)alloc((size_t)N * 256 * 2);     // fp16 h (GEMM out)
  unsigned short* xbuf = (unsigned short*)alloc((size_t)Npad * 256 * 2);  // fp16 x
  unsigned short* fbuf = (unsigned short*)alloc((size_t)Npad * 256 * 2);  // fp16 agg out
  float* a_s    = (float*)alloc((size_t)N * 4 * 4);
  float* a_d    = (float*)alloc((size_t)N * 4 * 4);
  float* pooled = (float*)alloc((size_t)G * 256 * 4);
  int*   count  = (int*)alloc((size_t)N * 4);
  int*   rowptr = (int*)alloc((size_t)(N + 1) * 4);
  int*   nxt    = (int*)alloc((size_t)N * 4);
  int*   colx   = (int*)alloc((size_t)T * 4);
  int*   rowx   = (int*)alloc((size_t)T * 4);
  float* ew     = (float*)alloc((size_t)T * 4 * 4);
  int*   bsum   = (int*)alloc((size_t)nb * 4);
  int*   boff   = (int*)alloc((size_t)(nb + 1) * 4);
  unsigned short* wt1 = (unsigned short*)alloc(256 * 256 * 2);
  unsigned short* wt2 = (unsigned short*)alloc(256 * 256 * 2);

  dim3 blk(256);
  dim3 gemmGrid(Npad / 128, 2);
  int initRange = max(N, G * 256);
  int xtot = N * 256;

  // pre-passes + CSR build (shared by both layers) + init
  conv_w<<<dim3(256, 2), blk, 0, stream>>>(W1, W2, wt1, wt2);
  conv_x<<<(xtot / 4 + 255) / 256, blk, 0, stream>>>(x, xbuf, xtot);
  init_misc<<<(initRange + 255) / 256, blk, 0, stream>>>(count, pooled, N, G);
  hist_k<<<(E + 255) / 256, blk, 0, stream>>>(dst, count, E);
  scan_phaseA<<<nb, blk, 0, stream>>>(count, bsum, N);
  scan_phaseB<<<1, blk, 0, stream>>>(bsum, boff, nb);
  scan_phaseC<<<nb, blk, 0, stream>>>(count, boff, rowptr, nxt, N, nb);
  scatter_k<<<(T + 255) / 256, blk, 0, stream>>>(src, dst, nxt, colx, rowx, E, N);

  // ---- layer 1
  gemm_mfma<<<gemmGrid, blk, 0, stream>>>(xbuf, wt1, atts1, attd1, hbuf, a_s, a_d, N);
  edge_w<<<(T + 255) / 256, blk, 0, stream>>>(colx, rowx, a_s, a_d, ew, T);
  agg<<<(N + 3) / 4, blk, 0, stream>>>(hbuf, rowptr, colx, ew, b1, fbuf, N);

  // ---- layer 2
  gemm_mfma<<<gemmGrid, blk, 0, stream>>>(fbuf, wt2, atts2, attd2, hbuf, a_s, a_d, N);
  edge_w<<<(T + 255) / 256, blk, 0, stream>>>(colx, rowx, a_s, a_d, ew, T);
  agg<<<(N + 3) / 4, blk, 0, stream>>>(hbuf, rowptr, colx, ew, b2, fbuf, N);

  // ---- pool + head
  pool_max<<<(N + PNB - 1) / PNB, blk, 0, stream>>>(fbuf, batch, pooled, N);
  head_k<<<G, 128, 0, stream>>>(pooled, l1w, l1b, l2w, l2b, (float*)d_out);
}

// Round 11
// 238.852 us; speedup vs baseline: 3.7806x; 1.0276x over previous
//
#include <hip/hip_runtime.h>
#include <math.h>

#define LRELU_SLOPE 0.2f
#define NEG_INF __int_as_float(0xff800000)

typedef float f32x4 __attribute__((ext_vector_type(4)));
typedef _Float16 f16x8 __attribute__((ext_vector_type(8)));
typedef _Float16 f16x2 __attribute__((ext_vector_type(2)));
typedef unsigned short us8 __attribute__((ext_vector_type(8)));

__device__ __forceinline__ void atomicMaxF(float* addr, float v) {
  if (v >= 0.f) atomicMax((int*)addr, __float_as_int(v));
  else atomicMin((unsigned int*)addr, (unsigned int)__float_as_int(v));
}

__device__ __forceinline__ unsigned short f2h(float f) {
  _Float16 h = (_Float16)f;                       // v_cvt_f16_f32 (RNE)
  return __builtin_bit_cast(unsigned short, h);
}
__device__ __forceinline__ float2 up2(unsigned int u) {
  f16x2 h = __builtin_bit_cast(f16x2, u);
  return make_float2((float)h.x, (float)h.y);
}

// async global->LDS, 16B per lane; LDS dest must be the wave-uniform base
__device__ __forceinline__ void async_copy16(const unsigned short* g, unsigned short* l) {
  __builtin_amdgcn_global_load_lds(
      (const __attribute__((address_space(1))) void*)g,
      (__attribute__((address_space(3))) void*)l, 16, 0, 0);
}

// ---------------- W pre-pass: transpose + cvt to fp16 --------------------------
__global__ void conv_w(const float* __restrict__ W1, const float* __restrict__ W2,
                       unsigned short* __restrict__ t1, unsigned short* __restrict__ t2) {
  const float* W = blockIdx.y ? W2 : W1;
  unsigned short* t = blockIdx.y ? t2 : t1;
  int k = blockIdx.x, n = threadIdx.x;
  t[n * 256 + k] = f2h(W[k * 256 + n]);
}

// ---------------- X pre-pass: f32 -> fp16 --------------------------------------
__global__ __launch_bounds__(256) void conv_x(
    const float* __restrict__ x, unsigned short* __restrict__ xo, int total) {
  int base = (blockIdx.x * 256 + threadIdx.x) * 4;
  if (base >= total) return;
  float4 v = *(const float4*)(x + base);
  ushort4 h;
  h.x = f2h(v.x); h.y = f2h(v.y); h.z = f2h(v.z); h.w = f2h(v.w);
  *(ushort4*)(xo + base) = h;
}

// ---------------- GEMM + fused attention coefficients --------------------------
// Cfp16[M,256] = A[M,256] @ B^T (fp16 MFMA, f32 accum).
// Each wave's 64 output cols = one full head -> a_s/a_d computed exactly from
// f32 acc via 4 FMAs/row + 16-lane shfl reduce, written once (no atomics).
__global__ __launch_bounds__(256) void gemm_mfma(
    const unsigned short* __restrict__ A, const unsigned short* __restrict__ Bt,
    const float* __restrict__ att_s, const float* __restrict__ att_d,
    unsigned short* __restrict__ C, float* __restrict__ a_s,
    float* __restrict__ a_d, int M) {
  __shared__ __align__(16) unsigned short sA[128 * 64];
  __shared__ __align__(16) unsigned short sB[128 * 64];
  const int tid = threadIdx.x;
  const int lane = tid & 63;
  const int wave = tid >> 6;
  const int wr = wave >> 1, wc = wave & 1;
  const int bm = blockIdx.x * 128;
  const int bn = blockIdx.y * 128;

  const int srow = lane >> 3;                          // 0..7
  const int scol = (((lane & 7) ^ (lane >> 3)) << 3);  // swizzled ushort col

  f32x4 acc[4][4];
#pragma unroll
  for (int i = 0; i < 4; ++i)
#pragma unroll
    for (int j = 0; j < 4; ++j) acc[i][j] = (f32x4){0.f, 0.f, 0.f, 0.f};

  for (int kc = 0; kc < 256; kc += 64) {
#pragma unroll
    for (int i = 0; i < 4; ++i) {
      const int r0 = wave * 32 + i * 8;
      const size_t ga = (size_t)(bm + r0 + srow) * 256 + kc + scol;
      const size_t gb = (size_t)(bn + r0 + srow) * 256 + kc + scol;
      async_copy16(A + ga, &sA[r0 * 64]);
      async_copy16(Bt + gb, &sB[r0 * 64]);
    }
    __syncthreads();
#pragma unroll
    for (int ks = 0; ks < 64; ks += 32) {
      const int kbase = ks + ((lane >> 4) << 3);
      const int kx = kbase ^ ((lane & 7) << 3);
      f16x8 af[4], bf[4];
#pragma unroll
      for (int f = 0; f < 4; ++f) {
        int ar = wr * 64 + f * 16 + (lane & 15);
        int br = wc * 64 + f * 16 + (lane & 15);
        af[f] = __builtin_bit_cast(f16x8, *(const us8*)&sA[ar * 64 + kx]);
        bf[f] = __builtin_bit_cast(f16x8, *(const us8*)&sB[br * 64 + kx]);
      }
#pragma unroll
      for (int i = 0; i < 4; ++i)
#pragma unroll
        for (int j = 0; j < 4; ++j)
          acc[i][j] = __builtin_amdgcn_mfma_f32_16x16x32_f16(af[i], bf[j], acc[i][j], 0, 0, 0);
    }
    __syncthreads();
  }

  // ---- fused attention coefficients: head = blockIdx.y*2 + wc
  const int head = blockIdx.y * 2 + wc;
  float ws[4], wd[4];
#pragma unroll
  for (int j = 0; j < 4; ++j) {
    ws[j] = att_s[head * 64 + j * 16 + (lane & 15)];
    wd[j] = att_d[head * 64 + j * 16 + (lane & 15)];
  }
#pragma unroll
  for (int i = 0; i < 4; ++i) {
#pragma unroll
    for (int r = 0; r < 4; ++r) {
      float ps = 0.f, pd = 0.f;
#pragma unroll
      for (int j = 0; j < 4; ++j) {
        ps = fmaf(acc[i][j][r], ws[j], ps);
        pd = fmaf(acc[i][j][r], wd[j], pd);
      }
#pragma unroll
      for (int off = 1; off < 16; off <<= 1) {
        ps += __shfl_xor(ps, off);
        pd += __shfl_xor(pd, off);
      }
      int row = bm + wr * 64 + i * 16 + ((lane >> 4) << 2) + r;
      if ((lane & 15) == 0 && row < M) {
        a_s[row * 4 + head] = ps;
        a_d[row * 4 + head] = pd;
      }
    }
  }

  // ---- C store (fp16). m=(lane>>4)*4+reg, n=lane&15 within each 16x16 frag
#pragma unroll
  for (int i = 0; i < 4; ++i) {
#pragma unroll
    for (int r = 0; r < 4; ++r) {
      int row = bm + wr * 64 + i * 16 + ((lane >> 4) << 2) + r;
      if (row < M) {
#pragma unroll
        for (int j = 0; j < 4; ++j)
          C[(size_t)row * 256 + bn + wc * 64 + j * 16 + (lane & 15)] = f2h(acc[i][j][r]);
      }
    }
  }
}

// ---------------- misc init ---------------------------------------------------
__global__ void init_misc(int* __restrict__ count, float* __restrict__ pooled,
                          int N_, int G_) {
  int t = blockIdx.x * 256 + threadIdx.x;
  if (t < N_) count[t] = 1;                 // self loop
  if (t < G_ * 256) pooled[t] = NEG_INF;
}

// ---------------- CSR build ----------------------------------------------------
__global__ void hist_k(const int* __restrict__ dst, int* __restrict__ count, int E_) {
  int t = blockIdx.x * 256 + threadIdx.x;
  if (t < E_) atomicAdd(&count[dst[t]], 1);
}

#define SCB 1024

__global__ __launch_bounds__(256) void scan_phaseA(
    const int* __restrict__ count, int* __restrict__ bsum, int N_) {
  int t = threadIdx.x;
  int base = blockIdx.x * SCB + t * 4;
  int s = 0;
  if (base + 3 < N_) {
    int4 v = *(const int4*)(count + base);
    s = v.x + v.y + v.z + v.w;
  } else {
#pragma unroll
    for (int k = 0; k < 4; ++k) if (base + k < N_) s += count[base + k];
  }
#pragma unroll
  for (int off = 32; off > 0; off >>= 1) s += __shfl_xor(s, off);
  __shared__ int red[4];
  int wave = t >> 6, lane = t & 63;
  if (lane == 0) red[wave] = s;
  __syncthreads();
  if (t == 0) bsum[blockIdx.x] = red[0] + red[1] + red[2] + red[3];
}

__global__ __launch_bounds__(256) void scan_phaseB(
    const int* __restrict__ bsum, int* __restrict__ boff, int nb) {
  __shared__ int tmp[256];
  int t = threadIdx.x;
  int v = (t < nb) ? bsum[t] : 0;
  tmp[t] = v;
  __syncthreads();
  for (int off = 1; off < 256; off <<= 1) {
    int u = (t >= off) ? tmp[t - off] : 0;
    __syncthreads();
    tmp[t] += u;
    __syncthreads();
  }
  if (t < nb) boff[t] = tmp[t] - v;  // exclusive
  if (t == 0) boff[nb] = tmp[255];   // grand total
}

__global__ __launch_bounds__(256) void scan_phaseC(
    const int* __restrict__ count, const int* __restrict__ boff,
    int* __restrict__ rowptr, int* __restrict__ nxt, int N_, int nb) {
  __shared__ int tmp[256];
  int t = threadIdx.x;
  int base = blockIdx.x * SCB + t * 4;
  int4 v = make_int4(0, 0, 0, 0);
  if (base + 3 < N_) {
    v = *(const int4*)(count + base);
  } else {
    if (base + 0 < N_) v.x = count[base + 0];
    if (base + 1 < N_) v.y = count[base + 1];
    if (base + 2 < N_) v.z = count[base + 2];
  }
  int s = v.x + v.y + v.z + v.w;
  tmp[t] = s;
  __syncthreads();
  for (int off = 1; off < 256; off <<= 1) {
    int u = (t >= off) ? tmp[t - off] : 0;
    __syncthreads();
    tmp[t] += u;
    __syncthreads();
  }
  int run = boff[blockIdx.x] + tmp[t] - s;
  int4 rp;
  rp.x = run; run += v.x;
  rp.y = run; run += v.y;
  rp.z = run; run += v.z;
  rp.w = run;
  if (base + 3 < N_) {
    *(int4*)(rowptr + base) = rp;
    *(int4*)(nxt + base) = rp;
  } else {
    if (base + 0 < N_) { rowptr[base + 0] = rp.x; nxt[base + 0] = rp.x; }
    if (base + 1 < N_) { rowptr[base + 1] = rp.y; nxt[base + 1] = rp.y; }
    if (base + 2 < N_) { rowptr[base + 2] = rp.z; nxt[base + 2] = rp.z; }
  }
  if (blockIdx.x == 0 && t == 0) rowptr[N_] = boff[nb];
}

__global__ void scatter_k(const int* __restrict__ src, const int* __restrict__ dst,
                          int* __restrict__ nxt, int* __restrict__ colx,
                          int* __restrict__ rowx, int E_, int N_) {
  int t = blockIdx.x * 256 + threadIdx.x;
  if (t >= E_ + N_) return;
  int s = (t < E_) ? src[t] : (t - E_);
  int d = (t < E_) ? dst[t] : (t - E_);
  int pos = atomicAdd(&nxt[d], 1);
  colx[pos] = s;
  rowx[pos] = d;
}

// ---------------- per-slot softmax weights, head-major: ewt[head][slot] --------
__global__ __launch_bounds__(256) void edge_w(
    const int* __restrict__ colx, const int* __restrict__ rowx,
    const float* __restrict__ a_s, const float* __restrict__ a_d,
    float* __restrict__ ewt, int T) {
  int t = blockIdx.x * 256 + threadIdx.x;
  if (t >= T) return;
  int s = colx[t], d = rowx[t];
  float4 as4 = *(const float4*)(a_s + (size_t)s * 4);
  float4 ad4 = *(const float4*)(a_d + (size_t)d * 4);
  float l;
  l = as4.x + ad4.x; l = l > 0.f ? l : LRELU_SLOPE * l; ewt[0 * (size_t)T + t] = __expf(l);
  l = as4.y + ad4.y; l = l > 0.f ? l : LRELU_SLOPE * l; ewt[1 * (size_t)T + t] = __expf(l);
  l = as4.z + ad4.z; l = l > 0.f ? l : LRELU_SLOPE * l; ewt[2 * (size_t)T + t] = __expf(l);
  l = as4.w + ad4.w; l = l > 0.f ? l : LRELU_SLOPE * l; ewt[3 * (size_t)T + t] = __expf(l);
}

// ---------------- aggregation: wave-per-node, 4x unroll, vectorized ew/colx ---
__global__ __launch_bounds__(256) void agg(
    const unsigned short* __restrict__ h, const int* __restrict__ rowptr,
    const int* __restrict__ colx, const float* __restrict__ ewt, int T,
    const float* __restrict__ bias, unsigned short* __restrict__ out, int N_) {
  const int wave = threadIdx.x >> 6;
  const int lane = threadIdx.x & 63;
  const int n = blockIdx.x * 4 + wave;
  if (n >= N_) return;
  const int head = lane >> 4;           // lane owns channels [4*lane, 4*lane+4)
  const float* ewh = ewt + (size_t)head * T;
  const size_t coff = (size_t)lane * 4;
  const int e0 = rowptr[n], e1 = rowptr[n + 1];
  float4 acc = make_float4(0.f, 0.f, 0.f, 0.f);
  float dsum = 0.f;
  int j = e0;
  // peel to 4-slot alignment (16B for int4/float4 loads)
  for (; j < e1 && (j & 3); ++j) {
    int s = colx[j];
    float w = ewh[j];
    uint2 g = *(const uint2*)(h + (size_t)s * 256 + coff);
    dsum += w;
    float2 a = up2(g.x), b = up2(g.y);
    acc.x = fmaf(w, a.x, acc.x); acc.y = fmaf(w, a.y, acc.y);
    acc.z = fmaf(w, b.x, acc.z); acc.w = fmaf(w, b.y, acc.w);
  }
  for (; j + 4 <= e1; j += 4) {
    int4 s4 = *(const int4*)(colx + j);
    float4 w4 = *(const float4*)(ewh + j);
    uint2 g0 = *(const uint2*)(h + (size_t)s4.x * 256 + coff);
    uint2 g1 = *(const uint2*)(h + (size_t)s4.y * 256 + coff);
    uint2 g2 = *(const uint2*)(h + (size_t)s4.z * 256 + coff);
    uint2 g3 = *(const uint2*)(h + (size_t)s4.w * 256 + coff);
    dsum += (w4.x + w4.y) + (w4.z + w4.w);
    float2 a0 = up2(g0.x), b0 = up2(g0.y);
    float2 a1 = up2(g1.x), b1 = up2(g1.y);
    float2 a2 = up2(g2.x), b2 = up2(g2.y);
    float2 a3 = up2(g3.x), b3 = up2(g3.y);
    acc.x = fmaf(w4.x, a0.x, acc.x); acc.y = fmaf(w4.x, a0.y, acc.y);
    acc.z = fmaf(w4.x, b0.x, acc.z); acc.w = fmaf(w4.x, b0.y, acc.w);
    acc.x = fmaf(w4.y, a1.x, acc.x); acc.y = fmaf(w4.y, a1.y, acc.y);
    acc.z = fmaf(w4.y, b1.x, acc.z); acc.w = fmaf(w4.y, b1.y, acc.w);
    acc.x = fmaf(w4.z, a2.x, acc.x); acc.y = fmaf(w4.z, a2.y, acc.y);
    acc.z = fmaf(w4.z, b2.x, acc.z); acc.w = fmaf(w4.z, b2.y, acc.w);
    acc.x = fmaf(w4.w, a3.x, acc.x); acc.y = fmaf(w4.w, a3.y, acc.y);
    acc.z = fmaf(w4.w, b3.x, acc.z); acc.w = fmaf(w4.w, b3.y, acc.w);
  }
  for (; j < e1; ++j) {
    int s = colx[j];
    float w = ewh[j];
    uint2 g = *(const uint2*)(h + (size_t)s * 256 + coff);
    dsum += w;
    float2 a = up2(g.x), b = up2(g.y);
    acc.x = fmaf(w, a.x, acc.x); acc.y = fmaf(w, a.y, acc.y);
    acc.z = fmaf(w, b.x, acc.z); acc.w = fmaf(w, b.y, acc.w);
  }
  const float inv = 1.f / (dsum + 1e-16f);
  const float4 b4 = *(const float4*)(bias + coff);
  float v;
  float4 o;
  v = acc.x * inv + b4.x; o.x = v > 0.f ? v : expm1f(v);
  v = acc.y * inv + b4.y; o.y = v > 0.f ? v : expm1f(v);
  v = acc.z * inv + b4.z; o.z = v > 0.f ? v : expm1f(v);
  v = acc.w * inv + b4.w; o.w = v > 0.f ? v : expm1f(v);
  ushort4 oh;
  oh.x = f2h(o.x); oh.y = f2h(o.y); oh.z = f2h(o.z); oh.w = f2h(o.w);
  *(ushort4*)(out + (size_t)n * 256 + coff) = oh;
}

// ---------------- graph max-pool from fp16 (batch is sorted) -------------------
#define PNB 32
__global__ __launch_bounds__(256) void pool_max(
    const unsigned short* __restrict__ fb, const int* __restrict__ batch,
    float* __restrict__ pooled, int N_) {
  const int c2 = threadIdx.x & 127;        // channels 2*c2, 2*c2+1
  const int slot = threadIdx.x >> 7;       // 2 slots x 16 nodes
  const int ns = blockIdx.x * PNB + slot * 16;
  const int ne = min(ns + 16, N_);
  if (ns >= N_) return;
  float r0 = NEG_INF, r1 = NEG_INF;
  int g = batch[ns];
#pragma unroll 4
  for (int n = ns; n < ne; ++n) {
    int gn = batch[n];
    unsigned int w = *(const unsigned int*)(fb + (size_t)n * 256 + c2 * 2);
    if (gn != g) {
      atomicMaxF(&pooled[(size_t)g * 256 + c2 * 2], r0);
      atomicMaxF(&pooled[(size_t)g * 256 + c2 * 2 + 1], r1);
      r0 = r1 = NEG_INF; g = gn;
    }
    float2 xv = up2(w);
    r0 = fmaxf(r0, xv.x);
    r1 = fmaxf(r1, xv.y);
  }
  atomicMaxF(&pooled[(size_t)g * 256 + c2 * 2], r0);
  atomicMaxF(&pooled[(size_t)g * 256 + c2 * 2 + 1], r1);
}

// ---------------- head: fixup -inf, lin1 (256->128), lin2 (128->2) ------------
__global__ __launch_bounds__(128) void head_k(
    const float* __restrict__ pooled, const float* __restrict__ w1,
    const float* __restrict__ b1, const float* __restrict__ w2,
    const float* __restrict__ b2, float* __restrict__ out) {
  __shared__ float ps[256];
  __shared__ float z1[128];
  int g = blockIdx.x;
  int t = threadIdx.x;
  for (int i = t; i < 256; i += 128) {
    float v = pooled[(size_t)g * 256 + i];
    if (v < -1e37f) v = 0.f;   // empty-graph guard (isneginf -> 0)
    ps[i] = v;
  }
  __syncthreads();
  float a = b1[t];
  for (int k = 0; k < 256; ++k) a = fmaf(ps[k], w1[k * 128 + t], a);
  z1[t] = a;
  __syncthreads();
  if (t < 2) {
    float a2 = b2[t];
    for (int j = 0; j < 128; ++j) a2 = fmaf(z1[j], w2[j * 2 + t], a2);
    out[g * 2 + t] = a2;
  }
}

// ---------------- driver --------------------------------------------------------
extern "C" void kernel_launch(void* const* d_in, const int* in_sizes, int n_in,
                              void* d_out, int out_size, void* d_ws, size_t ws_size,
                              hipStream_t stream) {
  const int N = in_sizes[2];         // batch array length = #nodes
  const int E = in_sizes[1] / 2;     // edge_index is [2,E]
  const int G = out_size / 2;        // output [G,2]
  const int T = E + N;               // CSR slots (incl. self loops)
  const int Tpad = ((T + 3) / 4) * 4;
  const int Npad = ((N + 127) / 128) * 128;

  const float* x     = (const float*)d_in[0];
  const int*   ei    = (const int*)d_in[1];
  const int*   src   = ei;
  const int*   dst   = ei + E;
  const int*   batch = (const int*)d_in[2];
  const float* W1    = (const float*)d_in[3];
  const float* atts1 = (const float*)d_in[4];
  const float* attd1 = (const float*)d_in[5];
  const float* b1    = (const float*)d_in[6];
  const float* W2    = (const float*)d_in[7];
  const float* atts2 = (const float*)d_in[8];
  const float* attd2 = (const float*)d_in[9];
  const float* b2    = (const float*)d_in[10];
  const float* l1w   = (const float*)d_in[11];
  const float* l1b   = (const float*)d_in[12];
  const float* l2w   = (const float*)d_in[13];
  const float* l2b   = (const float*)d_in[14];

  uintptr_t p = (uintptr_t)d_ws;
  auto alloc = [&](size_t bytes) -> void* {
    p = (p + 255) & ~(uintptr_t)255;
    void* r = (void*)p;
    p += bytes;
    return r;
  };
  const int nb = (N + SCB - 1) / SCB;
  unsigned short* hbuf = (unsigned short*)alloc((size_t)N * 256 * 2);     // fp16 h (GEMM out)
  unsigned short* xbuf = (unsigned short*)alloc((size_t)Npad * 256 * 2);  // fp16 x
  unsigned short* fbuf = (unsigned short*)alloc((size_t)Npad * 256 * 2);  // fp16 agg out
  float* a_s    = (float*)alloc((size_t)N * 4 * 4);
  float* a_d    = (float*)alloc((size_t)N * 4 * 4);
  float* pooled = (float*)alloc((size_t)G * 256 * 4);
  int*   count  = (int*)alloc((size_t)N * 4);
  int*   rowptr = (int*)alloc((size_t)(N + 1) * 4);
  int*   nxt    = (int*)alloc((size_t)N * 4);
  int*   colx   = (int*)alloc((size_t)Tpad * 4);
  int*   rowx   = (int*)alloc((size_t)Tpad * 4);
  float* ewt    = (float*)alloc((size_t)Tpad * 4 * 4);
  int*   bsum   = (int*)alloc((size_t)nb * 4);
  int*   boff   = (int*)alloc((size_t)(nb + 1) * 4);
  unsigned short* wt1 = (unsigned short*)alloc(256 * 256 * 2);
  unsigned short* wt2 = (unsigned short*)alloc(256 * 256 * 2);

  dim3 blk(256);
  dim3 gemmGrid(Npad / 128, 2);
  int initRange = max(N, G * 256);
  int xtot = N * 256;

  // pre-passes + CSR build (shared by both layers) + init
  conv_w<<<dim3(256, 2), blk, 0, stream>>>(W1, W2, wt1, wt2);
  conv_x<<<(xtot / 4 + 255) / 256, blk, 0, stream>>>(x, xbuf, xtot);
  init_misc<<<(initRange + 255) / 256, blk, 0, stream>>>(count, pooled, N, G);
  hist_k<<<(E + 255) / 256, blk, 0, stream>>>(dst, count, E);
  scan_phaseA<<<nb, blk, 0, stream>>>(count, bsum, N);
  scan_phaseB<<<1, blk, 0, stream>>>(bsum, boff, nb);
  scan_phaseC<<<nb, blk, 0, stream>>>(count, boff, rowptr, nxt, N, nb);
  scatter_k<<<(T + 255) / 256, blk, 0, stream>>>(src, dst, nxt, colx, rowx, E, N);

  // ---- layer 1
  gemm_mfma<<<gemmGrid, blk, 0, stream>>>(xbuf, wt1, atts1, attd1, hbuf, a_s, a_d, N);
  edge_w<<<(T + 255) / 256, blk, 0, stream>>>(colx, rowx, a_s, a_d, ewt, Tpad);
  agg<<<(N + 3) / 4, blk, 0, stream>>>(hbuf, rowptr, colx, ewt, Tpad, b1, fbuf, N);

  // ---- layer 2
  gemm_mfma<<<gemmGrid, blk, 0, stream>>>(fbuf, wt2, atts2, attd2, hbuf, a_s, a_d, N);
  edge_w<<<(T + 255) / 256, blk, 0, stream>>>(colx, rowx, a_s, a_d, ewt, Tpad);
  agg<<<(N + 3) / 4, blk, 0, stream>>>(hbuf, rowptr, colx, ewt, Tpad, b2, fbuf, N);

  // ---- pool + head
  pool_max<<<(N + PNB - 1) / PNB, blk, 0, stream>>>(fbuf, batch, pooled, N);
  head_k<<<G, 128, 0, stream>>>(pooled, l1w, l1b, l2w, l2b, (float*)d_out);
}

// Round 12
// 233.699 us; speedup vs baseline: 3.8640x; 1.0221x over previous
//
#include <hip/hip_runtime.h>
#include <math.h>

#define LRELU_SLOPE 0.2f
#define NEG_INF __int_as_float(0xff800000)

typedef float f32x4 __attribute__((ext_vector_type(4)));
typedef _Float16 f16x8 __attribute__((ext_vector_type(8)));
typedef _Float16 f16x2 __attribute__((ext_vector_type(2)));
typedef unsigned short us8 __attribute__((ext_vector_type(8)));

__device__ __forceinline__ void atomicMaxF(float* addr, float v) {
  if (v >= 0.f) atomicMax((int*)addr, __float_as_int(v));
  else atomicMin((unsigned int*)addr, (unsigned int)__float_as_int(v));
}

__device__ __forceinline__ unsigned short f2h(float f) {
  _Float16 h = (_Float16)f;                       // v_cvt_f16_f32 (RNE)
  return __builtin_bit_cast(unsigned short, h);
}
__device__ __forceinline__ float2 up2(unsigned int u) {
  f16x2 h = __builtin_bit_cast(f16x2, u);
  return make_float2((float)h.x, (float)h.y);
}

// async global->LDS, 16B per lane; LDS dest must be the wave-uniform base
__device__ __forceinline__ void async_copy16(const unsigned short* g, unsigned short* l) {
  __builtin_amdgcn_global_load_lds(
      (const __attribute__((address_space(1))) void*)g,
      (__attribute__((address_space(3))) void*)l, 16, 0, 0);
}

// ---------------- W pre-pass: transpose + cvt to fp16 --------------------------
__global__ void conv_w(const float* __restrict__ W1, const float* __restrict__ W2,
                       unsigned short* __restrict__ t1, unsigned short* __restrict__ t2) {
  const float* W = blockIdx.y ? W2 : W1;
  unsigned short* t = blockIdx.y ? t2 : t1;
  int k = blockIdx.x, n = threadIdx.x;
  t[n * 256 + k] = f2h(W[k * 256 + n]);
}

// ---------------- X pre-pass: f32 -> fp16 --------------------------------------
__global__ __launch_bounds__(256) void conv_x(
    const float* __restrict__ x, unsigned short* __restrict__ xo, int total) {
  int base = (blockIdx.x * 256 + threadIdx.x) * 4;
  if (base >= total) return;
  float4 v = *(const float4*)(x + base);
  ushort4 h;
  h.x = f2h(v.x); h.y = f2h(v.y); h.z = f2h(v.z); h.w = f2h(v.w);
  *(ushort4*)(xo + base) = h;
}

// ---------------- GEMM + fused attention coefficients --------------------------
// Cfp16[M,256] = A[M,256] @ B^T (fp16 MFMA, f32 accum).
// Each wave's 64 output cols = one full head -> a_s/a_d computed exactly from
// f32 acc via 4 FMAs/row + 16-lane shfl reduce, written once (no atomics).
__global__ __launch_bounds__(256) void gemm_mfma(
    const unsigned short* __restrict__ A, const unsigned short* __restrict__ Bt,
    const float* __restrict__ att_s, const float* __restrict__ att_d,
    unsigned short* __restrict__ C, float* __restrict__ a_s,
    float* __restrict__ a_d, int M) {
  __shared__ __align__(16) unsigned short sA[128 * 64];
  __shared__ __align__(16) unsigned short sB[128 * 64];
  const int tid = threadIdx.x;
  const int lane = tid & 63;
  const int wave = tid >> 6;
  const int wr = wave >> 1, wc = wave & 1;
  const int bm = blockIdx.x * 128;
  const int bn = blockIdx.y * 128;

  const int srow = lane >> 3;                          // 0..7
  const int scol = (((lane & 7) ^ (lane >> 3)) << 3);  // swizzled ushort col

  f32x4 acc[4][4];
#pragma unroll
  for (int i = 0; i < 4; ++i)
#pragma unroll
    for (int j = 0; j < 4; ++j) acc[i][j] = (f32x4){0.f, 0.f, 0.f, 0.f};

  for (int kc = 0; kc < 256; kc += 64) {
#pragma unroll
    for (int i = 0; i < 4; ++i) {
      const int r0 = wave * 32 + i * 8;
      const size_t ga = (size_t)(bm + r0 + srow) * 256 + kc + scol;
      const size_t gb = (size_t)(bn + r0 + srow) * 256 + kc + scol;
      async_copy16(A + ga, &sA[r0 * 64]);
      async_copy16(Bt + gb, &sB[r0 * 64]);
    }
    __syncthreads();
#pragma unroll
    for (int ks = 0; ks < 64; ks += 32) {
      const int kbase = ks + ((lane >> 4) << 3);
      const int kx = kbase ^ ((lane & 7) << 3);
      f16x8 af[4], bf[4];
#pragma unroll
      for (int f = 0; f < 4; ++f) {
        int ar = wr * 64 + f * 16 + (lane & 15);
        int br = wc * 64 + f * 16 + (lane & 15);
        af[f] = __builtin_bit_cast(f16x8, *(const us8*)&sA[ar * 64 + kx]);
        bf[f] = __builtin_bit_cast(f16x8, *(const us8*)&sB[br * 64 + kx]);
      }
#pragma unroll
      for (int i = 0; i < 4; ++i)
#pragma unroll
        for (int j = 0; j < 4; ++j)
          acc[i][j] = __builtin_amdgcn_mfma_f32_16x16x32_f16(af[i], bf[j], acc[i][j], 0, 0, 0);
    }
    __syncthreads();
  }

  // ---- fused attention coefficients: head = blockIdx.y*2 + wc
  const int head = blockIdx.y * 2 + wc;
  float ws[4], wd[4];
#pragma unroll
  for (int j = 0; j < 4; ++j) {
    ws[j] = att_s[head * 64 + j * 16 + (lane & 15)];
    wd[j] = att_d[head * 64 + j * 16 + (lane & 15)];
  }
#pragma unroll
  for (int i = 0; i < 4; ++i) {
#pragma unroll
    for (int r = 0; r < 4; ++r) {
      float ps = 0.f, pd = 0.f;
#pragma unroll
      for (int j = 0; j < 4; ++j) {
        ps = fmaf(acc[i][j][r], ws[j], ps);
        pd = fmaf(acc[i][j][r], wd[j], pd);
      }
#pragma unroll
      for (int off = 1; off < 16; off <<= 1) {
        ps += __shfl_xor(ps, off);
        pd += __shfl_xor(pd, off);
      }
      int row = bm + wr * 64 + i * 16 + ((lane >> 4) << 2) + r;
      if ((lane & 15) == 0 && row < M) {
        a_s[row * 4 + head] = ps;
        a_d[row * 4 + head] = pd;
      }
    }
  }

  // ---- C store (fp16). m=(lane>>4)*4+reg, n=lane&15 within each 16x16 frag
#pragma unroll
  for (int i = 0; i < 4; ++i) {
#pragma unroll
    for (int r = 0; r < 4; ++r) {
      int row = bm + wr * 64 + i * 16 + ((lane >> 4) << 2) + r;
      if (row < M) {
#pragma unroll
        for (int j = 0; j < 4; ++j)
          C[(size_t)row * 256 + bn + wc * 64 + j * 16 + (lane & 15)] = f2h(acc[i][j][r]);
      }
    }
  }
}

// ---------------- misc init ---------------------------------------------------
__global__ void init_misc(int* __restrict__ count, float* __restrict__ pooled,
                          int N_, int G_) {
  int t = blockIdx.x * 256 + threadIdx.x;
  if (t < N_) count[t] = 1;                 // self loop
  if (t < G_ * 256) pooled[t] = NEG_INF;
}

// ---------------- CSR build ----------------------------------------------------
__global__ void hist_k(const int* __restrict__ dst, int* __restrict__ count, int E_) {
  int t = blockIdx.x * 256 + threadIdx.x;
  if (t < E_) atomicAdd(&count[dst[t]], 1);
}

#define SCB 1024

__global__ __launch_bounds__(256) void scan_phaseA(
    const int* __restrict__ count, int* __restrict__ bsum, int N_) {
  int t = threadIdx.x;
  int base = blockIdx.x * SCB + t * 4;
  int s = 0;
  if (base + 3 < N_) {
    int4 v = *(const int4*)(count + base);
    s = v.x + v.y + v.z + v.w;
  } else {
#pragma unroll
    for (int k = 0; k < 4; ++k) if (base + k < N_) s += count[base + k];
  }
#pragma unroll
  for (int off = 32; off > 0; off >>= 1) s += __shfl_xor(s, off);
  __shared__ int red[4];
  int wave = t >> 6, lane = t & 63;
  if (lane == 0) red[wave] = s;
  __syncthreads();
  if (t == 0) bsum[blockIdx.x] = red[0] + red[1] + red[2] + red[3];
}

__global__ __launch_bounds__(256) void scan_phaseB(
    const int* __restrict__ bsum, int* __restrict__ boff, int nb) {
  __shared__ int tmp[256];
  int t = threadIdx.x;
  int v = (t < nb) ? bsum[t] : 0;
  tmp[t] = v;
  __syncthreads();
  for (int off = 1; off < 256; off <<= 1) {
    int u = (t >= off) ? tmp[t - off] : 0;
    __syncthreads();
    tmp[t] += u;
    __syncthreads();
  }
  if (t < nb) boff[t] = tmp[t] - v;  // exclusive
  if (t == 0) boff[nb] = tmp[255];   // grand total
}

__global__ __launch_bounds__(256) void scan_phaseC(
    const int* __restrict__ count, const int* __restrict__ boff,
    int* __restrict__ rowptr, int* __restrict__ nxt, int N_, int nb) {
  __shared__ int tmp[256];
  int t = threadIdx.x;
  int base = blockIdx.x * SCB + t * 4;
  int4 v = make_int4(0, 0, 0, 0);
  if (base + 3 < N_) {
    v = *(const int4*)(count + base);
  } else {
    if (base + 0 < N_) v.x = count[base + 0];
    if (base + 1 < N_) v.y = count[base + 1];
    if (base + 2 < N_) v.z = count[base + 2];
  }
  int s = v.x + v.y + v.z + v.w;
  tmp[t] = s;
  __syncthreads();
  for (int off = 1; off < 256; off <<= 1) {
    int u = (t >= off) ? tmp[t - off] : 0;
    __syncthreads();
    tmp[t] += u;
    __syncthreads();
  }
  int run = boff[blockIdx.x] + tmp[t] - s;
  int4 rp;
  rp.x = run; run += v.x;
  rp.y = run; run += v.y;
  rp.z = run; run += v.z;
  rp.w = run;
  if (base + 3 < N_) {
    *(int4*)(rowptr + base) = rp;
    *(int4*)(nxt + base) = rp;
  } else {
    if (base + 0 < N_) { rowptr[base + 0] = rp.x; nxt[base + 0] = rp.x; }
    if (base + 1 < N_) { rowptr[base + 1] = rp.y; nxt[base + 1] = rp.y; }
    if (base + 2 < N_) { rowptr[base + 2] = rp.z; nxt[base + 2] = rp.z; }
  }
  if (blockIdx.x == 0 && t == 0) rowptr[N_] = boff[nb];
}

__global__ void scatter_k(const int* __restrict__ src, const int* __restrict__ dst,
                          int* __restrict__ nxt, int* __restrict__ colx,
                          int* __restrict__ rowx, int E_, int N_) {
  int t = blockIdx.x * 256 + threadIdx.x;
  if (t >= E_ + N_) return;
  int s = (t < E_) ? src[t] : (t - E_);
  int d = (t < E_) ? dst[t] : (t - E_);
  int pos = atomicAdd(&nxt[d], 1);
  colx[pos] = s;
  rowx[pos] = d;
}

// ---------------- per-slot softmax weights, head-major: ewt[head][slot] --------
__global__ __launch_bounds__(256) void edge_w(
    const int* __restrict__ colx, const int* __restrict__ rowx,
    const float* __restrict__ a_s, const float* __restrict__ a_d,
    float* __restrict__ ewt, int T) {
  int t = blockIdx.x * 256 + threadIdx.x;
  if (t >= T) return;
  int s = colx[t], d = rowx[t];
  float4 as4 = *(const float4*)(a_s + (size_t)s * 4);
  float4 ad4 = *(const float4*)(a_d + (size_t)d * 4);
  float l;
  l = as4.x + ad4.x; l = l > 0.f ? l : LRELU_SLOPE * l; ewt[0 * (size_t)T + t] = __expf(l);
  l = as4.y + ad4.y; l = l > 0.f ? l : LRELU_SLOPE * l; ewt[1 * (size_t)T + t] = __expf(l);
  l = as4.z + ad4.z; l = l > 0.f ? l : LRELU_SLOPE * l; ewt[2 * (size_t)T + t] = __expf(l);
  l = as4.w + ad4.w; l = l > 0.f ? l : LRELU_SLOPE * l; ewt[3 * (size_t)T + t] = __expf(l);
}

// ---------------- aggregation: 2 edges per wave-instruction -------------------
// lane owns 8 channels (16B); half-waves process different edges concurrently.
// out[n,c] = elu( (sum_e w_e * h[s_e,c]) / sum_e w_e + bias[c] )
__global__ __launch_bounds__(256) void agg(
    const unsigned short* __restrict__ h, const int* __restrict__ rowptr,
    const int* __restrict__ colx, const float* __restrict__ ewt, int T,
    const float* __restrict__ bias, unsigned short* __restrict__ out, int N_) {
  const int wave = threadIdx.x >> 6;
  const int lane = threadIdx.x & 63;
  const int n = blockIdx.x * 4 + wave;
  if (n >= N_) return;
  const int half = lane >> 5;          // which edge of the pair
  const int lc = lane & 31;            // 32 lanes cover 256 channels
  const int head = lc >> 3;            // 8 lanes per head
  const float* ewh = ewt + (size_t)head * T;
  const size_t choff = (size_t)lc * 8; // ushort offset (16B per lane)
  const int e0 = rowptr[n], e1 = rowptr[n + 1];
  f32x4 accA = (f32x4){0.f, 0.f, 0.f, 0.f};
  f32x4 accB = (f32x4){0.f, 0.f, 0.f, 0.f};
  float dsum = 0.f;
  int j = e0;
  // 4 edges per iteration: two pair-steps, independent gathers in flight
  for (; j + 4 <= e1; j += 4) {
    int s0 = colx[j + half];
    int s1 = colx[j + 2 + half];
    float w0 = ewh[j + half];
    float w1 = ewh[j + 2 + half];
    uint4 g0 = *(const uint4*)(h + (size_t)s0 * 256 + choff);
    uint4 g1 = *(const uint4*)(h + (size_t)s1 * 256 + choff);
    dsum += w0 + w1;
    float2 p0 = up2(g0.x), p1 = up2(g0.y), p2 = up2(g0.z), p3 = up2(g0.w);
    accA.x = fmaf(w0, p0.x, accA.x); accA.y = fmaf(w0, p0.y, accA.y);
    accA.z = fmaf(w0, p1.x, accA.z); accA.w = fmaf(w0, p1.y, accA.w);
    accB.x = fmaf(w0, p2.x, accB.x); accB.y = fmaf(w0, p2.y, accB.y);
    accB.z = fmaf(w0, p3.x, accB.z); accB.w = fmaf(w0, p3.y, accB.w);
    float2 q0 = up2(g1.x), q1 = up2(g1.y), q2 = up2(g1.z), q3 = up2(g1.w);
    accA.x = fmaf(w1, q0.x, accA.x); accA.y = fmaf(w1, q0.y, accA.y);
    accA.z = fmaf(w1, q1.x, accA.z); accA.w = fmaf(w1, q1.y, accA.w);
    accB.x = fmaf(w1, q2.x, accB.x); accB.y = fmaf(w1, q2.y, accB.y);
    accB.z = fmaf(w1, q3.x, accB.z); accB.w = fmaf(w1, q3.y, accB.w);
  }
  // 2-edge step
  for (; j + 2 <= e1; j += 2) {
    int s0 = colx[j + half];
    float w0 = ewh[j + half];
    uint4 g0 = *(const uint4*)(h + (size_t)s0 * 256 + choff);
    dsum += w0;
    float2 p0 = up2(g0.x), p1 = up2(g0.y), p2 = up2(g0.z), p3 = up2(g0.w);
    accA.x = fmaf(w0, p0.x, accA.x); accA.y = fmaf(w0, p0.y, accA.y);
    accA.z = fmaf(w0, p1.x, accA.z); accA.w = fmaf(w0, p1.y, accA.w);
    accB.x = fmaf(w0, p2.x, accB.x); accB.y = fmaf(w0, p2.y, accB.y);
    accB.z = fmaf(w0, p3.x, accB.z); accB.w = fmaf(w0, p3.y, accB.w);
  }
  // last single edge: upper half contributes zero (w masked)
  if (j < e1) {
    int s0 = colx[j];
    float w0 = half ? 0.f : ewh[j];
    uint4 g0 = *(const uint4*)(h + (size_t)s0 * 256 + choff);
    dsum += w0;
    float2 p0 = up2(g0.x), p1 = up2(g0.y), p2 = up2(g0.z), p3 = up2(g0.w);
    accA.x = fmaf(w0, p0.x, accA.x); accA.y = fmaf(w0, p0.y, accA.y);
    accA.z = fmaf(w0, p1.x, accA.z); accA.w = fmaf(w0, p1.y, accA.w);
    accB.x = fmaf(w0, p2.x, accB.x); accB.y = fmaf(w0, p2.y, accB.y);
    accB.z = fmaf(w0, p3.x, accB.z); accB.w = fmaf(w0, p3.y, accB.w);
  }
  // combine the two half-waves (lane l <-> l+32, same channels/head)
  accA.x += __shfl_xor(accA.x, 32); accA.y += __shfl_xor(accA.y, 32);
  accA.z += __shfl_xor(accA.z, 32); accA.w += __shfl_xor(accA.w, 32);
  accB.x += __shfl_xor(accB.x, 32); accB.y += __shfl_xor(accB.y, 32);
  accB.z += __shfl_xor(accB.z, 32); accB.w += __shfl_xor(accB.w, 32);
  dsum += __shfl_xor(dsum, 32);
  if (half == 0) {
    const float inv = 1.f / (dsum + 1e-16f);
    const float4 bA = *(const float4*)(bias + lc * 8);
    const float4 bB = *(const float4*)(bias + lc * 8 + 4);
    float v;
    us8 o;
    v = accA.x * inv + bA.x; o[0] = f2h(v > 0.f ? v : expm1f(v));
    v = accA.y * inv + bA.y; o[1] = f2h(v > 0.f ? v : expm1f(v));
    v = accA.z * inv + bA.z; o[2] = f2h(v > 0.f ? v : expm1f(v));
    v = accA.w * inv + bA.w; o[3] = f2h(v > 0.f ? v : expm1f(v));
    v = accB.x * inv + bB.x; o[4] = f2h(v > 0.f ? v : expm1f(v));
    v = accB.y * inv + bB.y; o[5] = f2h(v > 0.f ? v : expm1f(v));
    v = accB.z * inv + bB.z; o[6] = f2h(v > 0.f ? v : expm1f(v));
    v = accB.w * inv + bB.w; o[7] = f2h(v > 0.f ? v : expm1f(v));
    *(us8*)(out + (size_t)n * 256 + choff) = o;
  }
}

// ---------------- graph max-pool from fp16 (batch is sorted) -------------------
#define PNB 32
__global__ __launch_bounds__(256) void pool_max(
    const unsigned short* __restrict__ fb, const int* __restrict__ batch,
    float* __restrict__ pooled, int N_) {
  const int c2 = threadIdx.x & 127;        // channels 2*c2, 2*c2+1
  const int slot = threadIdx.x >> 7;       // 2 slots x 16 nodes
  const int ns = blockIdx.x * PNB + slot * 16;
  const int ne = min(ns + 16, N_);
  if (ns >= N_) return;
  float r0 = NEG_INF, r1 = NEG_INF;
  int g = batch[ns];
#pragma unroll 4
  for (int n = ns; n < ne; ++n) {
    int gn = batch[n];
    unsigned int w = *(const unsigned int*)(fb + (size_t)n * 256 + c2 * 2);
    if (gn != g) {
      atomicMaxF(&pooled[(size_t)g * 256 + c2 * 2], r0);
      atomicMaxF(&pooled[(size_t)g * 256 + c2 * 2 + 1], r1);
      r0 = r1 = NEG_INF; g = gn;
    }
    float2 xv = up2(w);
    r0 = fmaxf(r0, xv.x);
    r1 = fmaxf(r1, xv.y);
  }
  atomicMaxF(&pooled[(size_t)g * 256 + c2 * 2], r0);
  atomicMaxF(&pooled[(size_t)g * 256 + c2 * 2 + 1], r1);
}

// ---------------- head: fixup -inf, lin1 (256->128), lin2 (128->2) ------------
__global__ __launch_bounds__(128) void head_k(
    const float* __restrict__ pooled, const float* __restrict__ w1,
    const float* __restrict__ b1, const float* __restrict__ w2,
    const float* __restrict__ b2, float* __restrict__ out) {
  __shared__ float ps[256];
  __shared__ float z1[128];
  int g = blockIdx.x;
  int t = threadIdx.x;
  for (int i = t; i < 256; i += 128) {
    float v = pooled[(size_t)g * 256 + i];
    if (v < -1e37f) v = 0.f;   // empty-graph guard (isneginf -> 0)
    ps[i] = v;
  }
  __syncthreads();
  float a = b1[t];
  for (int k = 0; k < 256; ++k) a = fmaf(ps[k], w1[k * 128 + t], a);
  z1[t] = a;
  __syncthreads();
  if (t < 2) {
    float a2 = b2[t];
    for (int j = 0; j < 128; ++j) a2 = fmaf(z1[j], w2[j * 2 + t], a2);
    out[g * 2 + t] = a2;
  }
}

// ---------------- driver --------------------------------------------------------
extern "C" void kernel_launch(void* const* d_in, const int* in_sizes, int n_in,
                              void* d_out, int out_size, void* d_ws, size_t ws_size,
                              hipStream_t stream) {
  const int N = in_sizes[2];         // batch array length = #nodes
  const int E = in_sizes[1] / 2;     // edge_index is [2,E]
  const int G = out_size / 2;        // output [G,2]
  const int T = E + N;               // CSR slots (incl. self loops)
  const int Tpad = ((T + 3) / 4) * 4;
  const int Npad = ((N + 127) / 128) * 128;

  const float* x     = (const float*)d_in[0];
  const int*   ei    = (const int*)d_in[1];
  const int*   src   = ei;
  const int*   dst   = ei + E;
  const int*   batch = (const int*)d_in[2];
  const float* W1    = (const float*)d_in[3];
  const float* atts1 = (const float*)d_in[4];
  const float* attd1 = (const float*)d_in[5];
  const float* b1    = (const float*)d_in[6];
  const float* W2    = (const float*)d_in[7];
  const float* atts2 = (const float*)d_in[8];
  const float* attd2 = (const float*)d_in[9];
  const float* b2    = (const float*)d_in[10];
  const float* l1w   = (const float*)d_in[11];
  const float* l1b   = (const float*)d_in[12];
  const float* l2w   = (const float*)d_in[13];
  const float* l2b   = (const float*)d_in[14];

  uintptr_t p = (uintptr_t)d_ws;
  auto alloc = [&](size_t bytes) -> void* {
    p = (p + 255) & ~(uintptr_t)255;
    void* r = (void*)p;
    p += bytes;
    return r;
  };
  const int nb = (N + SCB - 1) / SCB;
  unsigned short* hbuf = (unsigned short*)alloc((size_t)N * 256 * 2);     // fp16 h (GEMM out)
  unsigned short* xbuf = (unsigned short*)alloc((size_t)Npad * 256 * 2);  // fp16 x
  unsigned short* fbuf = (unsigned short*)alloc((size_t)Npad * 256 * 2);  // fp16 agg out
  float* a_s    = (float*)alloc((size_t)N * 4 * 4);
  float* a_d    = (float*)alloc((size_t)N * 4 * 4);
  float* pooled = (float*)alloc((size_t)G * 256 * 4);
  int*   count  = (int*)alloc((size_t)N * 4);
  int*   rowptr = (int*)alloc((size_t)(N + 1) * 4);
  int*   nxt    = (int*)alloc((size_t)N * 4);
  int*   colx   = (int*)alloc((size_t)Tpad * 4);
  int*   rowx   = (int*)alloc((size_t)Tpad * 4);
  float* ewt    = (float*)alloc((size_t)Tpad * 4 * 4);
  int*   bsum   = (int*)alloc((size_t)nb * 4);
  int*   boff   = (int*)alloc((size_t)(nb + 1) * 4);
  unsigned short* wt1 = (unsigned short*)alloc(256 * 256 * 2);
  unsigned short* wt2 = (unsigned short*)alloc(256 * 256 * 2);

  dim3 blk(256);
  dim3 gemmGrid(Npad / 128, 2);
  int initRange = max(N, G * 256);
  int xtot = N * 256;

  // pre-passes + CSR build (shared by both layers) + init
  conv_w<<<dim3(256, 2), blk, 0, stream>>>(W1, W2, wt1, wt2);
  conv_x<<<(xtot / 4 + 255) / 256, blk, 0, stream>>>(x, xbuf, xtot);
  init_misc<<<(initRange + 255) / 256, blk, 0, stream>>>(count, pooled, N, G);
  hist_k<<<(E + 255) / 256, blk, 0, stream>>>(dst, count, E);
  scan_phaseA<<<nb, blk, 0, stream>>>(count, bsum, N);
  scan_phaseB<<<1, blk, 0, stream>>>(bsum, boff, nb);
  scan_phaseC<<<nb, blk, 0, stream>>>(count, boff, rowptr, nxt, N, nb);
  scatter_k<<<(T + 255) / 256, blk, 0, stream>>>(src, dst, nxt, colx, rowx, E, N);

  // ---- layer 1
  gemm_mfma<<<gemmGrid, blk, 0, stream>>>(xbuf, wt1, atts1, attd1, hbuf, a_s, a_d, N);
  edge_w<<<(T + 255) / 256, blk, 0, stream>>>(colx, rowx, a_s, a_d, ewt, Tpad);
  agg<<<(N + 3) / 4, blk, 0, stream>>>(hbuf, rowptr, colx, ewt, Tpad, b1, fbuf, N);

  // ---- layer 2
  gemm_mfma<<<gemmGrid, blk, 0, stream>>>(fbuf, wt2, atts2, attd2, hbuf, a_s, a_d, N);
  edge_w<<<(T + 255) / 256, blk, 0, stream>>>(colx, rowx, a_s, a_d, ewt, Tpad);
  agg<<<(N + 3) / 4, blk, 0, stream>>>(hbuf, rowptr, colx, ewt, Tpad, b2, fbuf, N);

  // ---- pool + head
  pool_max<<<(N + PNB - 1) / PNB, blk, 0, stream>>>(fbuf, batch, pooled, N);
  head_k<<<G, 128, 0, stream>>>(pooled, l1w, l1b, l2w, l2b, (float*)d_out);
}